// Round 16
// baseline (1154.804 us; speedup 1.0000x reference)
//
#include <hip/hip_runtime.h>
#include <hip/hip_bf16.h>
#include <math.h>

// RWKV7 attention, round 16: fp16 scan streams end-to-end.
//  - All six scan streams (EW,R,Kf,KK,BV,V) stored fp16 in global; producers write
//    fp16 directly (gemm_h2 fp16-out mode, gemm_f32 mode1, ka_epi, lora1->HG16).
//  - rwkv_scan: 6 ds_reads/step (5xb128 + u16), 11 gld16/chunk, converts in PRE.
//  - gn_bonus emits ON fp16 directly (Wo mixcvt pass deleted); g-gate mixcvt deleted.
// Scan config/math otherwise identical to round-15 (proven 402us structure).

typedef __attribute__((ext_vector_type(8))) unsigned short ushort8;
typedef __attribute__((ext_vector_type(8))) _Float16 f16x8;
typedef __attribute__((ext_vector_type(4))) float f32x4;
typedef __attribute__((ext_vector_type(2))) float f32x2;

__device__ inline unsigned short f2h(float f) {
    _Float16 h = (_Float16)f;
    return __builtin_bit_cast(unsigned short, h);
}
__device__ inline float h2f(unsigned short u) {
    return (float)__builtin_bit_cast(_Float16, u);
}
__device__ inline float sigm(float x) { return 1.f / (1.f + expf(-x)); }

// ---- VALU cross-lane reductions (DPP rotates + permlane swaps; distinct-reg rule from r9) ----
template <int CTRL>
__device__ __forceinline__ float rrot(float x) {
    int xi = __builtin_bit_cast(int, x);
    int yi = __builtin_amdgcn_update_dpp(xi, xi, CTRL, 0xf, 0xf, true);
    return x + __builtin_bit_cast(float, yi);
}
__device__ __forceinline__ float red8(float x)  { return rrot<0x128>(x); }
__device__ __forceinline__ float red16(float x) {
    float b = x;
    asm("" : "+v"(b));
    float a = x;
    asm("v_permlane16_swap_b32 %0, %1" : "+v"(a), "+v"(b));
    return a + b;
}
__device__ __forceinline__ float red32(float x) {
    float b = x;
    asm("" : "+v"(b));
    float a = x;
    asm("v_permlane32_swap_b32 %0, %1" : "+v"(a), "+v"(b));
    return a + b;
}
__device__ __forceinline__ float full64(float x) {
    x = rrot<0x121>(x);
    x = rrot<0x122>(x);
    x = rrot<0x124>(x);
    x = rrot<0x128>(x);
    return red32(red16(x));
}

// async global -> LDS. LDS dest = uniform base + lane*size.
__device__ __forceinline__ void gld16(void* lds, const void* g)
{
    __builtin_amdgcn_global_load_lds(
        (const __attribute__((address_space(1))) void*)g,
        (__attribute__((address_space(3))) void*)lds, 16, 0, 0);
}

// ---------------- mix (optional) + convert to single fp16 ----------------
__global__ void mixcvt_h(const float* __restrict__ in, const float* __restrict__ xxr,
                         unsigned short* __restrict__ o16, int T, int D, int total8, int domix)
{
    int i = blockIdx.x * 256 + threadIdx.x;
    if (i >= total8) return;
    const size_t e = (size_t)i * 8;
    float a[8];
    *(float4*)&a[0] = *(const float4*)(in + e);
    *(float4*)&a[4] = *(const float4*)(in + e + 4);
    if (domix) {
        const int m = (int)(e / D);
        const int d = (int)(e % D);
        const int t = m % T;
        float p[8] = {0.f,0.f,0.f,0.f,0.f,0.f,0.f,0.f};
        if (t > 0) {
            *(float4*)&p[0] = *(const float4*)(in + e - D);
            *(float4*)&p[4] = *(const float4*)(in + e - D + 4);
        }
        float xv[8];
        *(float4*)&xv[0] = *(const float4*)(xxr + d);
        *(float4*)&xv[4] = *(const float4*)(xxr + d + 4);
        #pragma unroll
        for (int j = 0; j < 8; ++j) a[j] += (p[j] - a[j]) * xv[j];
    }
    ushort8 o;
    #pragma unroll
    for (int j = 0; j < 8; ++j) o[j] = f2h(a[j]);
    *(ushort8*)(o16 + e) = o;
}

// two mixes in one pass (hid/prev read once)
__global__ void mixcvt2_h(const float* __restrict__ in,
                          const float* __restrict__ xx0, const float* __restrict__ xx1,
                          unsigned short* __restrict__ o0, unsigned short* __restrict__ o1,
                          int T, int D, int total8)
{
    int i = blockIdx.x * 256 + threadIdx.x;
    if (i >= total8) return;
    const size_t e = (size_t)i * 8;
    float a[8];
    *(float4*)&a[0] = *(const float4*)(in + e);
    *(float4*)&a[4] = *(const float4*)(in + e + 4);
    const int m = (int)(e / D);
    const int d = (int)(e % D);
    const int t = m % T;
    float p[8] = {0.f,0.f,0.f,0.f,0.f,0.f,0.f,0.f};
    if (t > 0) {
        *(float4*)&p[0] = *(const float4*)(in + e - D);
        *(float4*)&p[4] = *(const float4*)(in + e - D + 4);
    }
    float x0[8], x1[8];
    *(float4*)&x0[0] = *(const float4*)(xx0 + d);
    *(float4*)&x0[4] = *(const float4*)(xx0 + d + 4);
    *(float4*)&x1[0] = *(const float4*)(xx1 + d);
    *(float4*)&x1[4] = *(const float4*)(xx1 + d + 4);
    ushort8 r0, r1;
    #pragma unroll
    for (int j = 0; j < 8; ++j) {
        r0[j] = f2h(a[j] + (p[j] - a[j]) * x0[j]);
        r1[j] = f2h(a[j] + (p[j] - a[j]) * x1[j]);
    }
    *(ushort8*)(o0 + e) = r0;
    *(ushort8*)(o1 + e) = r1;
}

// ---------------- weight split: hi = fp16(w), lo = fp16(w - hi) ----------------
__global__ void wsplit_h(const float* __restrict__ in,
                         unsigned short* __restrict__ hi, unsigned short* __restrict__ lo,
                         int total8)
{
    int i = blockIdx.x * 256 + threadIdx.x;
    if (i >= total8) return;
    const size_t e = (size_t)i * 8;
    float a[8];
    *(float4*)&a[0] = *(const float4*)(in + e);
    *(float4*)&a[4] = *(const float4*)(in + e + 4);
    ushort8 h8, l8;
    #pragma unroll
    for (int j = 0; j < 8; ++j) {
        const unsigned short h = f2h(a[j]);
        h8[j] = h;
        l8[j] = f2h(a[j] - h2f(h));
    }
    *(ushort8*)(hi + e) = h8;
    *(ushort8*)(lo + e) = l8;
}

// ---------------- fp16 2-term MFMA GEMM: C[M,N] = A[M,K] @ W[N,K]^T ----------
// A single fp16; W hi/lo fp16; acc = A*Wh + A*Wl.
// mode 0: Cf = acc (f32). mode 1: Cb = fp16(acc). mode 2: Cb = fp16(lerp(acc,aux,sigm(yv+bias))).
#define GBM 128
#define GBN 128

__global__ __launch_bounds__(256) void gemm_h2(
    const unsigned short* __restrict__ Ag,
    const unsigned short* __restrict__ Bhg, const unsigned short* __restrict__ Blg,
    float* __restrict__ Cf, unsigned short* __restrict__ Cb,
    int M, int N, int K, int mode,
    const float* __restrict__ yv, const float* __restrict__ bias,
    const float* __restrict__ aux,
    size_t sA, size_t sB, size_t sC)
{
    __shared__ unsigned short As[GBM * 32];
    __shared__ unsigned short Bhs[GBN * 32], Bls[GBN * 32];
    const int z = blockIdx.z;
    Ag  += (size_t)z * sA;
    Bhg += (size_t)z * sB;
    Blg += (size_t)z * sB;
    if (Cf) Cf += (size_t)z * sC;
    if (Cb) Cb += (size_t)z * sC;
    const int tid = threadIdx.x;
    const int m0 = blockIdx.x * GBM;
    const int n0 = blockIdx.y * GBN;
    const int wave = tid >> 6, lane = tid & 63;
    const int wr = (wave >> 1) * 64, wc = (wave & 1) * 64;
    const int fr = lane & 15, fq = lane >> 4;

    f32x4 acc[4][4];
    #pragma unroll
    for (int i = 0; i < 4; ++i)
        #pragma unroll
        for (int j = 0; j < 4; ++j)
            acc[i][j] = (f32x4){0.f, 0.f, 0.f, 0.f};

    const unsigned short* gsrc;
    unsigned short* lbuf;
    int rofs, nld;
    if (wave == 0)      { gsrc = Ag;  lbuf = As;           rofs = m0;      nld = 4; }
    else if (wave == 1) { gsrc = Ag;  lbuf = As + 64 * 32; rofs = m0 + 64; nld = 4; }
    else if (wave == 2) { gsrc = Bhg; lbuf = Bhs;          rofs = n0;      nld = 8; }
    else                { gsrc = Blg; lbuf = Bls;          rofs = n0;      nld = 8; }
    const unsigned short* gbase = gsrc + (size_t)(rofs + (lane >> 2)) * K + ((lane & 3) << 3);

    for (int k0 = 0; k0 < K; k0 += 32) {
        #pragma unroll
        for (int j = 0; j < 8; ++j)
            if (j < nld)
                gld16(lbuf + j * 16 * 32, gbase + (size_t)(j * 16) * K + k0);
        __syncthreads();

        f16x8 fa[4], fbh[4], fbl[4];
        #pragma unroll
        for (int m = 0; m < 4; ++m)
            fa[m] = *(const f16x8*)&As[(wr + m * 16 + fr) * 32 + fq * 8];
        #pragma unroll
        for (int n = 0; n < 4; ++n) {
            fbh[n] = *(const f16x8*)&Bhs[(wc + n * 16 + fr) * 32 + fq * 8];
            fbl[n] = *(const f16x8*)&Bls[(wc + n * 16 + fr) * 32 + fq * 8];
        }
        #pragma unroll
        for (int m = 0; m < 4; ++m)
            #pragma unroll
            for (int n = 0; n < 4; ++n) {
                acc[m][n] = __builtin_amdgcn_mfma_f32_16x16x32_f16(fa[m], fbh[n], acc[m][n], 0, 0, 0);
                acc[m][n] = __builtin_amdgcn_mfma_f32_16x16x32_f16(fa[m], fbl[n], acc[m][n], 0, 0, 0);
            }
        __syncthreads();
    }

    #pragma unroll
    for (int m = 0; m < 4; ++m) {
        const int row = m0 + wr + m * 16 + fq * 4;
        #pragma unroll
        for (int n = 0; n < 4; ++n) {
            const int col = n0 + wc + n * 16 + fr;
            #pragma unroll
            for (int j = 0; j < 4; ++j) {
                const size_t idx = (size_t)(row + j) * N + col;
                float v = acc[m][n][j];
                if (mode == 2) {
                    const float sg = sigm(yv[idx] + bias[col]);
                    v = v + sg * (aux[idx] - v);
                }
                if (mode == 0) Cf[idx] = v;
                else           Cb[idx] = f2h(v);
            }
        }
    }
}

// ---------------- f32 SIMD GEMM (LoRA stage-2, yv/ya; mode 1 -> fp16 EW) ----------------
#define BM 64
#define BN 64
#define BK 16
__global__ __launch_bounds__(256) void gemm_f32(
    const float* __restrict__ A, const float* __restrict__ xx,
    const float* __restrict__ W, float* __restrict__ C, unsigned short* __restrict__ Cb,
    int M, int N, int K, int T, int mode, const float* __restrict__ bias)
{
    __shared__ float As[BK][BM + 4];
    __shared__ float Bs[BK][BN + 4];
    const int tid = threadIdx.x;
    const int m0 = blockIdx.x * BM;
    const int n0 = blockIdx.y * BN;
    const int lr = tid >> 2;
    const int lk = (tid & 3) << 2;
    const int tx = tid & 15;
    const int ty = tid >> 4;
    const int mrow = m0 + lr;
    const int nrow = n0 + lr;
    float acc[4][4];
    #pragma unroll
    for (int i = 0; i < 4; ++i)
        #pragma unroll
        for (int j = 0; j < 4; ++j) acc[i][j] = 0.f;

    for (int k0 = 0; k0 < K; k0 += BK) {
        const float* ap = A + (size_t)mrow * K + k0 + lk;
        float4 av = *(const float4*)ap;
        if (xx) {
            const int t = mrow % T;
            float4 pv = make_float4(0.f, 0.f, 0.f, 0.f);
            if (t > 0) pv = *(const float4*)(ap - K);
            const float4 xv = *(const float4*)(xx + k0 + lk);
            av.x += (pv.x - av.x) * xv.x;
            av.y += (pv.y - av.y) * xv.y;
            av.z += (pv.z - av.z) * xv.z;
            av.w += (pv.w - av.w) * xv.w;
        }
        float4 bv = make_float4(0.f, 0.f, 0.f, 0.f);
        if (nrow < N) bv = *(const float4*)(W + (size_t)nrow * K + k0 + lk);

        As[lk + 0][lr] = av.x; As[lk + 1][lr] = av.y;
        As[lk + 2][lr] = av.z; As[lk + 3][lr] = av.w;
        Bs[lk + 0][lr] = bv.x; Bs[lk + 1][lr] = bv.y;
        Bs[lk + 2][lr] = bv.z; Bs[lk + 3][lr] = bv.w;
        __syncthreads();

        #pragma unroll
        for (int kk = 0; kk < BK; ++kk) {
            const float4 a4 = *(const float4*)&As[kk][ty << 2];
            const float4 b4 = *(const float4*)&Bs[kk][tx << 2];
            const float a[4] = {a4.x, a4.y, a4.z, a4.w};
            const float b[4] = {b4.x, b4.y, b4.z, b4.w};
            #pragma unroll
            for (int i = 0; i < 4; ++i)
                #pragma unroll
                for (int j = 0; j < 4; ++j)
                    acc[i][j] = fmaf(a[i], b[j], acc[i][j]);
        }
        __syncthreads();
    }
    #pragma unroll
    for (int i = 0; i < 4; ++i) {
        const int m = m0 + (ty << 2) + i;
        #pragma unroll
        for (int j = 0; j < 4; ++j) {
            const int n = n0 + (tx << 2) + j;
            if (n < N) {
                const size_t idx = (size_t)m * N + n;
                float v = acc[i][j];
                if (mode == 1) Cb[idx] = f2h(0.6065306597126334f * sigm(v + bias[n]));
                else           C[idx]  = v;
            }
        }
    }
}

// ---------------- fused LoRA stage-1 (HG written fp16 directly) ------------
__global__ __launch_bounds__(256) void lora1(
    const float* __restrict__ hid, const float* __restrict__ x_x,
    const float* __restrict__ wA, const float* __restrict__ vA,
    const float* __restrict__ aA, const float* __restrict__ gA,
    float* __restrict__ HW, float* __restrict__ HV,
    float* __restrict__ HA, unsigned short* __restrict__ HG16,
    int M, int K, int T)
{
    __shared__ float As[BK][BM + 4];
    __shared__ float Bs[BK][BN + 4];
    const int y = blockIdx.y;
    const float* W; const float* xx; int act, nofs, nvalid;
    if (y == 0)      { W = wA; xx = x_x + 1 * (size_t)K; act = 1; nofs = 0;  nvalid = 64; }
    else if (y == 1) { W = vA; xx = x_x + 3 * (size_t)K; act = 0; nofs = 0;  nvalid = 16; }
    else if (y == 2) { W = aA; xx = x_x + 4 * (size_t)K; act = 0; nofs = 0;  nvalid = 64; }
    else             { W = gA + (size_t)(y - 3) * 64 * K; xx = x_x + 5 * (size_t)K; act = 2; nofs = (y - 3) * 64; nvalid = 64; }

    const int tid = threadIdx.x;
    const int m0 = blockIdx.x * BM;
    const int lr = tid >> 2;
    const int lk = (tid & 3) << 2;
    const int tx = tid & 15;
    const int ty = tid >> 4;
    const int mrow = m0 + lr;
    float acc[4][4];
    #pragma unroll
    for (int i = 0; i < 4; ++i)
        #pragma unroll
        for (int j = 0; j < 4; ++j) acc[i][j] = 0.f;

    for (int k0 = 0; k0 < K; k0 += BK) {
        const float* ap = hid + (size_t)mrow * K + k0 + lk;
        float4 av = *(const float4*)ap;
        {
            const int t = mrow % T;
            float4 pv = make_float4(0.f, 0.f, 0.f, 0.f);
            if (t > 0) pv = *(const float4*)(ap - K);
            const float4 xv = *(const float4*)(xx + k0 + lk);
            av.x += (pv.x - av.x) * xv.x;
            av.y += (pv.y - av.y) * xv.y;
            av.z += (pv.z - av.z) * xv.z;
            av.w += (pv.w - av.w) * xv.w;
        }
        float4 bv = make_float4(0.f, 0.f, 0.f, 0.f);
        if (lr < nvalid) bv = *(const float4*)(W + (size_t)lr * K + k0 + lk);

        As[lk + 0][lr] = av.x; As[lk + 1][lr] = av.y;
        As[lk + 2][lr] = av.z; As[lk + 3][lr] = av.w;
        Bs[lk + 0][lr] = bv.x; Bs[lk + 1][lr] = bv.y;
        Bs[lk + 2][lr] = bv.z; Bs[lk + 3][lr] = bv.w;
        __syncthreads();

        #pragma unroll
        for (int kk = 0; kk < BK; ++kk) {
            const float4 a4 = *(const float4*)&As[kk][ty << 2];
            const float4 b4 = *(const float4*)&Bs[kk][tx << 2];
            const float a[4] = {a4.x, a4.y, a4.z, a4.w};
            const float b[4] = {b4.x, b4.y, b4.z, b4.w};
            #pragma unroll
            for (int i = 0; i < 4; ++i)
                #pragma unroll
                for (int j = 0; j < 4; ++j)
                    acc[i][j] = fmaf(a[i], b[j], acc[i][j]);
        }
        __syncthreads();
    }
    #pragma unroll
    for (int i = 0; i < 4; ++i) {
        const int m = m0 + (ty << 2) + i;
        #pragma unroll
        for (int j = 0; j < 4; ++j) {
            const int n = (tx << 2) + j;
            if (n < nvalid) {
                float v = acc[i][j];
                if (act == 1) { HW[(size_t)m * 64 + n] = tanhf(v); }
                else if (act == 2) { HG16[(size_t)m * 128 + nofs + n] = f2h(sigm(v)); }
                else if (y == 1) { HV[(size_t)m * 16 + n] = v; }
                else { HA[(size_t)m * 64 + n] = v; }
            }
        }
    }
}

// per-(b,t,h) wave, fp16 io: a = sigmoid(ya+ab); kk = normalize(k0*k_k);
// bv = kk*a; kfinal = k0*(1+(a-1)*k_a). Reductions on VALU.
__global__ __launch_bounds__(256) void ka_epi(
    unsigned short* __restrict__ K16, const float* __restrict__ YA,
    unsigned short* __restrict__ KK16, unsigned short* __restrict__ BV16,
    const float* __restrict__ k_k, const float* __restrict__ k_a,
    const float* __restrict__ ab, int total, int H)
{
    int wid = (blockIdx.x << 2) | (threadIdx.x >> 6);
    if (wid >= total) return;
    const int l = threadIdx.x & 63;
    const int h = wid % H;
    const int ch = h * 64 + l;
    const size_t base = (size_t)wid * 64;
    const float k0 = h2f(K16[base + l]);
    const float a = sigm(YA[base + l] + ab[ch]);
    const float kkr = k0 * k_k[ch];
    const float ss = full64(kkr * kkr);
    const float inv = 1.f / fmaxf(sqrtf(ss), 1e-12f);
    const float kkn = kkr * inv;
    KK16[base + l] = f2h(kkn);
    BV16[base + l] = f2h(kkn * a);
    K16[base + l]  = f2h(k0 * fmaf(a - 1.f, k_a[ch], 1.f));
}

// DPLR scan, fp16 streams. ONE wave per block; grid = B*H*8 = 512 (2/CU).
// Block (b,h,slab): 8 v-cols. Lane l: vc=l&7, g=l>>3, owns k in [g*8,+8).
// Per step: 5 ds_read_b128 (fp16x8 each) + 1 u16; converts in PRE (off-chain).
#define SCH 16
__global__ __launch_bounds__(64) void rwkv_scan(
    const unsigned short* __restrict__ EW, const unsigned short* __restrict__ R,
    const unsigned short* __restrict__ Kf, const unsigned short* __restrict__ Vf,
    const unsigned short* __restrict__ KK, const unsigned short* __restrict__ BV,
    float* __restrict__ O, int T, int H)
{
    __shared__ unsigned short lds[2][5 * SCH * 64 + SCH * 8];

    const int blk = blockIdx.x;
    const int bh = blk & 63;               // slab-siblings 64 apart -> same XCD
    const int slab = blk >> 6;             // 0..7
    const int b = bh >> 5, h = bh & 31;
    const int l = threadIdx.x;
    const int vc = l & 7;
    const int g  = l >> 3;
    const int kb = g << 3;
    const int vb0 = slab << 3;
    const size_t step = (size_t)H * 64;
    const size_t base0 = ((size_t)b * T * H + h) * 64;

    // per gld16, lane l lands at base + l*8 ushorts = row (l>>3), col (l&7)*8 of [8][64]
    auto stage = [&](int c, int buf) {
        unsigned short* L = &lds[buf][0];
        const size_t t0 = (size_t)c * SCH;
        const unsigned short* gs[5] = {EW, R, Kf, KK, BV};
        #pragma unroll
        for (int s = 0; s < 5; ++s) {
            const unsigned short* gp = gs[s];
            #pragma unroll
            for (int j = 0; j < 2; ++j)
                gld16(L + s * SCH * 64 + j * 8 * 64,
                      gp + base0 + (t0 + j * 8 + (l >> 3)) * step + ((l & 7) << 3));
        }
        if (l < 16)
            gld16(L + 5 * SCH * 64,
                  Vf + base0 + (t0 + l) * step + vb0);
    };

    f32x2 s2[4];
    #pragma unroll
    for (int i = 0; i < 4; ++i) s2[i] = (f32x2){0.f, 0.f};

    struct P { f32x4 e[2], r[2], k[2], q[2], bb[2]; float vv; };
    P PA, PB;
    const int NCH = T / SCH;

    stage(0, 0);
    asm volatile("s_waitcnt vmcnt(0)" ::: "memory");
    __builtin_amdgcn_sched_barrier(0);

    for (int c = 0; c < NCH; ++c) {
        if (c + 1 < NCH) stage(c + 1, (c + 1) & 1);

        const unsigned short* L = &lds[c & 1][0];
        auto PRE = [&](P& pp, int tt) {
            const int o = tt * 64 + kb;
            const f16x8 eh = *(const f16x8*)(L + 0 * SCH * 64 + o);
            const f16x8 rh = *(const f16x8*)(L + 1 * SCH * 64 + o);
            const f16x8 kh = *(const f16x8*)(L + 2 * SCH * 64 + o);
            const f16x8 qh = *(const f16x8*)(L + 3 * SCH * 64 + o);
            const f16x8 bh = *(const f16x8*)(L + 4 * SCH * 64 + o);
            const unsigned short vvh = L[5 * SCH * 64 + tt * 8 + vc];
            #pragma unroll
            for (int j = 0; j < 4; ++j) {
                pp.e[0][j] = (float)eh[j];  pp.e[1][j] = (float)eh[4 + j];
                pp.r[0][j] = (float)rh[j];  pp.r[1][j] = (float)rh[4 + j];
                pp.k[0][j] = (float)kh[j];  pp.k[1][j] = (float)kh[4 + j];
                pp.q[0][j] = (float)qh[j];  pp.q[1][j] = (float)qh[4 + j];
                pp.bb[0][j] = (float)bh[j]; pp.bb[1][j] = (float)bh[4 + j];
            }
            pp.vv = h2f(vvh);
        };
        auto COMP = [&](const P& pp, int tt) {
            f32x2 sa0 = (f32x2){0.f, 0.f}, sa1 = (f32x2){0.f, 0.f};
            #pragma unroll
            for (int j = 0; j < 2; ++j) {
                const f32x2 elo = __builtin_shufflevector(pp.e[j], pp.e[j], 0, 1);
                const f32x2 ehi = __builtin_shufflevector(pp.e[j], pp.e[j], 2, 3);
                const f32x2 qlo = __builtin_shufflevector(pp.q[j], pp.q[j], 0, 1);
                const f32x2 qhi = __builtin_shufflevector(pp.q[j], pp.q[j], 2, 3);
                s2[2*j]   *= elo;
                s2[2*j+1] *= ehi;
                sa0 += qlo * s2[2*j];
                sa1 += qhi * s2[2*j+1];
            }
            const f32x2 sas = sa0 + sa1;
            float p = -(sas.x + sas.y);
            p = red32(red16(red8(p)));
            const f32x2 p2 = (f32x2){p, p};
            const f32x2 v2 = (f32x2){pp.vv, pp.vv};
            f32x2 o0 = (f32x2){0.f, 0.f}, o1 = (f32x2){0.f, 0.f};
            #pragma unroll
            for (int j = 0; j < 2; ++j) {
                const f32x2 klo = __builtin_shufflevector(pp.k[j], pp.k[j], 0, 1);
                const f32x2 khi = __builtin_shufflevector(pp.k[j], pp.k[j], 2, 3);
                const f32x2 blo = __builtin_shufflevector(pp.bb[j], pp.bb[j], 0, 1);
                const f32x2 bhi = __builtin_shufflevector(pp.bb[j], pp.bb[j], 2, 3);
                const f32x2 rlo = __builtin_shufflevector(pp.r[j], pp.r[j], 0, 1);
                const f32x2 rhi = __builtin_shufflevector(pp.r[j], pp.r[j], 2, 3);
                s2[2*j]   = blo * p2 + (klo * v2 + s2[2*j]);
                s2[2*j+1] = bhi * p2 + (khi * v2 + s2[2*j+1]);
                o0 += rlo * s2[2*j];
                o1 += rhi * s2[2*j+1];
            }
            const f32x2 os = o0 + o1;
            float oo = os.x + os.y;
            oo = red32(red16(red8(oo)));
            if (g == 0)
                O[base0 + (size_t)(c * SCH + tt) * step + vb0 + vc] = oo;
        };

        PRE(PA, 0);
        PRE(PB, 1);
        #pragma unroll
        for (int tt = 0; tt < SCH - 2; tt += 2) {
            COMP(PA, tt);     PRE(PA, tt + 2);
            COMP(PB, tt + 1); PRE(PB, tt + 3);
        }
        COMP(PA, SCH - 2);
        COMP(PB, SCH - 1);

        asm volatile("s_waitcnt vmcnt(0)" ::: "memory");
        __builtin_amdgcn_sched_barrier(0);
    }
}

// GroupNorm + bonus + precomputed g-gate; fp16 r/k/v in, fp16 ON out.
__global__ __launch_bounds__(256) void gn_bonus(
    const float* __restrict__ O, const unsigned short* __restrict__ R16,
    const unsigned short* __restrict__ K16, const unsigned short* __restrict__ V16,
    const float* __restrict__ G, const float* __restrict__ r_k,
    const float* __restrict__ gn_w, const float* __restrict__ gn_b,
    unsigned short* __restrict__ ON16, int total, int H, float eps)
{
    int wid = (blockIdx.x << 2) | (threadIdx.x >> 6);
    if (wid >= total) return;
    const int l = threadIdx.x & 63;
    const int h = wid % H;
    const int ch = h * 64 + l;
    const size_t base = (size_t)wid * 64;

    const float o = O[base + l];
    const float mu = full64(o) * (1.f / 64.f);
    const float d = o - mu;
    const float ss = full64(d * d);
    const float inv = 1.f / sqrtf(ss * (1.f / 64.f) + eps);
    float on = d * inv * gn_w[ch] + gn_b[ch];

    const float r = h2f(R16[base + l]);
    const float k = h2f(K16[base + l]);
    const float vv = h2f(V16[base + l]);
    const float p = full64(r * k * r_k[ch]);
    on = fmaf(p, vv, on);
    ON16[base + l] = f2h(on * G[base + l]);
}

extern "C" void kernel_launch(void* const* d_in, const int* in_sizes, int n_in,
                              void* d_out, int out_size, void* d_ws, size_t ws_size,
                              hipStream_t stream)
{
    const int B = 2, T = 2048, D = 2048, H = 32;
    const int M = B * T;

    const float* hid = (const float*)d_in[0];
    const float* vst = (const float*)d_in[1];
    const float* x_x = (const float*)d_in[2];
    const float* k_k = (const float*)d_in[3];
    const float* k_a = (const float*)d_in[4];
    const float* r_k = (const float*)d_in[5];
    const float* Wr  = (const float*)d_in[6];
    const float* Wk  = (const float*)d_in[7];
    const float* Wv  = (const float*)d_in[8];
    const float* Wo  = (const float*)d_in[9];
    const float* wA  = (const float*)d_in[10];
    const float* wB  = (const float*)d_in[11];
    const float* wb  = (const float*)d_in[12];
    const float* vA  = (const float*)d_in[13];
    const float* vB  = (const float*)d_in[14];
    const float* vb  = (const float*)d_in[15];
    const float* aA  = (const float*)d_in[16];
    const float* aB  = (const float*)d_in[17];
    const float* ab  = (const float*)d_in[18];
    const float* gA  = (const float*)d_in[19];
    const float* gB  = (const float*)d_in[20];
    const float* gnw = (const float*)d_in[21];
    const float* gnb = (const float*)d_in[22];
    float* out = (float*)d_out;

    const size_t NE = (size_t)M * D;   // 8,388,608
    const size_t DD = (size_t)D * D;   // 4,194,304
    const size_t need = (6 * NE + (size_t)M * 272) * sizeof(float);  // <= proven budget
    if (ws_size < need) return;

    float* W0 = (float*)d_ws;      // X2 fp16 staging -> gb hi/lo (2nd half) + ON16 (1st half)
    float* W1 = W0 + NE;           // weight hi/lo staging
    float* W2 = W1 + NE;           // R16 | K16->Kf16
    float* W3 = W2 + NE;           // yv f32 -> ya f32 -> G f32
    float* W4 = W3 + NE;           // EW16 | KK16
    float* W5 = W4 + NE;           // BV16 | V16
    float* HW = W5 + NE;
    float* HV = HW + (size_t)M * 64;
    float* HA = HV + (size_t)M * 16;
    unsigned short* HG16 = (unsigned short*)(HA + (size_t)M * 64);

    dim3 blk(256);
    const int nMix = (int)(NE / 8);
    const int nW   = (int)(DD / 8);
    const float* nf = nullptr;
    unsigned short* nb = nullptr;

    unsigned short* X2   = (unsigned short*)W0;
    unsigned short* WRK  = (unsigned short*)W1;
    unsigned short* R16  = (unsigned short*)W2;
    unsigned short* K16  = R16 + NE;
    unsigned short* EW16 = (unsigned short*)W4;
    unsigned short* KK16 = EW16 + NE;
    unsigned short* BV16 = (unsigned short*)W5;
    unsigned short* V16  = BV16 + NE;

    // ---- phase 1: fused LoRA stage-1 ----
    hipLaunchKernelGGL(lora1, dim3(M / BM, 5), blk, 0, stream,
                       hid, x_x, wA, vA, aA, gA, HW, HV, HA, HG16, M, D, T);

    // ---- phase 2: yv -> W3 ----
    hipLaunchKernelGGL(gemm_f32, dim3(M / BM, D / BN), blk, 0, stream, HV, nf, vB, W3, nb, M, D, 16, T, 0, nf);

    // ---- phase 3a: R+K batched, fp16 out ----
    hipLaunchKernelGGL(mixcvt2_h, dim3(nMix / 256), blk, 0, stream,
                       hid, x_x + 0 * (size_t)D, x_x + 2 * (size_t)D, X2, X2 + NE, T, D, nMix);
    hipLaunchKernelGGL(wsplit_h, dim3(nW / 256), blk, 0, stream, Wr, WRK, WRK + DD, nW);
    hipLaunchKernelGGL(wsplit_h, dim3(nW / 256), blk, 0, stream, Wk, WRK + 2 * DD, WRK + 3 * DD, nW);
    hipLaunchKernelGGL(gemm_h2, dim3(M / GBM, D / GBN, 2), blk, 0, stream,
                       X2, WRK, WRK + DD, nullptr, R16, M, D, D, 1, nf, nf, nf,
                       NE, 2 * DD, NE);   // Cb: z0 -> R16, z1 -> K16

    // ---- phase 3b: V (lerp epilogue), fp16 out ----
    hipLaunchKernelGGL(mixcvt_h, dim3(nMix / 256), blk, 0, stream, hid, x_x + 3 * (size_t)D, X2, T, D, nMix, 1);
    hipLaunchKernelGGL(wsplit_h, dim3(nW / 256), blk, 0, stream, Wv, WRK, WRK + DD, nW);
    hipLaunchKernelGGL(gemm_h2, dim3(M / GBM, D / GBN, 1), blk, 0, stream,
                       X2, WRK, WRK + DD, nullptr, V16, M, D, D, 2, W3, vb, vst, 0, 0, 0);

    // ---- phase 4: LoRA stage-2 (EW fp16; ya f32 -> W3, yv dead) ----
    hipLaunchKernelGGL(gemm_f32, dim3(M / BM, D / BN), blk, 0, stream, HW, nf, wB, nullptr, EW16, M, D, 64, T, 1, wb);
    hipLaunchKernelGGL(gemm_f32, dim3(M / BM, D / BN), blk, 0, stream, HA, nf, aB, W3, nb, M, D, 64, T, 0, nf);

    // ---- phase 5: ka epilogue (fp16 io) ----
    const int totalW = M * H;
    hipLaunchKernelGGL(ka_epi, dim3(totalW / 4), blk, 0, stream, K16, W3, KK16, BV16, k_k, k_a, ab, totalW, H);

    // ---- phase 6: scan -> d_out ----
    hipLaunchKernelGGL(rwkv_scan, dim3(B * H * 8), dim3(64), 0, stream, EW16, R16, K16, V16, KK16, BV16, out, T, H);

    // ---- phase 7: g-gate GEMM (HG16 @ gB hi/lo -> G in W3) + gn_bonus -> ON16 ----
    unsigned short* gbHi = X2 + NE;                 // W0 second half (X2 dead)
    unsigned short* gbLo = gbHi + (size_t)D * 128;
    hipLaunchKernelGGL(wsplit_h, dim3((D * 128 / 8) / 256), blk, 0, stream, gB, gbHi, gbLo, D * 128 / 8);
    hipLaunchKernelGGL(gemm_h2, dim3(M / GBM, D / GBN, 1), blk, 0, stream,
                       HG16, gbHi, gbLo, W3, nullptr, M, D, 128, 0, nf, nf, nf, 0, 0, 0);
    unsigned short* ON16 = (unsigned short*)W0;     // W0 first half
    hipLaunchKernelGGL(gn_bonus, dim3(totalW / 4), blk, 0, stream, out, R16, K16, V16, W3, r_k, gnw, gnb, ON16, totalW, H, 64.f * 1e-5f);

    // ---- phase 8: Wo projection -> d_out (f32) ----
    hipLaunchKernelGGL(wsplit_h, dim3(nW / 256), blk, 0, stream, Wo, WRK, WRK + DD, nW);
    hipLaunchKernelGGL(gemm_h2, dim3(M / GBM, D / GBN, 1), blk, 0, stream,
                       ON16, WRK, WRK + DD, out, nullptr, M, D, D, 0, nf, nf, nf, 0, 0, 0);
}

// Round 17
// 1005.134 us; speedup vs baseline: 1.1489x; 1.1489x over previous
//
#include <hip/hip_runtime.h>
#include <hip/hip_bf16.h>
#include <math.h>

// RWKV7 attention, round 17 (= round 15 + single-term fp16 for R/K/V GEMMs):
//  - Scan and all streams reverted to round-15 (f32 streams; fp16 LDS regressed in r16).
//  - gemm_h2 templated on TERMS: R/K and V dispatches use TERMS=1 (A fp16 x Wh fp16,
//    lo term dropped; half the MFMAs, no Bl staging); g-gate and Wo keep TERMS=2.

typedef __attribute__((ext_vector_type(8))) unsigned short ushort8;
typedef __attribute__((ext_vector_type(8))) _Float16 f16x8;
typedef __attribute__((ext_vector_type(4))) float f32x4;
typedef __attribute__((ext_vector_type(2))) float f32x2;

__device__ inline unsigned short f2h(float f) {
    _Float16 h = (_Float16)f;
    return __builtin_bit_cast(unsigned short, h);
}
__device__ inline float h2f(unsigned short u) {
    return (float)__builtin_bit_cast(_Float16, u);
}
__device__ inline float sigm(float x) { return 1.f / (1.f + expf(-x)); }

// ---- VALU cross-lane reductions (DPP rotates + permlane swaps; distinct-reg rule from r9) ----
template <int CTRL>
__device__ __forceinline__ float rrot(float x) {
    int xi = __builtin_bit_cast(int, x);
    int yi = __builtin_amdgcn_update_dpp(xi, xi, CTRL, 0xf, 0xf, true);
    return x + __builtin_bit_cast(float, yi);
}
__device__ __forceinline__ float red8(float x)  { return rrot<0x128>(x); }
__device__ __forceinline__ float red16(float x) {
    float b = x;
    asm("" : "+v"(b));
    float a = x;
    asm("v_permlane16_swap_b32 %0, %1" : "+v"(a), "+v"(b));
    return a + b;
}
__device__ __forceinline__ float red32(float x) {
    float b = x;
    asm("" : "+v"(b));
    float a = x;
    asm("v_permlane32_swap_b32 %0, %1" : "+v"(a), "+v"(b));
    return a + b;
}
__device__ __forceinline__ float full64(float x) {
    x = rrot<0x121>(x);
    x = rrot<0x122>(x);
    x = rrot<0x124>(x);
    x = rrot<0x128>(x);
    return red32(red16(x));
}

// async global -> LDS. LDS dest = uniform base + lane*size.
__device__ __forceinline__ void gld16(void* lds, const void* g)
{
    __builtin_amdgcn_global_load_lds(
        (const __attribute__((address_space(1))) void*)g,
        (__attribute__((address_space(3))) void*)lds, 16, 0, 0);
}
__device__ __forceinline__ void gld4(void* lds, const void* g)
{
    __builtin_amdgcn_global_load_lds(
        (const __attribute__((address_space(1))) void*)g,
        (__attribute__((address_space(3))) void*)lds, 4, 0, 0);
}

// ---------------- mix (optional) + convert to single fp16 ----------------
__global__ void mixcvt_h(const float* __restrict__ in, const float* __restrict__ xxr,
                         unsigned short* __restrict__ o16, int T, int D, int total8, int domix)
{
    int i = blockIdx.x * 256 + threadIdx.x;
    if (i >= total8) return;
    const size_t e = (size_t)i * 8;
    float a[8];
    *(float4*)&a[0] = *(const float4*)(in + e);
    *(float4*)&a[4] = *(const float4*)(in + e + 4);
    if (domix) {
        const int m = (int)(e / D);
        const int d = (int)(e % D);
        const int t = m % T;
        float p[8] = {0.f,0.f,0.f,0.f,0.f,0.f,0.f,0.f};
        if (t > 0) {
            *(float4*)&p[0] = *(const float4*)(in + e - D);
            *(float4*)&p[4] = *(const float4*)(in + e - D + 4);
        }
        float xv[8];
        *(float4*)&xv[0] = *(const float4*)(xxr + d);
        *(float4*)&xv[4] = *(const float4*)(xxr + d + 4);
        #pragma unroll
        for (int j = 0; j < 8; ++j) a[j] += (p[j] - a[j]) * xv[j];
    }
    ushort8 o;
    #pragma unroll
    for (int j = 0; j < 8; ++j) o[j] = f2h(a[j]);
    *(ushort8*)(o16 + e) = o;
}

// two mixes in one pass (hid/prev read once)
__global__ void mixcvt2_h(const float* __restrict__ in,
                          const float* __restrict__ xx0, const float* __restrict__ xx1,
                          unsigned short* __restrict__ o0, unsigned short* __restrict__ o1,
                          int T, int D, int total8)
{
    int i = blockIdx.x * 256 + threadIdx.x;
    if (i >= total8) return;
    const size_t e = (size_t)i * 8;
    float a[8];
    *(float4*)&a[0] = *(const float4*)(in + e);
    *(float4*)&a[4] = *(const float4*)(in + e + 4);
    const int m = (int)(e / D);
    const int d = (int)(e % D);
    const int t = m % T;
    float p[8] = {0.f,0.f,0.f,0.f,0.f,0.f,0.f,0.f};
    if (t > 0) {
        *(float4*)&p[0] = *(const float4*)(in + e - D);
        *(float4*)&p[4] = *(const float4*)(in + e - D + 4);
    }
    float x0[8], x1[8];
    *(float4*)&x0[0] = *(const float4*)(xx0 + d);
    *(float4*)&x0[4] = *(const float4*)(xx0 + d + 4);
    *(float4*)&x1[0] = *(const float4*)(xx1 + d);
    *(float4*)&x1[4] = *(const float4*)(xx1 + d + 4);
    ushort8 r0, r1;
    #pragma unroll
    for (int j = 0; j < 8; ++j) {
        r0[j] = f2h(a[j] + (p[j] - a[j]) * x0[j]);
        r1[j] = f2h(a[j] + (p[j] - a[j]) * x1[j]);
    }
    *(ushort8*)(o0 + e) = r0;
    *(ushort8*)(o1 + e) = r1;
}

// ---------------- weight split: hi = fp16(w), lo = fp16(w - hi) ----------------
__global__ void wsplit_h(const float* __restrict__ in,
                         unsigned short* __restrict__ hi, unsigned short* __restrict__ lo,
                         int total8)
{
    int i = blockIdx.x * 256 + threadIdx.x;
    if (i >= total8) return;
    const size_t e = (size_t)i * 8;
    float a[8];
    *(float4*)&a[0] = *(const float4*)(in + e);
    *(float4*)&a[4] = *(const float4*)(in + e + 4);
    ushort8 h8, l8;
    #pragma unroll
    for (int j = 0; j < 8; ++j) {
        const unsigned short h = f2h(a[j]);
        h8[j] = h;
        l8[j] = f2h(a[j] - h2f(h));
    }
    *(ushort8*)(hi + e) = h8;
    *(ushort8*)(lo + e) = l8;
}

// weight convert, hi only (for TERMS=1 GEMMs)
__global__ void wcvt_h(const float* __restrict__ in,
                       unsigned short* __restrict__ hi, int total8)
{
    int i = blockIdx.x * 256 + threadIdx.x;
    if (i >= total8) return;
    const size_t e = (size_t)i * 8;
    float a[8];
    *(float4*)&a[0] = *(const float4*)(in + e);
    *(float4*)&a[4] = *(const float4*)(in + e + 4);
    ushort8 h8;
    #pragma unroll
    for (int j = 0; j < 8; ++j) h8[j] = f2h(a[j]);
    *(ushort8*)(hi + e) = h8;
}

// ---------------- fp16 MFMA GEMM: C[M,N] = A[M,K] @ W[N,K]^T, f32 out ----------
// A single fp16; W hi (+lo if TERMS==2). blockIdx.z strides A/B/C by sA/sB/sC.
// mode 0: C = acc ; mode 2: C = lerp(acc, aux, sigmoid(yv + bias[col]))
#define GBM 128
#define GBN 128

template <int TERMS>
__global__ __launch_bounds__(256) void gemm_h2(
    const unsigned short* __restrict__ Ag,
    const unsigned short* __restrict__ Bhg, const unsigned short* __restrict__ Blg,
    float* __restrict__ C, int M, int N, int K, int mode,
    const float* __restrict__ yv, const float* __restrict__ bias,
    const float* __restrict__ aux,
    size_t sA, size_t sB, size_t sC)
{
    __shared__ unsigned short As[GBM * 32];
    __shared__ unsigned short Bhs[GBN * 32], Bls[GBN * 32];
    const int z = blockIdx.z;
    Ag  += (size_t)z * sA;
    Bhg += (size_t)z * sB;
    Blg += (size_t)z * sB;
    C   += (size_t)z * sC;
    const int tid = threadIdx.x;
    const int m0 = blockIdx.x * GBM;
    const int n0 = blockIdx.y * GBN;
    const int wave = tid >> 6, lane = tid & 63;
    const int wr = (wave >> 1) * 64, wc = (wave & 1) * 64;
    const int fr = lane & 15, fq = lane >> 4;

    f32x4 acc[4][4];
    #pragma unroll
    for (int i = 0; i < 4; ++i)
        #pragma unroll
        for (int j = 0; j < 4; ++j)
            acc[i][j] = (f32x4){0.f, 0.f, 0.f, 0.f};

    // staging: wave0/1 -> A halves, wave2 -> Bh, wave3 -> Bl (idle if TERMS==1)
    const unsigned short* gsrc;
    unsigned short* lbuf;
    int rofs, nld;
    if (wave == 0)      { gsrc = Ag;  lbuf = As;           rofs = m0;      nld = 4; }
    else if (wave == 1) { gsrc = Ag;  lbuf = As + 64 * 32; rofs = m0 + 64; nld = 4; }
    else if (wave == 2) { gsrc = Bhg; lbuf = Bhs;          rofs = n0;      nld = 8; }
    else                { gsrc = Blg; lbuf = Bls;          rofs = n0;      nld = (TERMS == 2) ? 8 : 0; }
    const unsigned short* gbase = gsrc + (size_t)(rofs + (lane >> 2)) * K + ((lane & 3) << 3);

    for (int k0 = 0; k0 < K; k0 += 32) {
        #pragma unroll
        for (int j = 0; j < 8; ++j)
            if (j < nld)
                gld16(lbuf + j * 16 * 32, gbase + (size_t)(j * 16) * K + k0);
        __syncthreads();

        f16x8 fa[4], fbh[4], fbl[4];
        #pragma unroll
        for (int m = 0; m < 4; ++m)
            fa[m] = *(const f16x8*)&As[(wr + m * 16 + fr) * 32 + fq * 8];
        #pragma unroll
        for (int n = 0; n < 4; ++n) {
            fbh[n] = *(const f16x8*)&Bhs[(wc + n * 16 + fr) * 32 + fq * 8];
            if constexpr (TERMS == 2)
                fbl[n] = *(const f16x8*)&Bls[(wc + n * 16 + fr) * 32 + fq * 8];
        }
        #pragma unroll
        for (int m = 0; m < 4; ++m)
            #pragma unroll
            for (int n = 0; n < 4; ++n) {
                acc[m][n] = __builtin_amdgcn_mfma_f32_16x16x32_f16(fa[m], fbh[n], acc[m][n], 0, 0, 0);
                if constexpr (TERMS == 2)
                    acc[m][n] = __builtin_amdgcn_mfma_f32_16x16x32_f16(fa[m], fbl[n], acc[m][n], 0, 0, 0);
            }
        __syncthreads();
    }

    #pragma unroll
    for (int m = 0; m < 4; ++m) {
        const int row = m0 + wr + m * 16 + fq * 4;
        #pragma unroll
        for (int n = 0; n < 4; ++n) {
            const int col = n0 + wc + n * 16 + fr;
            #pragma unroll
            for (int j = 0; j < 4; ++j) {
                const size_t idx = (size_t)(row + j) * N + col;
                float v = acc[m][n][j];
                if (mode == 2) {
                    const float sg = sigm(yv[idx] + bias[col]);
                    v = v + sg * (aux[idx] - v);
                }
                C[idx] = v;
            }
        }
    }
}

// ---------------- f32 SIMD GEMM (LoRA stage-2, yv, g-gate) ----------------
#define BM 64
#define BN 64
#define BK 16
__global__ __launch_bounds__(256) void gemm_f32(
    const float* __restrict__ A, const float* __restrict__ xx,
    const float* __restrict__ W, float* __restrict__ C,
    int M, int N, int K, int T, int mode, const float* __restrict__ bias)
{
    __shared__ float As[BK][BM + 4];
    __shared__ float Bs[BK][BN + 4];
    const int tid = threadIdx.x;
    const int m0 = blockIdx.x * BM;
    const int n0 = blockIdx.y * BN;
    const int lr = tid >> 2;
    const int lk = (tid & 3) << 2;
    const int tx = tid & 15;
    const int ty = tid >> 4;
    const int mrow = m0 + lr;
    const int nrow = n0 + lr;
    float acc[4][4];
    #pragma unroll
    for (int i = 0; i < 4; ++i)
        #pragma unroll
        for (int j = 0; j < 4; ++j) acc[i][j] = 0.f;

    for (int k0 = 0; k0 < K; k0 += BK) {
        const float* ap = A + (size_t)mrow * K + k0 + lk;
        float4 av = *(const float4*)ap;
        if (xx) {
            const int t = mrow % T;
            float4 pv = make_float4(0.f, 0.f, 0.f, 0.f);
            if (t > 0) pv = *(const float4*)(ap - K);
            const float4 xv = *(const float4*)(xx + k0 + lk);
            av.x += (pv.x - av.x) * xv.x;
            av.y += (pv.y - av.y) * xv.y;
            av.z += (pv.z - av.z) * xv.z;
            av.w += (pv.w - av.w) * xv.w;
        }
        float4 bv = make_float4(0.f, 0.f, 0.f, 0.f);
        if (nrow < N) bv = *(const float4*)(W + (size_t)nrow * K + k0 + lk);

        As[lk + 0][lr] = av.x; As[lk + 1][lr] = av.y;
        As[lk + 2][lr] = av.z; As[lk + 3][lr] = av.w;
        Bs[lk + 0][lr] = bv.x; Bs[lk + 1][lr] = bv.y;
        Bs[lk + 2][lr] = bv.z; Bs[lk + 3][lr] = bv.w;
        __syncthreads();

        #pragma unroll
        for (int kk = 0; kk < BK; ++kk) {
            const float4 a4 = *(const float4*)&As[kk][ty << 2];
            const float4 b4 = *(const float4*)&Bs[kk][tx << 2];
            const float a[4] = {a4.x, a4.y, a4.z, a4.w};
            const float b[4] = {b4.x, b4.y, b4.z, b4.w};
            #pragma unroll
            for (int i = 0; i < 4; ++i)
                #pragma unroll
                for (int j = 0; j < 4; ++j)
                    acc[i][j] = fmaf(a[i], b[j], acc[i][j]);
        }
        __syncthreads();
    }
    #pragma unroll
    for (int i = 0; i < 4; ++i) {
        const int m = m0 + (ty << 2) + i;
        #pragma unroll
        for (int j = 0; j < 4; ++j) {
            const int n = n0 + (tx << 2) + j;
            if (n < N) {
                const size_t idx = (size_t)m * N + n;
                float v = acc[i][j];
                if (mode == 1) v = 0.6065306597126334f * sigm(v + bias[n]);
                C[idx] = v;
            }
        }
    }
}

// ---------------- fused LoRA stage-1: 4 GEMMs in one launch, act in epilogue ------------
__global__ __launch_bounds__(256) void lora1(
    const float* __restrict__ hid, const float* __restrict__ x_x,
    const float* __restrict__ wA, const float* __restrict__ vA,
    const float* __restrict__ aA, const float* __restrict__ gA,
    float* __restrict__ HW, float* __restrict__ HV,
    float* __restrict__ HA, float* __restrict__ HG,
    int M, int K, int T)
{
    __shared__ float As[BK][BM + 4];
    __shared__ float Bs[BK][BN + 4];
    const int y = blockIdx.y;
    const float* W; const float* xx; float* C; int NL, act, nofs, nvalid;
    if (y == 0)      { W = wA; xx = x_x + 1 * (size_t)K; C = HW; NL = 64;  act = 1; nofs = 0;  nvalid = 64; }
    else if (y == 1) { W = vA; xx = x_x + 3 * (size_t)K; C = HV; NL = 16;  act = 0; nofs = 0;  nvalid = 16; }
    else if (y == 2) { W = aA; xx = x_x + 4 * (size_t)K; C = HA; NL = 64;  act = 0; nofs = 0;  nvalid = 64; }
    else             { W = gA + (size_t)(y - 3) * 64 * K; xx = x_x + 5 * (size_t)K; C = HG; NL = 128; act = 2; nofs = (y - 3) * 64; nvalid = 64; }

    const int tid = threadIdx.x;
    const int m0 = blockIdx.x * BM;
    const int lr = tid >> 2;
    const int lk = (tid & 3) << 2;
    const int tx = tid & 15;
    const int ty = tid >> 4;
    const int mrow = m0 + lr;
    float acc[4][4];
    #pragma unroll
    for (int i = 0; i < 4; ++i)
        #pragma unroll
        for (int j = 0; j < 4; ++j) acc[i][j] = 0.f;

    for (int k0 = 0; k0 < K; k0 += BK) {
        const float* ap = hid + (size_t)mrow * K + k0 + lk;
        float4 av = *(const float4*)ap;
        {
            const int t = mrow % T;
            float4 pv = make_float4(0.f, 0.f, 0.f, 0.f);
            if (t > 0) pv = *(const float4*)(ap - K);
            const float4 xv = *(const float4*)(xx + k0 + lk);
            av.x += (pv.x - av.x) * xv.x;
            av.y += (pv.y - av.y) * xv.y;
            av.z += (pv.z - av.z) * xv.z;
            av.w += (pv.w - av.w) * xv.w;
        }
        float4 bv = make_float4(0.f, 0.f, 0.f, 0.f);
        if (lr < nvalid) bv = *(const float4*)(W + (size_t)lr * K + k0 + lk);

        As[lk + 0][lr] = av.x; As[lk + 1][lr] = av.y;
        As[lk + 2][lr] = av.z; As[lk + 3][lr] = av.w;
        Bs[lk + 0][lr] = bv.x; Bs[lk + 1][lr] = bv.y;
        Bs[lk + 2][lr] = bv.z; Bs[lk + 3][lr] = bv.w;
        __syncthreads();

        #pragma unroll
        for (int kk = 0; kk < BK; ++kk) {
            const float4 a4 = *(const float4*)&As[kk][ty << 2];
            const float4 b4 = *(const float4*)&Bs[kk][tx << 2];
            const float a[4] = {a4.x, a4.y, a4.z, a4.w};
            const float b[4] = {b4.x, b4.y, b4.z, b4.w};
            #pragma unroll
            for (int i = 0; i < 4; ++i)
                #pragma unroll
                for (int j = 0; j < 4; ++j)
                    acc[i][j] = fmaf(a[i], b[j], acc[i][j]);
        }
        __syncthreads();
    }
    #pragma unroll
    for (int i = 0; i < 4; ++i) {
        const int m = m0 + (ty << 2) + i;
        #pragma unroll
        for (int j = 0; j < 4; ++j) {
            const int n = (tx << 2) + j;
            if (n < nvalid) {
                float v = acc[i][j];
                if (act == 1) v = tanhf(v);
                else if (act == 2) v = sigm(v);
                C[(size_t)m * NL + nofs + n] = v;
            }
        }
    }
}

// per-(b,t,h) wave: a = sigmoid(ya+ab); kk = normalize(k0*k_k); bv = kk*a;
// kfinal = k0*(1+(a-1)*k_a).  Reduction on VALU (no DS).
__global__ __launch_bounds__(256) void ka_epi(
    float* __restrict__ Kf, float* __restrict__ A_BV, float* __restrict__ KKo,
    const float* __restrict__ k_k, const float* __restrict__ k_a,
    const float* __restrict__ ab, int total, int H)
{
    int wid = (blockIdx.x << 2) | (threadIdx.x >> 6);
    if (wid >= total) return;
    const int l = threadIdx.x & 63;
    const int h = wid % H;
    const int ch = h * 64 + l;
    const size_t base = (size_t)wid * 64;
    float k0 = Kf[base + l];
    float a = sigm(A_BV[base + l] + ab[ch]);
    float kkr = k0 * k_k[ch];
    float ss = full64(kkr * kkr);
    float inv = 1.f / fmaxf(sqrtf(ss), 1e-12f);
    float kkn = kkr * inv;
    KKo[base + l] = kkn;
    A_BV[base + l] = kkn * a;
    Kf[base + l] = k0 * fmaf(a - 1.f, k_a[ch], 1.f);
}

// DPLR scan (round-12/15 proven config). ONE wave per block; grid = B*H*8 = 512.
// Block (b,h,slab): 8 v-cols. Lane l: vc = l&7, g = l>>3, owns k in [g*8,+8).
// Chunks (SCH=16) staged via global_load_lds; reductions red8+red16+red32 (VALU).
#define SCH 16
__global__ __launch_bounds__(64) void rwkv_scan(
    const float* __restrict__ EW, const float* __restrict__ R,
    const float* __restrict__ Kf, const float* __restrict__ Vf,
    const float* __restrict__ KK, const float* __restrict__ BV,
    float* __restrict__ O, int T, int H)
{
    __shared__ float lds[2][5 * SCH * 64 + SCH * 8];

    const int blk = blockIdx.x;
    const int bh = blk & 63;               // slab-siblings 64 apart -> same XCD
    const int slab = blk >> 6;             // 0..7
    const int b = bh >> 5, h = bh & 31;
    const int l = threadIdx.x;
    const int vc = l & 7;
    const int g  = l >> 3;
    const int kb = g << 3;
    const int vb0 = slab << 3;
    const size_t step = (size_t)H * 64;
    const size_t base0 = ((size_t)b * T * H + h) * 64;

    auto stage = [&](int c, int buf) {
        float* L = &lds[buf][0];
        const size_t t0 = (size_t)c * SCH;
        const float* gs[5] = {EW, R, Kf, KK, BV};
        #pragma unroll
        for (int s = 0; s < 5; ++s) {
            const float* gp = gs[s];
            #pragma unroll
            for (int j = 0; j < 4; ++j)
                gld16(L + s * SCH * 64 + j * 4 * 64,
                      gp + base0 + (t0 + j * 4 + (l >> 4)) * step + ((l & 15) << 2));
        }
        gld4(L + 5 * SCH * 64,
             Vf + base0 + (t0 + (l >> 3)) * step + vb0 + (l & 7));
        gld4(L + 5 * SCH * 64 + 64,
             Vf + base0 + (t0 + 8 + (l >> 3)) * step + vb0 + (l & 7));
    };

    f32x2 s2[4];
    #pragma unroll
    for (int i = 0; i < 4; ++i) s2[i] = (f32x2){0.f, 0.f};

    struct P { f32x4 e[2], r[2], k[2], q[2], bb[2]; float vv; };
    P PA, PB;
    const int NCH = T / SCH;

    stage(0, 0);
    asm volatile("s_waitcnt vmcnt(0)" ::: "memory");
    __builtin_amdgcn_sched_barrier(0);

    for (int c = 0; c < NCH; ++c) {
        if (c + 1 < NCH) stage(c + 1, (c + 1) & 1);

        const float* L = &lds[c & 1][0];
        auto PRE = [&](P& pp, int tt) {
            const int o = tt * 64 + kb;
            #pragma unroll
            for (int j = 0; j < 2; ++j) {
                pp.e[j]  = *(const f32x4*)(L + 0 * SCH * 64 + o + j * 4);
                pp.r[j]  = *(const f32x4*)(L + 1 * SCH * 64 + o + j * 4);
                pp.k[j]  = *(const f32x4*)(L + 2 * SCH * 64 + o + j * 4);
                pp.q[j]  = *(const f32x4*)(L + 3 * SCH * 64 + o + j * 4);
                pp.bb[j] = *(const f32x4*)(L + 4 * SCH * 64 + o + j * 4);
            }
            pp.vv = L[5 * SCH * 64 + tt * 8 + vc];
        };
        auto COMP = [&](const P& pp, int tt) {
            f32x2 sa0 = (f32x2){0.f, 0.f}, sa1 = (f32x2){0.f, 0.f};
            #pragma unroll
            for (int j = 0; j < 2; ++j) {
                const f32x2 elo = __builtin_shufflevector(pp.e[j], pp.e[j], 0, 1);
                const f32x2 ehi = __builtin_shufflevector(pp.e[j], pp.e[j], 2, 3);
                const f32x2 qlo = __builtin_shufflevector(pp.q[j], pp.q[j], 0, 1);
                const f32x2 qhi = __builtin_shufflevector(pp.q[j], pp.q[j], 2, 3);
                s2[2*j]   *= elo;
                s2[2*j+1] *= ehi;
                sa0 += qlo * s2[2*j];
                sa1 += qhi * s2[2*j+1];
            }
            const f32x2 sas = sa0 + sa1;
            float p = -(sas.x + sas.y);
            p = red32(red16(red8(p)));
            const f32x2 p2 = (f32x2){p, p};
            const f32x2 v2 = (f32x2){pp.vv, pp.vv};
            f32x2 o0 = (f32x2){0.f, 0.f}, o1 = (f32x2){0.f, 0.f};
            #pragma unroll
            for (int j = 0; j < 2; ++j) {
                const f32x2 klo = __builtin_shufflevector(pp.k[j], pp.k[j], 0, 1);
                const f32x2 khi = __builtin_shufflevector(pp.k[j], pp.k[j], 2, 3);
                const f32x2 blo = __builtin_shufflevector(pp.bb[j], pp.bb[j], 0, 1);
                const f32x2 bhi = __builtin_shufflevector(pp.bb[j], pp.bb[j], 2, 3);
                const f32x2 rlo = __builtin_shufflevector(pp.r[j], pp.r[j], 0, 1);
                const f32x2 rhi = __builtin_shufflevector(pp.r[j], pp.r[j], 2, 3);
                s2[2*j]   = blo * p2 + (klo * v2 + s2[2*j]);
                s2[2*j+1] = bhi * p2 + (khi * v2 + s2[2*j+1]);
                o0 += rlo * s2[2*j];
                o1 += rhi * s2[2*j+1];
            }
            const f32x2 os = o0 + o1;
            float oo = os.x + os.y;
            oo = red32(red16(red8(oo)));
            if (g == 0)
                O[base0 + (size_t)(c * SCH + tt) * step + vb0 + vc] = oo;
        };

        PRE(PA, 0);
        PRE(PB, 1);
        #pragma unroll
        for (int tt = 0; tt < SCH - 2; tt += 2) {
            COMP(PA, tt);     PRE(PA, tt + 2);
            COMP(PB, tt + 1); PRE(PB, tt + 3);
        }
        COMP(PA, SCH - 2);
        COMP(PB, SCH - 1);

        asm volatile("s_waitcnt vmcnt(0)" ::: "memory");
        __builtin_amdgcn_sched_barrier(0);
    }
}

// GroupNorm + bonus + precomputed g-gate. Reductions on VALU (no DS).
__global__ __launch_bounds__(256) void gn_bonus(
    const float* __restrict__ O, const float* __restrict__ R,
    const float* __restrict__ Kf, const float* __restrict__ Vf,
    const float* __restrict__ G, const float* __restrict__ r_k,
    const float* __restrict__ gn_w, const float* __restrict__ gn_b,
    float* __restrict__ ON, int total, int H, float eps)
{
    int wid = (blockIdx.x << 2) | (threadIdx.x >> 6);
    if (wid >= total) return;
    const int l = threadIdx.x & 63;
    const int h = wid % H;
    const int ch = h * 64 + l;
    const size_t base = (size_t)wid * 64;

    const float o = O[base + l];
    const float mu = full64(o) * (1.f / 64.f);
    const float d = o - mu;
    const float ss = full64(d * d);
    const float inv = 1.f / sqrtf(ss * (1.f / 64.f) + eps);
    float on = d * inv * gn_w[ch] + gn_b[ch];

    const float r = R[base + l], k = Kf[base + l], vv = Vf[base + l];
    const float p = full64(r * k * r_k[ch]);
    on = fmaf(p, vv, on);
    ON[base + l] = on * G[base + l];
}

extern "C" void kernel_launch(void* const* d_in, const int* in_sizes, int n_in,
                              void* d_out, int out_size, void* d_ws, size_t ws_size,
                              hipStream_t stream)
{
    const int B = 2, T = 2048, D = 2048, H = 32;
    const int M = B * T;

    const float* hid = (const float*)d_in[0];
    const float* vst = (const float*)d_in[1];
    const float* x_x = (const float*)d_in[2];
    const float* k_k = (const float*)d_in[3];
    const float* k_a = (const float*)d_in[4];
    const float* r_k = (const float*)d_in[5];
    const float* Wr  = (const float*)d_in[6];
    const float* Wk  = (const float*)d_in[7];
    const float* Wv  = (const float*)d_in[8];
    const float* Wo  = (const float*)d_in[9];
    const float* wA  = (const float*)d_in[10];
    const float* wB  = (const float*)d_in[11];
    const float* wb  = (const float*)d_in[12];
    const float* vA  = (const float*)d_in[13];
    const float* vB  = (const float*)d_in[14];
    const float* vb  = (const float*)d_in[15];
    const float* aA  = (const float*)d_in[16];
    const float* aB  = (const float*)d_in[17];
    const float* ab  = (const float*)d_in[18];
    const float* gA  = (const float*)d_in[19];
    const float* gB  = (const float*)d_in[20];
    const float* gnw = (const float*)d_in[21];
    const float* gnb = (const float*)d_in[22];
    float* out = (float*)d_out;

    const size_t NE = (size_t)M * D;   // 8,388,608
    const size_t DD = (size_t)D * D;   // 4,194,304
    const size_t need = (6 * NE + (size_t)M * 272) * sizeof(float);  // ~196 MiB (proven)
    if (ws_size < need) return;

    float* R_  = (float*)d_ws;
    float* EW  = R_  + NE;
    float* Kf  = EW  + NE;
    float* Vf  = Kf  + NE;
    float* KK  = Vf  + NE;
    float* ABV = KK  + NE;
    float* HW  = ABV + NE;
    float* HV  = HW + (size_t)M * 64;
    float* HA  = HV + (size_t)M * 16;
    float* HG  = HA + (size_t)M * 64;

    dim3 blk(256);
    const int nMix = (int)(NE / 8);
    const int nW   = (int)(DD / 8);
    const float* nf = nullptr;

    // ---- phase 1: fused LoRA stage-1 (acts in epilogue) ----
    hipLaunchKernelGGL(lora1, dim3(M / BM, 5), blk, 0, stream,
                       hid, x_x, wA, vA, aA, gA, HW, HV, HA, HG, M, D, T);

    // ---- phase 2: yv -> ABV ----
    hipLaunchKernelGGL(gemm_f32, dim3(M / BM, D / BN), blk, 0, stream, HV, nf, vB, ABV, M, D, 16, T, 0, nf);

    // ---- phase 3a: R+K batched, single-term fp16 (one grid.z=2 dispatch) ----
    unsigned short* X2  = (unsigned short*)EW;   // [2][NE] fp16
    unsigned short* W2  = (unsigned short*)KK;   // [WrH, WkH] each DD (hi only)
    hipLaunchKernelGGL(mixcvt2_h, dim3(nMix / 256), blk, 0, stream,
                       hid, x_x + 0 * (size_t)D, x_x + 2 * (size_t)D, X2, X2 + NE, T, D, nMix);
    hipLaunchKernelGGL(wcvt_h, dim3(nW / 256), blk, 0, stream, Wr, W2, nW);
    hipLaunchKernelGGL(wcvt_h, dim3(nW / 256), blk, 0, stream, Wk, W2 + DD, nW);
    hipLaunchKernelGGL((gemm_h2<1>), dim3(M / GBM, D / GBN, 2), blk, 0, stream,
                       X2, W2, W2, R_, M, D, D, 0, nf, nf, nf,
                       NE, DD, 2 * NE);   // C: z0 -> R_, z1 -> Kf

    // ---- phase 3b: V (fused lerp epilogue), single-term ----
    hipLaunchKernelGGL(mixcvt_h, dim3(nMix / 256), blk, 0, stream, hid, x_x + 3 * (size_t)D, X2, T, D, nMix, 1);
    hipLaunchKernelGGL(wcvt_h, dim3(nW / 256), blk, 0, stream, Wv, W2, nW);
    hipLaunchKernelGGL((gemm_h2<1>), dim3(M / GBM, D / GBN, 1), blk, 0, stream,
                       X2, W2, W2, Vf, M, D, D, 2, ABV, vb, vst, 0, 0, 0);

    // ---- phase 4: LoRA stage-2 ----
    hipLaunchKernelGGL(gemm_f32, dim3(M / BM, D / BN), blk, 0, stream, HW, nf, wB, EW,  M, D, 64, T, 1, wb);
    hipLaunchKernelGGL(gemm_f32, dim3(M / BM, D / BN), blk, 0, stream, HA, nf, aB, ABV, M, D, 64, T, 0, nf);

    // ---- phase 5: ka epilogue ----
    const int totalW = M * H;
    hipLaunchKernelGGL(ka_epi, dim3(totalW / 4), blk, 0, stream, Kf, ABV, KK, k_k, k_a, ab, totalW, H);

    // ---- phase 6: scan -> d_out (512 single-wave blocks, 2/CU) ----
    hipLaunchKernelGGL(rwkv_scan, dim3(B * H * 8), dim3(64), 0, stream, EW, R_, Kf, Vf, KK, ABV, out, T, H);

    // ---- phase 7: g-gate via fp16 GEMM (TERMS=2; inputs in dead ABV window, G in KK) ----
    unsigned short* HG16 = (unsigned short*)ABV;              // M*128 shorts
    unsigned short* gbHi = HG16 + (size_t)M * 128;            // D*128 shorts
    unsigned short* gbLo = gbHi + (size_t)D * 128;
    float* G_ = KK;
    hipLaunchKernelGGL(mixcvt_h, dim3((M * 128 / 8) / 256), blk, 0, stream, HG, nf, HG16, T, D, M * 128 / 8, 0);
    hipLaunchKernelGGL(wsplit_h, dim3((D * 128 / 8) / 256), blk, 0, stream, gB, gbHi, gbLo, D * 128 / 8);
    hipLaunchKernelGGL((gemm_h2<2>), dim3(M / GBM, D / GBN, 1), blk, 0, stream,
                       HG16, gbHi, gbLo, G_, M, D, 128, 0, nf, nf, nf, 0, 0, 0);
    hipLaunchKernelGGL(gn_bonus, dim3(totalW / 4), blk, 0, stream, out, R_, Kf, Vf, G_, r_k, gnw, gnb, EW, totalW, H, 64.f * 1e-5f);

    // ---- phase 8: Wo projection -> d_out (TERMS=2) ----
    unsigned short* ON16 = (unsigned short*)KK;        // overwrites G after gn_bonus
    unsigned short* WoHi = (unsigned short*)ABV;       // overwrites HG16/gb (dead)
    unsigned short* WoLo = WoHi + DD;
    hipLaunchKernelGGL(mixcvt_h, dim3(nMix / 256), blk, 0, stream, EW, nf, ON16, T, D, nMix, 0);
    hipLaunchKernelGGL(wsplit_h, dim3(nW / 256), blk, 0, stream, Wo, WoHi, WoLo, nW);
    hipLaunchKernelGGL((gemm_h2<2>), dim3(M / GBM, D / GBN, 1), blk, 0, stream,
                       ON16, WoHi, WoLo, out, M, D, D, 0, nf, nf, nf, 0, 0, 0);
}

// Round 18
// 984.306 us; speedup vs baseline: 1.1732x; 1.0212x over previous
//
#include <hip/hip_runtime.h>
#include <hip/hip_bf16.h>
#include <math.h>

// RWKV7 attention, round 18 (= round 17 + dead-pass deletion / launch merging):
//  - lora1 writes HG as fp16 directly (g-gate mixcvt deleted; numerically identical).
//  - gn_bonus writes ON16 fp16 directly into dead EW window (Wo mixcvt deleted; identical).
//  - LoRA stage-2 (wB/aB) batched into one grid.z=2 dispatch (lora2_pair).
//  - wcvt for Wr+Wk merged into one dispatch.
// Scan / gemm_h2 / ka_epi identical to round 17 (proven 1005us, absmax 0.0039).

typedef __attribute__((ext_vector_type(8))) unsigned short ushort8;
typedef __attribute__((ext_vector_type(8))) _Float16 f16x8;
typedef __attribute__((ext_vector_type(4))) float f32x4;
typedef __attribute__((ext_vector_type(2))) float f32x2;

__device__ inline unsigned short f2h(float f) {
    _Float16 h = (_Float16)f;
    return __builtin_bit_cast(unsigned short, h);
}
__device__ inline float h2f(unsigned short u) {
    return (float)__builtin_bit_cast(_Float16, u);
}
__device__ inline float sigm(float x) { return 1.f / (1.f + expf(-x)); }

// ---- VALU cross-lane reductions (DPP rotates + permlane swaps; distinct-reg rule from r9) ----
template <int CTRL>
__device__ __forceinline__ float rrot(float x) {
    int xi = __builtin_bit_cast(int, x);
    int yi = __builtin_amdgcn_update_dpp(xi, xi, CTRL, 0xf, 0xf, true);
    return x + __builtin_bit_cast(float, yi);
}
__device__ __forceinline__ float red8(float x)  { return rrot<0x128>(x); }
__device__ __forceinline__ float red16(float x) {
    float b = x;
    asm("" : "+v"(b));
    float a = x;
    asm("v_permlane16_swap_b32 %0, %1" : "+v"(a), "+v"(b));
    return a + b;
}
__device__ __forceinline__ float red32(float x) {
    float b = x;
    asm("" : "+v"(b));
    float a = x;
    asm("v_permlane32_swap_b32 %0, %1" : "+v"(a), "+v"(b));
    return a + b;
}
__device__ __forceinline__ float full64(float x) {
    x = rrot<0x121>(x);
    x = rrot<0x122>(x);
    x = rrot<0x124>(x);
    x = rrot<0x128>(x);
    return red32(red16(x));
}

// async global -> LDS. LDS dest = uniform base + lane*size.
__device__ __forceinline__ void gld16(void* lds, const void* g)
{
    __builtin_amdgcn_global_load_lds(
        (const __attribute__((address_space(1))) void*)g,
        (__attribute__((address_space(3))) void*)lds, 16, 0, 0);
}
__device__ __forceinline__ void gld4(void* lds, const void* g)
{
    __builtin_amdgcn_global_load_lds(
        (const __attribute__((address_space(1))) void*)g,
        (__attribute__((address_space(3))) void*)lds, 4, 0, 0);
}

// ---------------- mix (optional) + convert to single fp16 ----------------
__global__ void mixcvt_h(const float* __restrict__ in, const float* __restrict__ xxr,
                         unsigned short* __restrict__ o16, int T, int D, int total8, int domix)
{
    int i = blockIdx.x * 256 + threadIdx.x;
    if (i >= total8) return;
    const size_t e = (size_t)i * 8;
    float a[8];
    *(float4*)&a[0] = *(const float4*)(in + e);
    *(float4*)&a[4] = *(const float4*)(in + e + 4);
    if (domix) {
        const int m = (int)(e / D);
        const int d = (int)(e % D);
        const int t = m % T;
        float p[8] = {0.f,0.f,0.f,0.f,0.f,0.f,0.f,0.f};
        if (t > 0) {
            *(float4*)&p[0] = *(const float4*)(in + e - D);
            *(float4*)&p[4] = *(const float4*)(in + e - D + 4);
        }
        float xv[8];
        *(float4*)&xv[0] = *(const float4*)(xxr + d);
        *(float4*)&xv[4] = *(const float4*)(xxr + d + 4);
        #pragma unroll
        for (int j = 0; j < 8; ++j) a[j] += (p[j] - a[j]) * xv[j];
    }
    ushort8 o;
    #pragma unroll
    for (int j = 0; j < 8; ++j) o[j] = f2h(a[j]);
    *(ushort8*)(o16 + e) = o;
}

// two mixes in one pass (hid/prev read once)
__global__ void mixcvt2_h(const float* __restrict__ in,
                          const float* __restrict__ xx0, const float* __restrict__ xx1,
                          unsigned short* __restrict__ o0, unsigned short* __restrict__ o1,
                          int T, int D, int total8)
{
    int i = blockIdx.x * 256 + threadIdx.x;
    if (i >= total8) return;
    const size_t e = (size_t)i * 8;
    float a[8];
    *(float4*)&a[0] = *(const float4*)(in + e);
    *(float4*)&a[4] = *(const float4*)(in + e + 4);
    const int m = (int)(e / D);
    const int d = (int)(e % D);
    const int t = m % T;
    float p[8] = {0.f,0.f,0.f,0.f,0.f,0.f,0.f,0.f};
    if (t > 0) {
        *(float4*)&p[0] = *(const float4*)(in + e - D);
        *(float4*)&p[4] = *(const float4*)(in + e - D + 4);
    }
    float x0[8], x1[8];
    *(float4*)&x0[0] = *(const float4*)(xx0 + d);
    *(float4*)&x0[4] = *(const float4*)(xx0 + d + 4);
    *(float4*)&x1[0] = *(const float4*)(xx1 + d);
    *(float4*)&x1[4] = *(const float4*)(xx1 + d + 4);
    ushort8 r0, r1;
    #pragma unroll
    for (int j = 0; j < 8; ++j) {
        r0[j] = f2h(a[j] + (p[j] - a[j]) * x0[j]);
        r1[j] = f2h(a[j] + (p[j] - a[j]) * x1[j]);
    }
    *(ushort8*)(o0 + e) = r0;
    *(ushort8*)(o1 + e) = r1;
}

// ---------------- weight split: hi = fp16(w), lo = fp16(w - hi) ----------------
__global__ void wsplit_h(const float* __restrict__ in,
                         unsigned short* __restrict__ hi, unsigned short* __restrict__ lo,
                         int total8)
{
    int i = blockIdx.x * 256 + threadIdx.x;
    if (i >= total8) return;
    const size_t e = (size_t)i * 8;
    float a[8];
    *(float4*)&a[0] = *(const float4*)(in + e);
    *(float4*)&a[4] = *(const float4*)(in + e + 4);
    ushort8 h8, l8;
    #pragma unroll
    for (int j = 0; j < 8; ++j) {
        const unsigned short h = f2h(a[j]);
        h8[j] = h;
        l8[j] = f2h(a[j] - h2f(h));
    }
    *(ushort8*)(hi + e) = h8;
    *(ushort8*)(lo + e) = l8;
}

// weight convert, hi only, two weights per launch (grid.y selects)
__global__ void wcvt2_h(const float* __restrict__ in0, const float* __restrict__ in1,
                        unsigned short* __restrict__ hi0, unsigned short* __restrict__ hi1,
                        int total8)
{
    int i = blockIdx.x * 256 + threadIdx.x;
    if (i >= total8) return;
    const float* in = (blockIdx.y == 0) ? in0 : in1;
    unsigned short* hi = (blockIdx.y == 0) ? hi0 : hi1;
    const size_t e = (size_t)i * 8;
    float a[8];
    *(float4*)&a[0] = *(const float4*)(in + e);
    *(float4*)&a[4] = *(const float4*)(in + e + 4);
    ushort8 h8;
    #pragma unroll
    for (int j = 0; j < 8; ++j) h8[j] = f2h(a[j]);
    *(ushort8*)(hi + e) = h8;
}

// ---------------- fp16 MFMA GEMM: C[M,N] = A[M,K] @ W[N,K]^T, f32 out ----------
#define GBM 128
#define GBN 128

template <int TERMS>
__global__ __launch_bounds__(256) void gemm_h2(
    const unsigned short* __restrict__ Ag,
    const unsigned short* __restrict__ Bhg, const unsigned short* __restrict__ Blg,
    float* __restrict__ C, int M, int N, int K, int mode,
    const float* __restrict__ yv, const float* __restrict__ bias,
    const float* __restrict__ aux,
    size_t sA, size_t sB, size_t sC)
{
    __shared__ unsigned short As[GBM * 32];
    __shared__ unsigned short Bhs[GBN * 32], Bls[GBN * 32];
    const int z = blockIdx.z;
    Ag  += (size_t)z * sA;
    Bhg += (size_t)z * sB;
    Blg += (size_t)z * sB;
    C   += (size_t)z * sC;
    const int tid = threadIdx.x;
    const int m0 = blockIdx.x * GBM;
    const int n0 = blockIdx.y * GBN;
    const int wave = tid >> 6, lane = tid & 63;
    const int wr = (wave >> 1) * 64, wc = (wave & 1) * 64;
    const int fr = lane & 15, fq = lane >> 4;

    f32x4 acc[4][4];
    #pragma unroll
    for (int i = 0; i < 4; ++i)
        #pragma unroll
        for (int j = 0; j < 4; ++j)
            acc[i][j] = (f32x4){0.f, 0.f, 0.f, 0.f};

    const unsigned short* gsrc;
    unsigned short* lbuf;
    int rofs, nld;
    if (wave == 0)      { gsrc = Ag;  lbuf = As;           rofs = m0;      nld = 4; }
    else if (wave == 1) { gsrc = Ag;  lbuf = As + 64 * 32; rofs = m0 + 64; nld = 4; }
    else if (wave == 2) { gsrc = Bhg; lbuf = Bhs;          rofs = n0;      nld = 8; }
    else                { gsrc = Blg; lbuf = Bls;          rofs = n0;      nld = (TERMS == 2) ? 8 : 0; }
    const unsigned short* gbase = gsrc + (size_t)(rofs + (lane >> 2)) * K + ((lane & 3) << 3);

    for (int k0 = 0; k0 < K; k0 += 32) {
        #pragma unroll
        for (int j = 0; j < 8; ++j)
            if (j < nld)
                gld16(lbuf + j * 16 * 32, gbase + (size_t)(j * 16) * K + k0);
        __syncthreads();

        f16x8 fa[4], fbh[4], fbl[4];
        #pragma unroll
        for (int m = 0; m < 4; ++m)
            fa[m] = *(const f16x8*)&As[(wr + m * 16 + fr) * 32 + fq * 8];
        #pragma unroll
        for (int n = 0; n < 4; ++n) {
            fbh[n] = *(const f16x8*)&Bhs[(wc + n * 16 + fr) * 32 + fq * 8];
            if constexpr (TERMS == 2)
                fbl[n] = *(const f16x8*)&Bls[(wc + n * 16 + fr) * 32 + fq * 8];
        }
        #pragma unroll
        for (int m = 0; m < 4; ++m)
            #pragma unroll
            for (int n = 0; n < 4; ++n) {
                acc[m][n] = __builtin_amdgcn_mfma_f32_16x16x32_f16(fa[m], fbh[n], acc[m][n], 0, 0, 0);
                if constexpr (TERMS == 2)
                    acc[m][n] = __builtin_amdgcn_mfma_f32_16x16x32_f16(fa[m], fbl[n], acc[m][n], 0, 0, 0);
            }
        __syncthreads();
    }

    #pragma unroll
    for (int m = 0; m < 4; ++m) {
        const int row = m0 + wr + m * 16 + fq * 4;
        #pragma unroll
        for (int n = 0; n < 4; ++n) {
            const int col = n0 + wc + n * 16 + fr;
            #pragma unroll
            for (int j = 0; j < 4; ++j) {
                const size_t idx = (size_t)(row + j) * N + col;
                float v = acc[m][n][j];
                if (mode == 2) {
                    const float sg = sigm(yv[idx] + bias[col]);
                    v = v + sg * (aux[idx] - v);
                }
                C[idx] = v;
            }
        }
    }
}

// ---------------- f32 SIMD GEMM (yv) ----------------
#define BM 64
#define BN 64
#define BK 16
__global__ __launch_bounds__(256) void gemm_f32(
    const float* __restrict__ A, const float* __restrict__ xx,
    const float* __restrict__ W, float* __restrict__ C,
    int M, int N, int K, int T, int mode, const float* __restrict__ bias)
{
    __shared__ float As[BK][BM + 4];
    __shared__ float Bs[BK][BN + 4];
    const int tid = threadIdx.x;
    const int m0 = blockIdx.x * BM;
    const int n0 = blockIdx.y * BN;
    const int lr = tid >> 2;
    const int lk = (tid & 3) << 2;
    const int tx = tid & 15;
    const int ty = tid >> 4;
    const int mrow = m0 + lr;
    const int nrow = n0 + lr;
    float acc[4][4];
    #pragma unroll
    for (int i = 0; i < 4; ++i)
        #pragma unroll
        for (int j = 0; j < 4; ++j) acc[i][j] = 0.f;

    for (int k0 = 0; k0 < K; k0 += BK) {
        const float* ap = A + (size_t)mrow * K + k0 + lk;
        float4 av = *(const float4*)ap;
        if (xx) {
            const int t = mrow % T;
            float4 pv = make_float4(0.f, 0.f, 0.f, 0.f);
            if (t > 0) pv = *(const float4*)(ap - K);
            const float4 xv = *(const float4*)(xx + k0 + lk);
            av.x += (pv.x - av.x) * xv.x;
            av.y += (pv.y - av.y) * xv.y;
            av.z += (pv.z - av.z) * xv.z;
            av.w += (pv.w - av.w) * xv.w;
        }
        float4 bv = make_float4(0.f, 0.f, 0.f, 0.f);
        if (nrow < N) bv = *(const float4*)(W + (size_t)nrow * K + k0 + lk);

        As[lk + 0][lr] = av.x; As[lk + 1][lr] = av.y;
        As[lk + 2][lr] = av.z; As[lk + 3][lr] = av.w;
        Bs[lk + 0][lr] = bv.x; Bs[lk + 1][lr] = bv.y;
        Bs[lk + 2][lr] = bv.z; Bs[lk + 3][lr] = bv.w;
        __syncthreads();

        #pragma unroll
        for (int kk = 0; kk < BK; ++kk) {
            const float4 a4 = *(const float4*)&As[kk][ty << 2];
            const float4 b4 = *(const float4*)&Bs[kk][tx << 2];
            const float a[4] = {a4.x, a4.y, a4.z, a4.w};
            const float b[4] = {b4.x, b4.y, b4.z, b4.w};
            #pragma unroll
            for (int i = 0; i < 4; ++i)
                #pragma unroll
                for (int j = 0; j < 4; ++j)
                    acc[i][j] = fmaf(a[i], b[j], acc[i][j]);
        }
        __syncthreads();
    }
    #pragma unroll
    for (int i = 0; i < 4; ++i) {
        const int m = m0 + (ty << 2) + i;
        #pragma unroll
        for (int j = 0; j < 4; ++j) {
            const int n = n0 + (tx << 2) + j;
            if (n < N) {
                const size_t idx = (size_t)m * N + n;
                float v = acc[i][j];
                if (mode == 1) v = 0.6065306597126334f * sigm(v + bias[n]);
                C[idx] = v;
            }
        }
    }
}

// ---------------- LoRA stage-2 pair (z=0: EW = 0.6065*sigm(HW@wB^T + wb); z=1: ya = HA@aB^T) ----
__global__ __launch_bounds__(256) void lora2_pair(
    const float* __restrict__ HW, const float* __restrict__ wBw, const float* __restrict__ wb,
    const float* __restrict__ HA, const float* __restrict__ aBw,
    float* __restrict__ EW, float* __restrict__ YA,
    int M, int N, int K)
{
    __shared__ float As[BK][BM + 4];
    __shared__ float Bs[BK][BN + 4];
    const int z = blockIdx.z;
    const float* A = (z == 0) ? HW : HA;
    const float* W = (z == 0) ? wBw : aBw;
    float* C = (z == 0) ? EW : YA;
    const int tid = threadIdx.x;
    const int m0 = blockIdx.x * BM;
    const int n0 = blockIdx.y * BN;
    const int lr = tid >> 2;
    const int lk = (tid & 3) << 2;
    const int tx = tid & 15;
    const int ty = tid >> 4;
    const int mrow = m0 + lr;
    const int nrow = n0 + lr;
    float acc[4][4];
    #pragma unroll
    for (int i = 0; i < 4; ++i)
        #pragma unroll
        for (int j = 0; j < 4; ++j) acc[i][j] = 0.f;

    for (int k0 = 0; k0 < K; k0 += BK) {
        const float* ap = A + (size_t)mrow * K + k0 + lk;
        const float4 av = *(const float4*)ap;
        float4 bv = make_float4(0.f, 0.f, 0.f, 0.f);
        if (nrow < N) bv = *(const float4*)(W + (size_t)nrow * K + k0 + lk);

        As[lk + 0][lr] = av.x; As[lk + 1][lr] = av.y;
        As[lk + 2][lr] = av.z; As[lk + 3][lr] = av.w;
        Bs[lk + 0][lr] = bv.x; Bs[lk + 1][lr] = bv.y;
        Bs[lk + 2][lr] = bv.z; Bs[lk + 3][lr] = bv.w;
        __syncthreads();

        #pragma unroll
        for (int kk = 0; kk < BK; ++kk) {
            const float4 a4 = *(const float4*)&As[kk][ty << 2];
            const float4 b4 = *(const float4*)&Bs[kk][tx << 2];
            const float a[4] = {a4.x, a4.y, a4.z, a4.w};
            const float b[4] = {b4.x, b4.y, b4.z, b4.w};
            #pragma unroll
            for (int i = 0; i < 4; ++i)
                #pragma unroll
                for (int j = 0; j < 4; ++j)
                    acc[i][j] = fmaf(a[i], b[j], acc[i][j]);
        }
        __syncthreads();
    }
    #pragma unroll
    for (int i = 0; i < 4; ++i) {
        const int m = m0 + (ty << 2) + i;
        #pragma unroll
        for (int j = 0; j < 4; ++j) {
            const int n = n0 + (tx << 2) + j;
            const size_t idx = (size_t)m * N + n;
            float v = acc[i][j];
            if (z == 0) v = 0.6065306597126334f * sigm(v + wb[n]);
            C[idx] = v;
        }
    }
}

// ---------------- fused LoRA stage-1 (HG written fp16 directly) ------------
__global__ __launch_bounds__(256) void lora1(
    const float* __restrict__ hid, const float* __restrict__ x_x,
    const float* __restrict__ wA, const float* __restrict__ vA,
    const float* __restrict__ aA, const float* __restrict__ gA,
    float* __restrict__ HW, float* __restrict__ HV,
    float* __restrict__ HA, unsigned short* __restrict__ HG16,
    int M, int K, int T)
{
    __shared__ float As[BK][BM + 4];
    __shared__ float Bs[BK][BN + 4];
    const int y = blockIdx.y;
    const float* W; const float* xx; int act, nofs, nvalid;
    if (y == 0)      { W = wA; xx = x_x + 1 * (size_t)K; act = 1; nofs = 0;  nvalid = 64; }
    else if (y == 1) { W = vA; xx = x_x + 3 * (size_t)K; act = 0; nofs = 0;  nvalid = 16; }
    else if (y == 2) { W = aA; xx = x_x + 4 * (size_t)K; act = 0; nofs = 0;  nvalid = 64; }
    else             { W = gA + (size_t)(y - 3) * 64 * K; xx = x_x + 5 * (size_t)K; act = 2; nofs = (y - 3) * 64; nvalid = 64; }

    const int tid = threadIdx.x;
    const int m0 = blockIdx.x * BM;
    const int lr = tid >> 2;
    const int lk = (tid & 3) << 2;
    const int tx = tid & 15;
    const int ty = tid >> 4;
    const int mrow = m0 + lr;
    float acc[4][4];
    #pragma unroll
    for (int i = 0; i < 4; ++i)
        #pragma unroll
        for (int j = 0; j < 4; ++j) acc[i][j] = 0.f;

    for (int k0 = 0; k0 < K; k0 += BK) {
        const float* ap = hid + (size_t)mrow * K + k0 + lk;
        float4 av = *(const float4*)ap;
        {
            const int t = mrow % T;
            float4 pv = make_float4(0.f, 0.f, 0.f, 0.f);
            if (t > 0) pv = *(const float4*)(ap - K);
            const float4 xv = *(const float4*)(xx + k0 + lk);
            av.x += (pv.x - av.x) * xv.x;
            av.y += (pv.y - av.y) * xv.y;
            av.z += (pv.z - av.z) * xv.z;
            av.w += (pv.w - av.w) * xv.w;
        }
        float4 bv = make_float4(0.f, 0.f, 0.f, 0.f);
        if (lr < nvalid) bv = *(const float4*)(W + (size_t)lr * K + k0 + lk);

        As[lk + 0][lr] = av.x; As[lk + 1][lr] = av.y;
        As[lk + 2][lr] = av.z; As[lk + 3][lr] = av.w;
        Bs[lk + 0][lr] = bv.x; Bs[lk + 1][lr] = bv.y;
        Bs[lk + 2][lr] = bv.z; Bs[lk + 3][lr] = bv.w;
        __syncthreads();

        #pragma unroll
        for (int kk = 0; kk < BK; ++kk) {
            const float4 a4 = *(const float4*)&As[kk][ty << 2];
            const float4 b4 = *(const float4*)&Bs[kk][tx << 2];
            const float a[4] = {a4.x, a4.y, a4.z, a4.w};
            const float b[4] = {b4.x, b4.y, b4.z, b4.w};
            #pragma unroll
            for (int i = 0; i < 4; ++i)
                #pragma unroll
                for (int j = 0; j < 4; ++j)
                    acc[i][j] = fmaf(a[i], b[j], acc[i][j]);
        }
        __syncthreads();
    }
    #pragma unroll
    for (int i = 0; i < 4; ++i) {
        const int m = m0 + (ty << 2) + i;
        #pragma unroll
        for (int j = 0; j < 4; ++j) {
            const int n = (tx << 2) + j;
            if (n < nvalid) {
                float v = acc[i][j];
                if (act == 1) { HW[(size_t)m * 64 + n] = tanhf(v); }
                else if (act == 2) { HG16[(size_t)m * 128 + nofs + n] = f2h(sigm(v)); }
                else if (y == 1) { HV[(size_t)m * 16 + n] = v; }
                else { HA[(size_t)m * 64 + n] = v; }
            }
        }
    }
}

// per-(b,t,h) wave: a = sigmoid(ya+ab); kk = normalize(k0*k_k); bv = kk*a;
// kfinal = k0*(1+(a-1)*k_a).  Reduction on VALU (no DS).
__global__ __launch_bounds__(256) void ka_epi(
    float* __restrict__ Kf, float* __restrict__ A_BV, float* __restrict__ KKo,
    const float* __restrict__ k_k, const float* __restrict__ k_a,
    const float* __restrict__ ab, int total, int H)
{
    int wid = (blockIdx.x << 2) | (threadIdx.x >> 6);
    if (wid >= total) return;
    const int l = threadIdx.x & 63;
    const int h = wid % H;
    const int ch = h * 64 + l;
    const size_t base = (size_t)wid * 64;
    float k0 = Kf[base + l];
    float a = sigm(A_BV[base + l] + ab[ch]);
    float kkr = k0 * k_k[ch];
    float ss = full64(kkr * kkr);
    float inv = 1.f / fmaxf(sqrtf(ss), 1e-12f);
    float kkn = kkr * inv;
    KKo[base + l] = kkn;
    A_BV[base + l] = kkn * a;
    Kf[base + l] = k0 * fmaf(a - 1.f, k_a[ch], 1.f);
}

// DPLR scan (proven config). ONE wave per block; grid = B*H*8 = 512.
#define SCH 16
__global__ __launch_bounds__(64) void rwkv_scan(
    const float* __restrict__ EW, const float* __restrict__ R,
    const float* __restrict__ Kf, const float* __restrict__ Vf,
    const float* __restrict__ KK, const float* __restrict__ BV,
    float* __restrict__ O, int T, int H)
{
    __shared__ float lds[2][5 * SCH * 64 + SCH * 8];

    const int blk = blockIdx.x;
    const int bh = blk & 63;
    const int slab = blk >> 6;
    const int b = bh >> 5, h = bh & 31;
    const int l = threadIdx.x;
    const int vc = l & 7;
    const int g  = l >> 3;
    const int kb = g << 3;
    const int vb0 = slab << 3;
    const size_t step = (size_t)H * 64;
    const size_t base0 = ((size_t)b * T * H + h) * 64;

    auto stage = [&](int c, int buf) {
        float* L = &lds[buf][0];
        const size_t t0 = (size_t)c * SCH;
        const float* gs[5] = {EW, R, Kf, KK, BV};
        #pragma unroll
        for (int s = 0; s < 5; ++s) {
            const float* gp = gs[s];
            #pragma unroll
            for (int j = 0; j < 4; ++j)
                gld16(L + s * SCH * 64 + j * 4 * 64,
                      gp + base0 + (t0 + j * 4 + (l >> 4)) * step + ((l & 15) << 2));
        }
        gld4(L + 5 * SCH * 64,
             Vf + base0 + (t0 + (l >> 3)) * step + vb0 + (l & 7));
        gld4(L + 5 * SCH * 64 + 64,
             Vf + base0 + (t0 + 8 + (l >> 3)) * step + vb0 + (l & 7));
    };

    f32x2 s2[4];
    #pragma unroll
    for (int i = 0; i < 4; ++i) s2[i] = (f32x2){0.f, 0.f};

    struct P { f32x4 e[2], r[2], k[2], q[2], bb[2]; float vv; };
    P PA, PB;
    const int NCH = T / SCH;

    stage(0, 0);
    asm volatile("s_waitcnt vmcnt(0)" ::: "memory");
    __builtin_amdgcn_sched_barrier(0);

    for (int c = 0; c < NCH; ++c) {
        if (c + 1 < NCH) stage(c + 1, (c + 1) & 1);

        const float* L = &lds[c & 1][0];
        auto PRE = [&](P& pp, int tt) {
            const int o = tt * 64 + kb;
            #pragma unroll
            for (int j = 0; j < 2; ++j) {
                pp.e[j]  = *(const f32x4*)(L + 0 * SCH * 64 + o + j * 4);
                pp.r[j]  = *(const f32x4*)(L + 1 * SCH * 64 + o + j * 4);
                pp.k[j]  = *(const f32x4*)(L + 2 * SCH * 64 + o + j * 4);
                pp.q[j]  = *(const f32x4*)(L + 3 * SCH * 64 + o + j * 4);
                pp.bb[j] = *(const f32x4*)(L + 4 * SCH * 64 + o + j * 4);
            }
            pp.vv = L[5 * SCH * 64 + tt * 8 + vc];
        };
        auto COMP = [&](const P& pp, int tt) {
            f32x2 sa0 = (f32x2){0.f, 0.f}, sa1 = (f32x2){0.f, 0.f};
            #pragma unroll
            for (int j = 0; j < 2; ++j) {
                const f32x2 elo = __builtin_shufflevector(pp.e[j], pp.e[j], 0, 1);
                const f32x2 ehi = __builtin_shufflevector(pp.e[j], pp.e[j], 2, 3);
                const f32x2 qlo = __builtin_shufflevector(pp.q[j], pp.q[j], 0, 1);
                const f32x2 qhi = __builtin_shufflevector(pp.q[j], pp.q[j], 2, 3);
                s2[2*j]   *= elo;
                s2[2*j+1] *= ehi;
                sa0 += qlo * s2[2*j];
                sa1 += qhi * s2[2*j+1];
            }
            const f32x2 sas = sa0 + sa1;
            float p = -(sas.x + sas.y);
            p = red32(red16(red8(p)));
            const f32x2 p2 = (f32x2){p, p};
            const f32x2 v2 = (f32x2){pp.vv, pp.vv};
            f32x2 o0 = (f32x2){0.f, 0.f}, o1 = (f32x2){0.f, 0.f};
            #pragma unroll
            for (int j = 0; j < 2; ++j) {
                const f32x2 klo = __builtin_shufflevector(pp.k[j], pp.k[j], 0, 1);
                const f32x2 khi = __builtin_shufflevector(pp.k[j], pp.k[j], 2, 3);
                const f32x2 blo = __builtin_shufflevector(pp.bb[j], pp.bb[j], 0, 1);
                const f32x2 bhi = __builtin_shufflevector(pp.bb[j], pp.bb[j], 2, 3);
                const f32x2 rlo = __builtin_shufflevector(pp.r[j], pp.r[j], 0, 1);
                const f32x2 rhi = __builtin_shufflevector(pp.r[j], pp.r[j], 2, 3);
                s2[2*j]   = blo * p2 + (klo * v2 + s2[2*j]);
                s2[2*j+1] = bhi * p2 + (khi * v2 + s2[2*j+1]);
                o0 += rlo * s2[2*j];
                o1 += rhi * s2[2*j+1];
            }
            const f32x2 os = o0 + o1;
            float oo = os.x + os.y;
            oo = red32(red16(red8(oo)));
            if (g == 0)
                O[base0 + (size_t)(c * SCH + tt) * step + vb0 + vc] = oo;
        };

        PRE(PA, 0);
        PRE(PB, 1);
        #pragma unroll
        for (int tt = 0; tt < SCH - 2; tt += 2) {
            COMP(PA, tt);     PRE(PA, tt + 2);
            COMP(PB, tt + 1); PRE(PB, tt + 3);
        }
        COMP(PA, SCH - 2);
        COMP(PB, SCH - 1);

        asm volatile("s_waitcnt vmcnt(0)" ::: "memory");
        __builtin_amdgcn_sched_barrier(0);
    }
}

// GroupNorm + bonus + precomputed g-gate; writes ON16 (fp16) directly.
__global__ __launch_bounds__(256) void gn_bonus(
    const float* __restrict__ O, const float* __restrict__ R,
    const float* __restrict__ Kf, const float* __restrict__ Vf,
    const float* __restrict__ G, const float* __restrict__ r_k,
    const float* __restrict__ gn_w, const float* __restrict__ gn_b,
    unsigned short* __restrict__ ON16, int total, int H, float eps)
{
    int wid = (blockIdx.x << 2) | (threadIdx.x >> 6);
    if (wid >= total) return;
    const int l = threadIdx.x & 63;
    const int h = wid % H;
    const int ch = h * 64 + l;
    const size_t base = (size_t)wid * 64;

    const float o = O[base + l];
    const float mu = full64(o) * (1.f / 64.f);
    const float d = o - mu;
    const float ss = full64(d * d);
    const float inv = 1.f / sqrtf(ss * (1.f / 64.f) + eps);
    float on = d * inv * gn_w[ch] + gn_b[ch];

    const float r = R[base + l], k = Kf[base + l], vv = Vf[base + l];
    const float p = full64(r * k * r_k[ch]);
    on = fmaf(p, vv, on);
    ON16[base + l] = f2h(on * G[base + l]);
}

extern "C" void kernel_launch(void* const* d_in, const int* in_sizes, int n_in,
                              void* d_out, int out_size, void* d_ws, size_t ws_size,
                              hipStream_t stream)
{
    const int B = 2, T = 2048, D = 2048, H = 32;
    const int M = B * T;

    const float* hid = (const float*)d_in[0];
    const float* vst = (const float*)d_in[1];
    const float* x_x = (const float*)d_in[2];
    const float* k_k = (const float*)d_in[3];
    const float* k_a = (const float*)d_in[4];
    const float* r_k = (const float*)d_in[5];
    const float* Wr  = (const float*)d_in[6];
    const float* Wk  = (const float*)d_in[7];
    const float* Wv  = (const float*)d_in[8];
    const float* Wo  = (const float*)d_in[9];
    const float* wA  = (const float*)d_in[10];
    const float* wB  = (const float*)d_in[11];
    const float* wb  = (const float*)d_in[12];
    const float* vA  = (const float*)d_in[13];
    const float* vB  = (const float*)d_in[14];
    const float* vb  = (const float*)d_in[15];
    const float* aA  = (const float*)d_in[16];
    const float* aB  = (const float*)d_in[17];
    const float* ab  = (const float*)d_in[18];
    const float* gA  = (const float*)d_in[19];
    const float* gB  = (const float*)d_in[20];
    const float* gnw = (const float*)d_in[21];
    const float* gnb = (const float*)d_in[22];
    float* out = (float*)d_out;

    const size_t NE = (size_t)M * D;   // 8,388,608
    const size_t DD = (size_t)D * D;   // 4,194,304
    const size_t need = (6 * NE + (size_t)M * 272) * sizeof(float);  // ~196 MiB (proven)
    if (ws_size < need) return;

    float* R_  = (float*)d_ws;
    float* EW  = R_  + NE;
    float* Kf  = EW  + NE;
    float* Vf  = Kf  + NE;
    float* KK  = Vf  + NE;
    float* ABV = KK  + NE;
    float* HW  = ABV + NE;
    float* HV  = HW + (size_t)M * 64;
    float* HA  = HV + (size_t)M * 16;
    unsigned short* HG16 = (unsigned short*)(HA + (size_t)M * 64);

    dim3 blk(256);
    const int nMix = (int)(NE / 8);
    const int nW   = (int)(DD / 8);
    const float* nf = nullptr;

    // ---- phase 1: fused LoRA stage-1 (acts in epilogue; HG fp16) ----
    hipLaunchKernelGGL(lora1, dim3(M / BM, 5), blk, 0, stream,
                       hid, x_x, wA, vA, aA, gA, HW, HV, HA, HG16, M, D, T);

    // ---- phase 2: yv -> ABV ----
    hipLaunchKernelGGL(gemm_f32, dim3(M / BM, D / BN), blk, 0, stream, HV, nf, vB, ABV, M, D, 16, T, 0, nf);

    // ---- phase 3a: R+K batched, single-term fp16 ----
    unsigned short* X2  = (unsigned short*)EW;   // [2][NE] fp16
    unsigned short* W2  = (unsigned short*)KK;   // [WrH, WkH] each DD (hi only)
    hipLaunchKernelGGL(mixcvt2_h, dim3(nMix / 256), blk, 0, stream,
                       hid, x_x + 0 * (size_t)D, x_x + 2 * (size_t)D, X2, X2 + NE, T, D, nMix);
    hipLaunchKernelGGL(wcvt2_h, dim3(nW / 256, 2), blk, 0, stream, Wr, Wk, W2, W2 + DD, nW);
    hipLaunchKernelGGL((gemm_h2<1>), dim3(M / GBM, D / GBN, 2), blk, 0, stream,
                       X2, W2, W2, R_, M, D, D, 0, nf, nf, nf,
                       NE, DD, 2 * NE);   // C: z0 -> R_, z1 -> Kf

    // ---- phase 3b: V (fused lerp epilogue), single-term ----
    hipLaunchKernelGGL(mixcvt_h, dim3(nMix / 256), blk, 0, stream, hid, x_x + 3 * (size_t)D, X2, T, D, nMix, 1);
    hipLaunchKernelGGL(wcvt2_h, dim3(nW / 256, 1), blk, 0, stream, Wv, Wv, W2, W2, nW);
    hipLaunchKernelGGL((gemm_h2<1>), dim3(M / GBM, D / GBN, 1), blk, 0, stream,
                       X2, W2, W2, Vf, M, D, D, 2, ABV, vb, vst, 0, 0, 0);

    // ---- phase 4: LoRA stage-2 batched (z0: EW, z1: ya -> ABV) ----
    hipLaunchKernelGGL(lora2_pair, dim3(M / BM, D / BN, 2), blk, 0, stream,
                       HW, wB, wb, HA, aB, EW, ABV, M, D, 64);

    // ---- phase 5: ka epilogue ----
    const int totalW = M * H;
    hipLaunchKernelGGL(ka_epi, dim3(totalW / 4), blk, 0, stream, Kf, ABV, KK, k_k, k_a, ab, totalW, H);

    // ---- phase 6: scan -> d_out (512 single-wave blocks, 2/CU) ----
    hipLaunchKernelGGL(rwkv_scan, dim3(B * H * 8), dim3(64), 0, stream, EW, R_, Kf, Vf, KK, ABV, out, T, H);

    // ---- phase 7: g-gate via fp16 GEMM (TERMS=2; gb staged in dead ABV window, G in KK) ----
    unsigned short* gbHi = (unsigned short*)ABV;              // D*128 shorts
    unsigned short* gbLo = gbHi + (size_t)D * 128;
    float* G_ = KK;
    hipLaunchKernelGGL(wsplit_h, dim3((D * 128 / 8) / 256), blk, 0, stream, gB, gbHi, gbLo, D * 128 / 8);
    hipLaunchKernelGGL((gemm_h2<2>), dim3(M / GBM, D / GBN, 1), blk, 0, stream,
                       HG16, gbHi, gbLo, G_, M, D, 128, 0, nf, nf, nf, 0, 0, 0);

    // gn_bonus writes ON16 directly into dead EW window
    unsigned short* ON16 = (unsigned short*)EW;
    hipLaunchKernelGGL(gn_bonus, dim3(totalW / 4), blk, 0, stream, out, R_, Kf, Vf, G_, r_k, gnw, gnb, ON16, totalW, H, 64.f * 1e-5f);

    // ---- phase 8: Wo projection -> d_out (TERMS=2) ----
    unsigned short* WoHi = (unsigned short*)ABV;       // gb dead after g-gate GEMM
    unsigned short* WoLo = WoHi + DD;
    hipLaunchKernelGGL(wsplit_h, dim3(nW / 256), blk, 0, stream, Wo, WoHi, WoLo, nW);
    hipLaunchKernelGGL((gemm_h2<2>), dim3(M / GBM, D / GBN, 1), blk, 0, stream,
                       ON16, WoHi, WoLo, out, M, D, D, 0, nf, nf, nf, 0, 0, 0);
}

// Round 19
// 918.337 us; speedup vs baseline: 1.2575x; 1.0718x over previous
//
#include <hip/hip_runtime.h>
#include <hip/hip_bf16.h>
#include <math.h>

// RWKV7 attention, round 19: LoRA stage-1/2 moved to fp16 MFMA.
//  - mixcvt4_h: w/a/g/v mixes fp16 in one pass (hid read once).
//  - wcvt_lora: LoRA-A weights zero-padded to [4][128][2048] fp16 (no OOB).
//  - lora1_h: z-batched MFMA GEMM (N-tile 128, K=2048), per-z act epilogue.
//  - LoRA stage-2 via gemm_h2<1> K=64 mode 3 (z0: EW=0.6065*sigm(+wb), z1: ya).
// Scan / ka_epi / gn_bonus / projections byte-identical to round 18 (984us, 0.0039).
//
// Window plan (W0..W5 = NE f32 each):
//  W1: X2(r,k fp16) -> yv f32 -> EW  |  W4: [w][a] fp16 -> WvH -> wB16/aB16 -> KK
//  W5: [g][v] fp16 -> YA -> BV       |  W3: WrH/WkH -> Vf  |  W0: WL pad -> R_ | W2: Kf

typedef __attribute__((ext_vector_type(8))) unsigned short ushort8;
typedef __attribute__((ext_vector_type(8))) _Float16 f16x8;
typedef __attribute__((ext_vector_type(4))) float f32x4;
typedef __attribute__((ext_vector_type(2))) float f32x2;

__device__ inline unsigned short f2h(float f) {
    _Float16 h = (_Float16)f;
    return __builtin_bit_cast(unsigned short, h);
}
__device__ inline float h2f(unsigned short u) {
    return (float)__builtin_bit_cast(_Float16, u);
}
__device__ inline float sigm(float x) { return 1.f / (1.f + expf(-x)); }

// ---- VALU cross-lane reductions (DPP rotates + permlane swaps; distinct-reg rule from r9) ----
template <int CTRL>
__device__ __forceinline__ float rrot(float x) {
    int xi = __builtin_bit_cast(int, x);
    int yi = __builtin_amdgcn_update_dpp(xi, xi, CTRL, 0xf, 0xf, true);
    return x + __builtin_bit_cast(float, yi);
}
__device__ __forceinline__ float red8(float x)  { return rrot<0x128>(x); }
__device__ __forceinline__ float red16(float x) {
    float b = x;
    asm("" : "+v"(b));
    float a = x;
    asm("v_permlane16_swap_b32 %0, %1" : "+v"(a), "+v"(b));
    return a + b;
}
__device__ __forceinline__ float red32(float x) {
    float b = x;
    asm("" : "+v"(b));
    float a = x;
    asm("v_permlane32_swap_b32 %0, %1" : "+v"(a), "+v"(b));
    return a + b;
}
__device__ __forceinline__ float full64(float x) {
    x = rrot<0x121>(x);
    x = rrot<0x122>(x);
    x = rrot<0x124>(x);
    x = rrot<0x128>(x);
    return red32(red16(x));
}

// async global -> LDS. LDS dest = uniform base + lane*size.
__device__ __forceinline__ void gld16(void* lds, const void* g)
{
    __builtin_amdgcn_global_load_lds(
        (const __attribute__((address_space(1))) void*)g,
        (__attribute__((address_space(3))) void*)lds, 16, 0, 0);
}
__device__ __forceinline__ void gld4(void* lds, const void* g)
{
    __builtin_amdgcn_global_load_lds(
        (const __attribute__((address_space(1))) void*)g,
        (__attribute__((address_space(3))) void*)lds, 4, 0, 0);
}

// ---------------- two mixes in one pass (r,k) ----------------
__global__ void mixcvt2_h(const float* __restrict__ in,
                          const float* __restrict__ xx0, const float* __restrict__ xx1,
                          unsigned short* __restrict__ o0, unsigned short* __restrict__ o1,
                          int T, int D, int total8)
{
    int i = blockIdx.x * 256 + threadIdx.x;
    if (i >= total8) return;
    const size_t e = (size_t)i * 8;
    float a[8];
    *(float4*)&a[0] = *(const float4*)(in + e);
    *(float4*)&a[4] = *(const float4*)(in + e + 4);
    const int m = (int)(e / D);
    const int d = (int)(e % D);
    const int t = m % T;
    float p[8] = {0.f,0.f,0.f,0.f,0.f,0.f,0.f,0.f};
    if (t > 0) {
        *(float4*)&p[0] = *(const float4*)(in + e - D);
        *(float4*)&p[4] = *(const float4*)(in + e - D + 4);
    }
    float x0[8], x1[8];
    *(float4*)&x0[0] = *(const float4*)(xx0 + d);
    *(float4*)&x0[4] = *(const float4*)(xx0 + d + 4);
    *(float4*)&x1[0] = *(const float4*)(xx1 + d);
    *(float4*)&x1[4] = *(const float4*)(xx1 + d + 4);
    ushort8 r0, r1;
    #pragma unroll
    for (int j = 0; j < 8; ++j) {
        r0[j] = f2h(a[j] + (p[j] - a[j]) * x0[j]);
        r1[j] = f2h(a[j] + (p[j] - a[j]) * x1[j]);
    }
    *(ushort8*)(o0 + e) = r0;
    *(ushort8*)(o1 + e) = r1;
}

// ---------------- four mixes in one pass (w,a,g,v) ----------------
__global__ void mixcvt4_h(const float* __restrict__ in, const float* __restrict__ x_x,
                          unsigned short* __restrict__ ow, unsigned short* __restrict__ oa,
                          unsigned short* __restrict__ og, unsigned short* __restrict__ ov,
                          int T, int D, int total8)
{
    int i = blockIdx.x * 256 + threadIdx.x;
    if (i >= total8) return;
    const size_t e = (size_t)i * 8;
    float a[8];
    *(float4*)&a[0] = *(const float4*)(in + e);
    *(float4*)&a[4] = *(const float4*)(in + e + 4);
    const int m = (int)(e / D);
    const int d = (int)(e % D);
    const int t = m % T;
    float p[8] = {0.f,0.f,0.f,0.f,0.f,0.f,0.f,0.f};
    if (t > 0) {
        *(float4*)&p[0] = *(const float4*)(in + e - D);
        *(float4*)&p[4] = *(const float4*)(in + e - D + 4);
    }
    const float* xxw = x_x + 1 * (size_t)D + d;
    const float* xxa = x_x + 4 * (size_t)D + d;
    const float* xxg = x_x + 5 * (size_t)D + d;
    const float* xxv = x_x + 3 * (size_t)D + d;
    ushort8 rw, ra, rg, rv;
    #pragma unroll
    for (int j = 0; j < 8; ++j) {
        const float dl = p[j] - a[j];
        rw[j] = f2h(a[j] + dl * xxw[j]);
        ra[j] = f2h(a[j] + dl * xxa[j]);
        rg[j] = f2h(a[j] + dl * xxg[j]);
        rv[j] = f2h(a[j] + dl * xxv[j]);
    }
    *(ushort8*)(ow + e) = rw;
    *(ushort8*)(oa + e) = ra;
    *(ushort8*)(og + e) = rg;
    *(ushort8*)(ov + e) = rv;
}

// ---------------- weight split: hi = fp16(w), lo = fp16(w - hi) ----------------
__global__ void wsplit_h(const float* __restrict__ in,
                         unsigned short* __restrict__ hi, unsigned short* __restrict__ lo,
                         int total8)
{
    int i = blockIdx.x * 256 + threadIdx.x;
    if (i >= total8) return;
    const size_t e = (size_t)i * 8;
    float a[8];
    *(float4*)&a[0] = *(const float4*)(in + e);
    *(float4*)&a[4] = *(const float4*)(in + e + 4);
    ushort8 h8, l8;
    #pragma unroll
    for (int j = 0; j < 8; ++j) {
        const unsigned short h = f2h(a[j]);
        h8[j] = h;
        l8[j] = f2h(a[j] - h2f(h));
    }
    *(ushort8*)(hi + e) = h8;
    *(ushort8*)(lo + e) = l8;
}

// weight convert, hi only, two weights per launch (grid.y selects)
__global__ void wcvt2_h(const float* __restrict__ in0, const float* __restrict__ in1,
                        unsigned short* __restrict__ hi0, unsigned short* __restrict__ hi1,
                        int total8)
{
    int i = blockIdx.x * 256 + threadIdx.x;
    if (i >= total8) return;
    const float* in = (blockIdx.y == 0) ? in0 : in1;
    unsigned short* hi = (blockIdx.y == 0) ? hi0 : hi1;
    const size_t e = (size_t)i * 8;
    float a[8];
    *(float4*)&a[0] = *(const float4*)(in + e);
    *(float4*)&a[4] = *(const float4*)(in + e + 4);
    ushort8 h8;
    #pragma unroll
    for (int j = 0; j < 8; ++j) h8[j] = f2h(a[j]);
    *(ushort8*)(hi + e) = h8;
}

// LoRA-A weights zero-padded to [4][128][2048] fp16 (z: 0=wA(64) 1=vA(16) 2=aA(64) 3=gA(128))
__global__ void wcvt_lora(const float* __restrict__ wA, const float* __restrict__ vA,
                          const float* __restrict__ aA, const float* __restrict__ gA,
                          unsigned short* __restrict__ WL, int K)
{
    const int z = blockIdx.y;
    int i = blockIdx.x * 256 + threadIdx.x;          // 32768 threads per z
    const size_t e = (size_t)i * 8;
    const int row = (int)(e / K);
    const int col = (int)(e % K);
    const int nv = (z == 0) ? 64 : (z == 1) ? 16 : (z == 2) ? 64 : 128;
    const float* src = (z == 0) ? wA : (z == 1) ? vA : (z == 2) ? aA : gA;
    ushort8 h8;
    if (row < nv) {
        float a[8];
        *(float4*)&a[0] = *(const float4*)(src + (size_t)row * K + col);
        *(float4*)&a[4] = *(const float4*)(src + (size_t)row * K + col + 4);
        #pragma unroll
        for (int j = 0; j < 8; ++j) h8[j] = f2h(a[j]);
    } else {
        #pragma unroll
        for (int j = 0; j < 8; ++j) h8[j] = 0;
    }
    *(ushort8*)(WL + (size_t)z * 128 * K + e) = h8;
}

// ---------------- fp16 MFMA GEMM: C[M,N] = A[M,K] @ W[N,K]^T, f32 out ----------
// mode 0: C=acc. mode 2: C=lerp(acc,aux,sigm(yv+bias)). mode 3: z0: C=0.6065*sigm(acc+bias), z1: C=acc.
#define GBM 128
#define GBN 128

template <int TERMS>
__global__ __launch_bounds__(256) void gemm_h2(
    const unsigned short* __restrict__ Ag,
    const unsigned short* __restrict__ Bhg, const unsigned short* __restrict__ Blg,
    float* __restrict__ C, int M, int N, int K, int mode,
    const float* __restrict__ yv, const float* __restrict__ bias,
    const float* __restrict__ aux,
    size_t sA, size_t sB, size_t sC)
{
    __shared__ unsigned short As[GBM * 32];
    __shared__ unsigned short Bhs[GBN * 32], Bls[GBN * 32];
    const int z = blockIdx.z;
    Ag  += (size_t)z * sA;
    Bhg += (size_t)z * sB;
    Blg += (size_t)z * sB;
    C   += (size_t)z * sC;
    const int tid = threadIdx.x;
    const int m0 = blockIdx.x * GBM;
    const int n0 = blockIdx.y * GBN;
    const int wave = tid >> 6, lane = tid & 63;
    const int wr = (wave >> 1) * 64, wc = (wave & 1) * 64;
    const int fr = lane & 15, fq = lane >> 4;

    f32x4 acc[4][4];
    #pragma unroll
    for (int i = 0; i < 4; ++i)
        #pragma unroll
        for (int j = 0; j < 4; ++j)
            acc[i][j] = (f32x4){0.f, 0.f, 0.f, 0.f};

    const unsigned short* gsrc;
    unsigned short* lbuf;
    int rofs, nld;
    if (wave == 0)      { gsrc = Ag;  lbuf = As;           rofs = m0;      nld = 4; }
    else if (wave == 1) { gsrc = Ag;  lbuf = As + 64 * 32; rofs = m0 + 64; nld = 4; }
    else if (wave == 2) { gsrc = Bhg; lbuf = Bhs;          rofs = n0;      nld = 8; }
    else                { gsrc = Blg; lbuf = Bls;          rofs = n0;      nld = (TERMS == 2) ? 8 : 0; }
    const unsigned short* gbase = gsrc + (size_t)(rofs + (lane >> 2)) * K + ((lane & 3) << 3);

    for (int k0 = 0; k0 < K; k0 += 32) {
        #pragma unroll
        for (int j = 0; j < 8; ++j)
            if (j < nld)
                gld16(lbuf + j * 16 * 32, gbase + (size_t)(j * 16) * K + k0);
        __syncthreads();

        f16x8 fa[4], fbh[4], fbl[4];
        #pragma unroll
        for (int m = 0; m < 4; ++m)
            fa[m] = *(const f16x8*)&As[(wr + m * 16 + fr) * 32 + fq * 8];
        #pragma unroll
        for (int n = 0; n < 4; ++n) {
            fbh[n] = *(const f16x8*)&Bhs[(wc + n * 16 + fr) * 32 + fq * 8];
            if constexpr (TERMS == 2)
                fbl[n] = *(const f16x8*)&Bls[(wc + n * 16 + fr) * 32 + fq * 8];
        }
        #pragma unroll
        for (int m = 0; m < 4; ++m)
            #pragma unroll
            for (int n = 0; n < 4; ++n) {
                acc[m][n] = __builtin_amdgcn_mfma_f32_16x16x32_f16(fa[m], fbh[n], acc[m][n], 0, 0, 0);
                if constexpr (TERMS == 2)
                    acc[m][n] = __builtin_amdgcn_mfma_f32_16x16x32_f16(fa[m], fbl[n], acc[m][n], 0, 0, 0);
            }
        __syncthreads();
    }

    #pragma unroll
    for (int m = 0; m < 4; ++m) {
        const int row = m0 + wr + m * 16 + fq * 4;
        #pragma unroll
        for (int n = 0; n < 4; ++n) {
            const int col = n0 + wc + n * 16 + fr;
            #pragma unroll
            for (int j = 0; j < 4; ++j) {
                const size_t idx = (size_t)(row + j) * N + col;
                float v = acc[m][n][j];
                if (mode == 2) {
                    const float sg = sigm(yv[idx] + bias[col]);
                    v = v + sg * (aux[idx] - v);
                } else if (mode == 3 && z == 0) {
                    v = 0.6065306597126334f * sigm(v + bias[col]);
                }
                C[idx] = v;
            }
        }
    }
}

// ---------------- LoRA stage-1 MFMA: z-batched, N-tile 128, per-z act epilogue ----------
__global__ __launch_bounds__(256) void lora1_h(
    const unsigned short* __restrict__ Xbase,   // [w][a][g][v] fp16, NE each
    const unsigned short* __restrict__ WL,      // [4][128][K] fp16 padded
    unsigned short* __restrict__ HW16, float* __restrict__ HV,
    unsigned short* __restrict__ HA16, unsigned short* __restrict__ HG16,
    int M, int K, size_t NE)
{
    __shared__ unsigned short As[GBM * 32];
    __shared__ unsigned short Bhs[GBN * 32];
    const int z = blockIdx.z;
    const size_t zofs = (z == 0) ? 0 : (z == 1) ? 3 * NE : (z == 2) ? NE : 2 * NE;  // w,v,a,g
    const unsigned short* Ag = Xbase + zofs;
    const unsigned short* Bg = WL + (size_t)z * 128 * K;
    const int tid = threadIdx.x;
    const int m0 = blockIdx.x * GBM;
    const int wave = tid >> 6, lane = tid & 63;
    const int wr = (wave >> 1) * 64, wc = (wave & 1) * 64;
    const int fr = lane & 15, fq = lane >> 4;

    f32x4 acc[4][4];
    #pragma unroll
    for (int i = 0; i < 4; ++i)
        #pragma unroll
        for (int j = 0; j < 4; ++j)
            acc[i][j] = (f32x4){0.f, 0.f, 0.f, 0.f};

    const unsigned short* gsrc;
    unsigned short* lbuf;
    int rofs, nld;
    if (wave == 0)      { gsrc = Ag; lbuf = As;           rofs = m0;      nld = 4; }
    else if (wave == 1) { gsrc = Ag; lbuf = As + 64 * 32; rofs = m0 + 64; nld = 4; }
    else if (wave == 2) { gsrc = Bg; lbuf = Bhs;          rofs = 0;       nld = 8; }
    else                { gsrc = Bg; lbuf = Bhs;          rofs = 0;       nld = 0; }
    const unsigned short* gbase = gsrc + (size_t)(rofs + (lane >> 2)) * K + ((lane & 3) << 3);

    for (int k0 = 0; k0 < K; k0 += 32) {
        #pragma unroll
        for (int j = 0; j < 8; ++j)
            if (j < nld)
                gld16(lbuf + j * 16 * 32, gbase + (size_t)(j * 16) * K + k0);
        __syncthreads();

        f16x8 fa[4], fb[4];
        #pragma unroll
        for (int m = 0; m < 4; ++m)
            fa[m] = *(const f16x8*)&As[(wr + m * 16 + fr) * 32 + fq * 8];
        #pragma unroll
        for (int n = 0; n < 4; ++n)
            fb[n] = *(const f16x8*)&Bhs[(wc + n * 16 + fr) * 32 + fq * 8];
        #pragma unroll
        for (int m = 0; m < 4; ++m)
            #pragma unroll
            for (int n = 0; n < 4; ++n)
                acc[m][n] = __builtin_amdgcn_mfma_f32_16x16x32_f16(fa[m], fb[n], acc[m][n], 0, 0, 0);
        __syncthreads();
    }

    #pragma unroll
    for (int m = 0; m < 4; ++m) {
        const int row = m0 + wr + m * 16 + fq * 4;
        #pragma unroll
        for (int n = 0; n < 4; ++n) {
            const int col = wc + n * 16 + fr;   // 0..127
            #pragma unroll
            for (int j = 0; j < 4; ++j) {
                const float v = acc[m][n][j];
                const int r = row + j;
                if (z == 0)      { if (col < 64) HW16[(size_t)r * 64 + col] = f2h(tanhf(v)); }
                else if (z == 1) { if (col < 16) HV[(size_t)r * 16 + col] = v; }
                else if (z == 2) { if (col < 64) HA16[(size_t)r * 64 + col] = f2h(v); }
                else             { HG16[(size_t)r * 128 + col] = f2h(sigm(v)); }
            }
        }
    }
}

// ---------------- f32 SIMD GEMM (yv only) ----------------
#define BM 64
#define BN 64
#define BK 16
__global__ __launch_bounds__(256) void gemm_f32(
    const float* __restrict__ A, const float* __restrict__ xx,
    const float* __restrict__ W, float* __restrict__ C,
    int M, int N, int K, int T, int mode, const float* __restrict__ bias)
{
    __shared__ float As[BK][BM + 4];
    __shared__ float Bs[BK][BN + 4];
    const int tid = threadIdx.x;
    const int m0 = blockIdx.x * BM;
    const int n0 = blockIdx.y * BN;
    const int lr = tid >> 2;
    const int lk = (tid & 3) << 2;
    const int tx = tid & 15;
    const int ty = tid >> 4;
    const int mrow = m0 + lr;
    const int nrow = n0 + lr;
    float acc[4][4];
    #pragma unroll
    for (int i = 0; i < 4; ++i)
        #pragma unroll
        for (int j = 0; j < 4; ++j) acc[i][j] = 0.f;

    for (int k0 = 0; k0 < K; k0 += BK) {
        const float* ap = A + (size_t)mrow * K + k0 + lk;
        float4 av = *(const float4*)ap;
        if (xx) {
            const int t = mrow % T;
            float4 pv = make_float4(0.f, 0.f, 0.f, 0.f);
            if (t > 0) pv = *(const float4*)(ap - K);
            const float4 xv = *(const float4*)(xx + k0 + lk);
            av.x += (pv.x - av.x) * xv.x;
            av.y += (pv.y - av.y) * xv.y;
            av.z += (pv.z - av.z) * xv.z;
            av.w += (pv.w - av.w) * xv.w;
        }
        float4 bv = make_float4(0.f, 0.f, 0.f, 0.f);
        if (nrow < N) bv = *(const float4*)(W + (size_t)nrow * K + k0 + lk);

        As[lk + 0][lr] = av.x; As[lk + 1][lr] = av.y;
        As[lk + 2][lr] = av.z; As[lk + 3][lr] = av.w;
        Bs[lk + 0][lr] = bv.x; Bs[lk + 1][lr] = bv.y;
        Bs[lk + 2][lr] = bv.z; Bs[lk + 3][lr] = bv.w;
        __syncthreads();

        #pragma unroll
        for (int kk = 0; kk < BK; ++kk) {
            const float4 a4 = *(const float4*)&As[kk][ty << 2];
            const float4 b4 = *(const float4*)&Bs[kk][tx << 2];
            const float a[4] = {a4.x, a4.y, a4.z, a4.w};
            const float b[4] = {b4.x, b4.y, b4.z, b4.w};
            #pragma unroll
            for (int i = 0; i < 4; ++i)
                #pragma unroll
                for (int j = 0; j < 4; ++j)
                    acc[i][j] = fmaf(a[i], b[j], acc[i][j]);
        }
        __syncthreads();
    }
    #pragma unroll
    for (int i = 0; i < 4; ++i) {
        const int m = m0 + (ty << 2) + i;
        #pragma unroll
        for (int j = 0; j < 4; ++j) {
            const int n = n0 + (tx << 2) + j;
            if (n < N) {
                const size_t idx = (size_t)m * N + n;
                float v = acc[i][j];
                if (mode == 1) v = 0.6065306597126334f * sigm(v + bias[n]);
                C[idx] = v;
            }
        }
    }
}

// per-(b,t,h) wave: a = sigmoid(ya+ab); kk = normalize(k0*k_k); bv = kk*a;
// kfinal = k0*(1+(a-1)*k_a).  Reduction on VALU (no DS).
__global__ __launch_bounds__(256) void ka_epi(
    float* __restrict__ Kf, float* __restrict__ A_BV, float* __restrict__ KKo,
    const float* __restrict__ k_k, const float* __restrict__ k_a,
    const float* __restrict__ ab, int total, int H)
{
    int wid = (blockIdx.x << 2) | (threadIdx.x >> 6);
    if (wid >= total) return;
    const int l = threadIdx.x & 63;
    const int h = wid % H;
    const int ch = h * 64 + l;
    const size_t base = (size_t)wid * 64;
    float k0 = Kf[base + l];
    float a = sigm(A_BV[base + l] + ab[ch]);
    float kkr = k0 * k_k[ch];
    float ss = full64(kkr * kkr);
    float inv = 1.f / fmaxf(sqrtf(ss), 1e-12f);
    float kkn = kkr * inv;
    KKo[base + l] = kkn;
    A_BV[base + l] = kkn * a;
    Kf[base + l] = k0 * fmaf(a - 1.f, k_a[ch], 1.f);
}

// DPLR scan (proven config). ONE wave per block; grid = B*H*8 = 512.
#define SCH 16
__global__ __launch_bounds__(64) void rwkv_scan(
    const float* __restrict__ EW, const float* __restrict__ R,
    const float* __restrict__ Kf, const float* __restrict__ Vf,
    const float* __restrict__ KK, const float* __restrict__ BV,
    float* __restrict__ O, int T, int H)
{
    __shared__ float lds[2][5 * SCH * 64 + SCH * 8];

    const int blk = blockIdx.x;
    const int bh = blk & 63;
    const int slab = blk >> 6;
    const int b = bh >> 5, h = bh & 31;
    const int l = threadIdx.x;
    const int vc = l & 7;
    const int g  = l >> 3;
    const int kb = g << 3;
    const int vb0 = slab << 3;
    const size_t step = (size_t)H * 64;
    const size_t base0 = ((size_t)b * T * H + h) * 64;

    auto stage = [&](int c, int buf) {
        float* L = &lds[buf][0];
        const size_t t0 = (size_t)c * SCH;
        const float* gs[5] = {EW, R, Kf, KK, BV};
        #pragma unroll
        for (int s = 0; s < 5; ++s) {
            const float* gp = gs[s];
            #pragma unroll
            for (int j = 0; j < 4; ++j)
                gld16(L + s * SCH * 64 + j * 4 * 64,
                      gp + base0 + (t0 + j * 4 + (l >> 4)) * step + ((l & 15) << 2));
        }
        gld4(L + 5 * SCH * 64,
             Vf + base0 + (t0 + (l >> 3)) * step + vb0 + (l & 7));
        gld4(L + 5 * SCH * 64 + 64,
             Vf + base0 + (t0 + 8 + (l >> 3)) * step + vb0 + (l & 7));
    };

    f32x2 s2[4];
    #pragma unroll
    for (int i = 0; i < 4; ++i) s2[i] = (f32x2){0.f, 0.f};

    struct P { f32x4 e[2], r[2], k[2], q[2], bb[2]; float vv; };
    P PA, PB;
    const int NCH = T / SCH;

    stage(0, 0);
    asm volatile("s_waitcnt vmcnt(0)" ::: "memory");
    __builtin_amdgcn_sched_barrier(0);

    for (int c = 0; c < NCH; ++c) {
        if (c + 1 < NCH) stage(c + 1, (c + 1) & 1);

        const float* L = &lds[c & 1][0];
        auto PRE = [&](P& pp, int tt) {
            const int o = tt * 64 + kb;
            #pragma unroll
            for (int j = 0; j < 2; ++j) {
                pp.e[j]  = *(const f32x4*)(L + 0 * SCH * 64 + o + j * 4);
                pp.r[j]  = *(const f32x4*)(L + 1 * SCH * 64 + o + j * 4);
                pp.k[j]  = *(const f32x4*)(L + 2 * SCH * 64 + o + j * 4);
                pp.q[j]  = *(const f32x4*)(L + 3 * SCH * 64 + o + j * 4);
                pp.bb[j] = *(const f32x4*)(L + 4 * SCH * 64 + o + j * 4);
            }
            pp.vv = L[5 * SCH * 64 + tt * 8 + vc];
        };
        auto COMP = [&](const P& pp, int tt) {
            f32x2 sa0 = (f32x2){0.f, 0.f}, sa1 = (f32x2){0.f, 0.f};
            #pragma unroll
            for (int j = 0; j < 2; ++j) {
                const f32x2 elo = __builtin_shufflevector(pp.e[j], pp.e[j], 0, 1);
                const f32x2 ehi = __builtin_shufflevector(pp.e[j], pp.e[j], 2, 3);
                const f32x2 qlo = __builtin_shufflevector(pp.q[j], pp.q[j], 0, 1);
                const f32x2 qhi = __builtin_shufflevector(pp.q[j], pp.q[j], 2, 3);
                s2[2*j]   *= elo;
                s2[2*j+1] *= ehi;
                sa0 += qlo * s2[2*j];
                sa1 += qhi * s2[2*j+1];
            }
            const f32x2 sas = sa0 + sa1;
            float p = -(sas.x + sas.y);
            p = red32(red16(red8(p)));
            const f32x2 p2 = (f32x2){p, p};
            const f32x2 v2 = (f32x2){pp.vv, pp.vv};
            f32x2 o0 = (f32x2){0.f, 0.f}, o1 = (f32x2){0.f, 0.f};
            #pragma unroll
            for (int j = 0; j < 2; ++j) {
                const f32x2 klo = __builtin_shufflevector(pp.k[j], pp.k[j], 0, 1);
                const f32x2 khi = __builtin_shufflevector(pp.k[j], pp.k[j], 2, 3);
                const f32x2 blo = __builtin_shufflevector(pp.bb[j], pp.bb[j], 0, 1);
                const f32x2 bhi = __builtin_shufflevector(pp.bb[j], pp.bb[j], 2, 3);
                const f32x2 rlo = __builtin_shufflevector(pp.r[j], pp.r[j], 0, 1);
                const f32x2 rhi = __builtin_shufflevector(pp.r[j], pp.r[j], 2, 3);
                s2[2*j]   = blo * p2 + (klo * v2 + s2[2*j]);
                s2[2*j+1] = bhi * p2 + (khi * v2 + s2[2*j+1]);
                o0 += rlo * s2[2*j];
                o1 += rhi * s2[2*j+1];
            }
            const f32x2 os = o0 + o1;
            float oo = os.x + os.y;
            oo = red32(red16(red8(oo)));
            if (g == 0)
                O[base0 + (size_t)(c * SCH + tt) * step + vb0 + vc] = oo;
        };

        PRE(PA, 0);
        PRE(PB, 1);
        #pragma unroll
        for (int tt = 0; tt < SCH - 2; tt += 2) {
            COMP(PA, tt);     PRE(PA, tt + 2);
            COMP(PB, tt + 1); PRE(PB, tt + 3);
        }
        COMP(PA, SCH - 2);
        COMP(PB, SCH - 1);

        asm volatile("s_waitcnt vmcnt(0)" ::: "memory");
        __builtin_amdgcn_sched_barrier(0);
    }
}

// GroupNorm + bonus + precomputed g-gate; writes ON16 (fp16) directly.
__global__ __launch_bounds__(256) void gn_bonus(
    const float* __restrict__ O, const float* __restrict__ R,
    const float* __restrict__ Kf, const float* __restrict__ Vf,
    const float* __restrict__ G, const float* __restrict__ r_k,
    const float* __restrict__ gn_w, const float* __restrict__ gn_b,
    unsigned short* __restrict__ ON16, int total, int H, float eps)
{
    int wid = (blockIdx.x << 2) | (threadIdx.x >> 6);
    if (wid >= total) return;
    const int l = threadIdx.x & 63;
    const int h = wid % H;
    const int ch = h * 64 + l;
    const size_t base = (size_t)wid * 64;

    const float o = O[base + l];
    const float mu = full64(o) * (1.f / 64.f);
    const float d = o - mu;
    const float ss = full64(d * d);
    const float inv = 1.f / sqrtf(ss * (1.f / 64.f) + eps);
    float on = d * inv * gn_w[ch] + gn_b[ch];

    const float r = R[base + l], k = Kf[base + l], vv = Vf[base + l];
    const float p = full64(r * k * r_k[ch]);
    on = fmaf(p, vv, on);
    ON16[base + l] = f2h(on * G[base + l]);
}

extern "C" void kernel_launch(void* const* d_in, const int* in_sizes, int n_in,
                              void* d_out, int out_size, void* d_ws, size_t ws_size,
                              hipStream_t stream)
{
    const int B = 2, T = 2048, D = 2048, H = 32;
    const int M = B * T;

    const float* hid = (const float*)d_in[0];
    const float* vst = (const float*)d_in[1];
    const float* x_x = (const float*)d_in[2];
    const float* k_k = (const float*)d_in[3];
    const float* k_a = (const float*)d_in[4];
    const float* r_k = (const float*)d_in[5];
    const float* Wr  = (const float*)d_in[6];
    const float* Wk  = (const float*)d_in[7];
    const float* Wv  = (const float*)d_in[8];
    const float* Wo  = (const float*)d_in[9];
    const float* wA  = (const float*)d_in[10];
    const float* wB  = (const float*)d_in[11];
    const float* wb  = (const float*)d_in[12];
    const float* vA  = (const float*)d_in[13];
    const float* vB  = (const float*)d_in[14];
    const float* vb  = (const float*)d_in[15];
    const float* aA  = (const float*)d_in[16];
    const float* aB  = (const float*)d_in[17];
    const float* ab  = (const float*)d_in[18];
    const float* gA  = (const float*)d_in[19];
    const float* gB  = (const float*)d_in[20];
    const float* gnw = (const float*)d_in[21];
    const float* gnb = (const float*)d_in[22];
    float* out = (float*)d_out;

    const size_t NE = (size_t)M * D;   // 8,388,608
    const size_t DD = (size_t)D * D;   // 4,194,304
    const size_t need = (6 * NE + (size_t)M * 272) * sizeof(float);  // proven budget
    if (ws_size < need) return;

    float* W0 = (float*)d_ws;      // WL pad -> R_
    float* W1 = W0 + NE;           // X2(r,k) -> yv -> EW -> ON16
    float* W2 = W1 + NE;           // Kf
    float* W3 = W2 + NE;           // WrH/WkH -> Vf  (Wo staging at end)
    float* W4 = W3 + NE;           // [w][a] mixes -> WvH -> wB16/aB16 -> KK -> G
    float* W5 = W4 + NE;           // [g][v] mixes -> YA -> BV -> gB staging
    float* SMALL = W5 + NE;        // M*272 floats
    unsigned short* HW16 = (unsigned short*)SMALL;                  // M*64 shorts
    unsigned short* HA16 = HW16 + (size_t)M * 64;                   // M*64 shorts
    unsigned short* HG16 = HA16 + (size_t)M * 64;                   // M*128 shorts
    float* HV = (float*)(HG16 + (size_t)M * 128);                   // M*16 f32

    dim3 blk(256);
    const int nMix = (int)(NE / 8);
    const int nW   = (int)(DD / 8);
    const float* nf = nullptr;

    unsigned short* X2   = (unsigned short*)W1;          // [r][k] fp16
    unsigned short* X4   = (unsigned short*)W4;          // [w][a][g][v] fp16 (spans W4,W5)
    unsigned short* WRK  = (unsigned short*)W3;          // WrH, WkH
    unsigned short* WL   = (unsigned short*)W0;          // [4][128][2048] fp16 pad

    // ---- 1-2: mixes (fp16) ----
    hipLaunchKernelGGL(mixcvt2_h, dim3(nMix / 256), blk, 0, stream,
                       hid, x_x + 0 * (size_t)D, x_x + 2 * (size_t)D, X2, X2 + NE, T, D, nMix);
    hipLaunchKernelGGL(mixcvt4_h, dim3(nMix / 256), blk, 0, stream,
                       hid, x_x, X4, X4 + NE, X4 + 2 * NE, X4 + 3 * NE, T, D, nMix);

    // ---- 3-4: weight staging ----
    hipLaunchKernelGGL(wcvt2_h, dim3(nW / 256, 2), blk, 0, stream, Wr, Wk, WRK, WRK + DD, nW);
    hipLaunchKernelGGL(wcvt_lora, dim3(128, 4), blk, 0, stream, wA, vA, aA, gA, WL, D);

    // ---- 5: LoRA stage-1 MFMA ----
    hipLaunchKernelGGL(lora1_h, dim3(M / GBM, 1, 4), blk, 0, stream,
                       X4, WL, HW16, HV, HA16, HG16, M, D, NE);

    // ---- 6: R+K batched, single-term fp16 ----
    hipLaunchKernelGGL((gemm_h2<1>), dim3(M / GBM, D / GBN, 2), blk, 0, stream,
                       X2, WRK, WRK, W0, M, D, D, 0, nf, nf, nf,
                       NE, DD, 2 * NE);   // z0 -> R_(W0), z1 -> Kf(W2)

    // ---- 7: yv -> W1 (X2 dead) ----
    hipLaunchKernelGGL(gemm_f32, dim3(M / BM, D / BN), blk, 0, stream, HV, nf, vB, W1, M, D, 16, T, 0, nf);

    // ---- 8-9: V projection (WvH staged in W4: w/a mixes dead) ----
    unsigned short* WvH = (unsigned short*)W4;
    hipLaunchKernelGGL(wcvt2_h, dim3(nW / 256, 1), blk, 0, stream, Wv, Wv, WvH, WvH, nW);
    hipLaunchKernelGGL((gemm_h2<1>), dim3(M / GBM, D / GBN, 1), blk, 0, stream,
                       X4 + 3 * NE, WvH, WvH, W3, M, D, D, 2, W1, vb, vst, 0, 0, 0);  // Vf -> W3

    // ---- 10: LoRA stage-2 MFMA (z0: EW -> W1; z1: ya -> W5) ----
    unsigned short* wB16 = (unsigned short*)W4;          // W4 free after V gemm
    unsigned short* aB16 = wB16 + (size_t)D * 64;
    hipLaunchKernelGGL(wcvt2_h, dim3((int)(D * 64 / 8 / 256), 2), blk, 0, stream, wB, aB, wB16, aB16, (int)(D * 64 / 8));
    hipLaunchKernelGGL((gemm_h2<1>), dim3(M / GBM, D / GBN, 2), blk, 0, stream,
                       HW16, wB16, wB16, W1, M, D, 64, 3, nf, wb, nf,
                       (size_t)M * 64, (size_t)D * 64, 4 * NE);  // z0->W1(EW), z1->W5(YA)

    // ---- 11: ka epilogue (Kf=W2, YA/BV=W5, KK=W4) ----
    const int totalW = M * H;
    hipLaunchKernelGGL(ka_epi, dim3(totalW / 4), blk, 0, stream, W2, W5, W4, k_k, k_a, ab, totalW, H);

    // ---- 12: scan -> d_out ----
    hipLaunchKernelGGL(rwkv_scan, dim3(B * H * 8), dim3(64), 0, stream, W1, W0, W2, W3, W4, W5, out, T, H);

    // ---- 13: g-gate GEMM (gB staged in W5; G -> W4) ----
    unsigned short* gbHi = (unsigned short*)W5;
    unsigned short* gbLo = gbHi + (size_t)D * 128;
    hipLaunchKernelGGL(wsplit_h, dim3((int)(D * 128 / 8 / 256)), blk, 0, stream, gB, gbHi, gbLo, (int)(D * 128 / 8));
    hipLaunchKernelGGL((gemm_h2<2>), dim3(M / GBM, D / GBN, 1), blk, 0, stream,
                       HG16, gbHi, gbLo, W4, M, D, 128, 0, nf, nf, nf, 0, 0, 0);

    // ---- 14: gn_bonus -> ON16 (W1) ----
    unsigned short* ON16 = (unsigned short*)W1;
    hipLaunchKernelGGL(gn_bonus, dim3(totalW / 4), blk, 0, stream, out, W0, W2, W3, W4, r_k, gnw, gnb, ON16, totalW, H, 64.f * 1e-5f);

    // ---- 15: Wo projection -> d_out (TERMS=2; staged in W3) ----
    unsigned short* WoHi = (unsigned short*)W3;
    unsigned short* WoLo = WoHi + DD;
    hipLaunchKernelGGL(wsplit_h, dim3(nW / 256), blk, 0, stream, Wo, WoHi, WoLo, nW);
    hipLaunchKernelGGL((gemm_h2<2>), dim3(M / GBM, D / GBN, 1), blk, 0, stream,
                       ON16, WoHi, WoLo, out, M, D, D, 0, nf, nf, nf, 0, 0, 0);
}

// Round 20
// 874.602 us; speedup vs baseline: 1.3204x; 1.0500x over previous
//
#include <hip/hip_runtime.h>
#include <hip/hip_bf16.h>
#include <math.h>

// RWKV7 attention, round 20 (= round 19 + output-path TERMS=1 + single-pass mixes):
//  - Wo and g-gate GEMMs moved to single-term fp16 (TERMS=1; R17 proved zero absmax
//    cost for fp16 weights on larger paths). wsplit passes become hi-only converts.
//  - mixcvt6_h: all six mixes (r,k,w,a,g,v) in one pass; hid read once.
// Scan / ka_epi / gn_bonus / other GEMMs byte-identical to round 19 (918us, 0.0039).

typedef __attribute__((ext_vector_type(8))) unsigned short ushort8;
typedef __attribute__((ext_vector_type(8))) _Float16 f16x8;
typedef __attribute__((ext_vector_type(4))) float f32x4;
typedef __attribute__((ext_vector_type(2))) float f32x2;

__device__ inline unsigned short f2h(float f) {
    _Float16 h = (_Float16)f;
    return __builtin_bit_cast(unsigned short, h);
}
__device__ inline float h2f(unsigned short u) {
    return (float)__builtin_bit_cast(_Float16, u);
}
__device__ inline float sigm(float x) { return 1.f / (1.f + expf(-x)); }

// ---- VALU cross-lane reductions (DPP rotates + permlane swaps; distinct-reg rule from r9) ----
template <int CTRL>
__device__ __forceinline__ float rrot(float x) {
    int xi = __builtin_bit_cast(int, x);
    int yi = __builtin_amdgcn_update_dpp(xi, xi, CTRL, 0xf, 0xf, true);
    return x + __builtin_bit_cast(float, yi);
}
__device__ __forceinline__ float red8(float x)  { return rrot<0x128>(x); }
__device__ __forceinline__ float red16(float x) {
    float b = x;
    asm("" : "+v"(b));
    float a = x;
    asm("v_permlane16_swap_b32 %0, %1" : "+v"(a), "+v"(b));
    return a + b;
}
__device__ __forceinline__ float red32(float x) {
    float b = x;
    asm("" : "+v"(b));
    float a = x;
    asm("v_permlane32_swap_b32 %0, %1" : "+v"(a), "+v"(b));
    return a + b;
}
__device__ __forceinline__ float full64(float x) {
    x = rrot<0x121>(x);
    x = rrot<0x122>(x);
    x = rrot<0x124>(x);
    x = rrot<0x128>(x);
    return red32(red16(x));
}

// async global -> LDS. LDS dest = uniform base + lane*size.
__device__ __forceinline__ void gld16(void* lds, const void* g)
{
    __builtin_amdgcn_global_load_lds(
        (const __attribute__((address_space(1))) void*)g,
        (__attribute__((address_space(3))) void*)lds, 16, 0, 0);
}
__device__ __forceinline__ void gld4(void* lds, const void* g)
{
    __builtin_amdgcn_global_load_lds(
        (const __attribute__((address_space(1))) void*)g,
        (__attribute__((address_space(3))) void*)lds, 4, 0, 0);
}

// ---------------- all six mixes in one pass (r,k,w,a,g,v) ----------------
__global__ void mixcvt6_h(const float* __restrict__ in, const float* __restrict__ x_x,
                          unsigned short* __restrict__ oR, unsigned short* __restrict__ oK,
                          unsigned short* __restrict__ ow, unsigned short* __restrict__ oa,
                          unsigned short* __restrict__ og, unsigned short* __restrict__ ov,
                          int T, int D, int total8)
{
    int i = blockIdx.x * 256 + threadIdx.x;
    if (i >= total8) return;
    const size_t e = (size_t)i * 8;
    float a[8];
    *(float4*)&a[0] = *(const float4*)(in + e);
    *(float4*)&a[4] = *(const float4*)(in + e + 4);
    const int m = (int)(e / D);
    const int d = (int)(e % D);
    const int t = m % T;
    float p[8] = {0.f,0.f,0.f,0.f,0.f,0.f,0.f,0.f};
    if (t > 0) {
        *(float4*)&p[0] = *(const float4*)(in + e - D);
        *(float4*)&p[4] = *(const float4*)(in + e - D + 4);
    }
    const float* xxr = x_x + 0 * (size_t)D + d;
    const float* xxw = x_x + 1 * (size_t)D + d;
    const float* xxk = x_x + 2 * (size_t)D + d;
    const float* xxv = x_x + 3 * (size_t)D + d;
    const float* xxa = x_x + 4 * (size_t)D + d;
    const float* xxg = x_x + 5 * (size_t)D + d;
    ushort8 rr, rk, rw, ra, rg, rv;
    #pragma unroll
    for (int j = 0; j < 8; ++j) {
        const float dl = p[j] - a[j];
        rr[j] = f2h(a[j] + dl * xxr[j]);
        rk[j] = f2h(a[j] + dl * xxk[j]);
        rw[j] = f2h(a[j] + dl * xxw[j]);
        ra[j] = f2h(a[j] + dl * xxa[j]);
        rg[j] = f2h(a[j] + dl * xxg[j]);
        rv[j] = f2h(a[j] + dl * xxv[j]);
    }
    *(ushort8*)(oR + e) = rr;
    *(ushort8*)(oK + e) = rk;
    *(ushort8*)(ow + e) = rw;
    *(ushort8*)(oa + e) = ra;
    *(ushort8*)(og + e) = rg;
    *(ushort8*)(ov + e) = rv;
}

// weight convert, hi only, two weights per launch (grid.y selects)
__global__ void wcvt2_h(const float* __restrict__ in0, const float* __restrict__ in1,
                        unsigned short* __restrict__ hi0, unsigned short* __restrict__ hi1,
                        int total8)
{
    int i = blockIdx.x * 256 + threadIdx.x;
    if (i >= total8) return;
    const float* in = (blockIdx.y == 0) ? in0 : in1;
    unsigned short* hi = (blockIdx.y == 0) ? hi0 : hi1;
    const size_t e = (size_t)i * 8;
    float a[8];
    *(float4*)&a[0] = *(const float4*)(in + e);
    *(float4*)&a[4] = *(const float4*)(in + e + 4);
    ushort8 h8;
    #pragma unroll
    for (int j = 0; j < 8; ++j) h8[j] = f2h(a[j]);
    *(ushort8*)(hi + e) = h8;
}

// LoRA-A weights zero-padded to [4][128][2048] fp16 (z: 0=wA(64) 1=vA(16) 2=aA(64) 3=gA(128))
__global__ void wcvt_lora(const float* __restrict__ wA, const float* __restrict__ vA,
                          const float* __restrict__ aA, const float* __restrict__ gA,
                          unsigned short* __restrict__ WL, int K)
{
    const int z = blockIdx.y;
    int i = blockIdx.x * 256 + threadIdx.x;
    const size_t e = (size_t)i * 8;
    const int row = (int)(e / K);
    const int col = (int)(e % K);
    const int nv = (z == 0) ? 64 : (z == 1) ? 16 : (z == 2) ? 64 : 128;
    const float* src = (z == 0) ? wA : (z == 1) ? vA : (z == 2) ? aA : gA;
    ushort8 h8;
    if (row < nv) {
        float a[8];
        *(float4*)&a[0] = *(const float4*)(src + (size_t)row * K + col);
        *(float4*)&a[4] = *(const float4*)(src + (size_t)row * K + col + 4);
        #pragma unroll
        for (int j = 0; j < 8; ++j) h8[j] = f2h(a[j]);
    } else {
        #pragma unroll
        for (int j = 0; j < 8; ++j) h8[j] = 0;
    }
    *(ushort8*)(WL + (size_t)z * 128 * K + e) = h8;
}

// ---------------- fp16 MFMA GEMM: C[M,N] = A[M,K] @ W[N,K]^T, f32 out ----------
// mode 0: C=acc. mode 2: C=lerp(acc,aux,sigm(yv+bias)). mode 3: z0: C=0.6065*sigm(acc+bias), z1: C=acc.
#define GBM 128
#define GBN 128

template <int TERMS>
__global__ __launch_bounds__(256) void gemm_h2(
    const unsigned short* __restrict__ Ag,
    const unsigned short* __restrict__ Bhg, const unsigned short* __restrict__ Blg,
    float* __restrict__ C, int M, int N, int K, int mode,
    const float* __restrict__ yv, const float* __restrict__ bias,
    const float* __restrict__ aux,
    size_t sA, size_t sB, size_t sC)
{
    __shared__ unsigned short As[GBM * 32];
    __shared__ unsigned short Bhs[GBN * 32], Bls[GBN * 32];
    const int z = blockIdx.z;
    Ag  += (size_t)z * sA;
    Bhg += (size_t)z * sB;
    Blg += (size_t)z * sB;
    C   += (size_t)z * sC;
    const int tid = threadIdx.x;
    const int m0 = blockIdx.x * GBM;
    const int n0 = blockIdx.y * GBN;
    const int wave = tid >> 6, lane = tid & 63;
    const int wr = (wave >> 1) * 64, wc = (wave & 1) * 64;
    const int fr = lane & 15, fq = lane >> 4;

    f32x4 acc[4][4];
    #pragma unroll
    for (int i = 0; i < 4; ++i)
        #pragma unroll
        for (int j = 0; j < 4; ++j)
            acc[i][j] = (f32x4){0.f, 0.f, 0.f, 0.f};

    const unsigned short* gsrc;
    unsigned short* lbuf;
    int rofs, nld;
    if (wave == 0)      { gsrc = Ag;  lbuf = As;           rofs = m0;      nld = 4; }
    else if (wave == 1) { gsrc = Ag;  lbuf = As + 64 * 32; rofs = m0 + 64; nld = 4; }
    else if (wave == 2) { gsrc = Bhg; lbuf = Bhs;          rofs = n0;      nld = 8; }
    else                { gsrc = Blg; lbuf = Bls;          rofs = n0;      nld = (TERMS == 2) ? 8 : 0; }
    const unsigned short* gbase = gsrc + (size_t)(rofs + (lane >> 2)) * K + ((lane & 3) << 3);

    for (int k0 = 0; k0 < K; k0 += 32) {
        #pragma unroll
        for (int j = 0; j < 8; ++j)
            if (j < nld)
                gld16(lbuf + j * 16 * 32, gbase + (size_t)(j * 16) * K + k0);
        __syncthreads();

        f16x8 fa[4], fbh[4], fbl[4];
        #pragma unroll
        for (int m = 0; m < 4; ++m)
            fa[m] = *(const f16x8*)&As[(wr + m * 16 + fr) * 32 + fq * 8];
        #pragma unroll
        for (int n = 0; n < 4; ++n) {
            fbh[n] = *(const f16x8*)&Bhs[(wc + n * 16 + fr) * 32 + fq * 8];
            if constexpr (TERMS == 2)
                fbl[n] = *(const f16x8*)&Bls[(wc + n * 16 + fr) * 32 + fq * 8];
        }
        #pragma unroll
        for (int m = 0; m < 4; ++m)
            #pragma unroll
            for (int n = 0; n < 4; ++n) {
                acc[m][n] = __builtin_amdgcn_mfma_f32_16x16x32_f16(fa[m], fbh[n], acc[m][n], 0, 0, 0);
                if constexpr (TERMS == 2)
                    acc[m][n] = __builtin_amdgcn_mfma_f32_16x16x32_f16(fa[m], fbl[n], acc[m][n], 0, 0, 0);
            }
        __syncthreads();
    }

    #pragma unroll
    for (int m = 0; m < 4; ++m) {
        const int row = m0 + wr + m * 16 + fq * 4;
        #pragma unroll
        for (int n = 0; n < 4; ++n) {
            const int col = n0 + wc + n * 16 + fr;
            #pragma unroll
            for (int j = 0; j < 4; ++j) {
                const size_t idx = (size_t)(row + j) * N + col;
                float v = acc[m][n][j];
                if (mode == 2) {
                    const float sg = sigm(yv[idx] + bias[col]);
                    v = v + sg * (aux[idx] - v);
                } else if (mode == 3 && z == 0) {
                    v = 0.6065306597126334f * sigm(v + bias[col]);
                }
                C[idx] = v;
            }
        }
    }
}

// ---------------- LoRA stage-1 MFMA: z-batched, N-tile 128, per-z act epilogue ----------
__global__ __launch_bounds__(256) void lora1_h(
    const unsigned short* __restrict__ Xbase,   // [w][a][g][v] fp16, NE each
    const unsigned short* __restrict__ WL,      // [4][128][K] fp16 padded
    unsigned short* __restrict__ HW16, float* __restrict__ HV,
    unsigned short* __restrict__ HA16, unsigned short* __restrict__ HG16,
    int M, int K, size_t NE)
{
    __shared__ unsigned short As[GBM * 32];
    __shared__ unsigned short Bhs[GBN * 32];
    const int z = blockIdx.z;
    const size_t zofs = (z == 0) ? 0 : (z == 1) ? 3 * NE : (z == 2) ? NE : 2 * NE;  // w,v,a,g
    const unsigned short* Ag = Xbase + zofs;
    const unsigned short* Bg = WL + (size_t)z * 128 * K;
    const int tid = threadIdx.x;
    const int m0 = blockIdx.x * GBM;
    const int wave = tid >> 6, lane = tid & 63;
    const int wr = (wave >> 1) * 64, wc = (wave & 1) * 64;
    const int fr = lane & 15, fq = lane >> 4;

    f32x4 acc[4][4];
    #pragma unroll
    for (int i = 0; i < 4; ++i)
        #pragma unroll
        for (int j = 0; j < 4; ++j)
            acc[i][j] = (f32x4){0.f, 0.f, 0.f, 0.f};

    const unsigned short* gsrc;
    unsigned short* lbuf;
    int rofs, nld;
    if (wave == 0)      { gsrc = Ag; lbuf = As;           rofs = m0;      nld = 4; }
    else if (wave == 1) { gsrc = Ag; lbuf = As + 64 * 32; rofs = m0 + 64; nld = 4; }
    else if (wave == 2) { gsrc = Bg; lbuf = Bhs;          rofs = 0;       nld = 8; }
    else                { gsrc = Bg; lbuf = Bhs;          rofs = 0;       nld = 0; }
    const unsigned short* gbase = gsrc + (size_t)(rofs + (lane >> 2)) * K + ((lane & 3) << 3);

    for (int k0 = 0; k0 < K; k0 += 32) {
        #pragma unroll
        for (int j = 0; j < 8; ++j)
            if (j < nld)
                gld16(lbuf + j * 16 * 32, gbase + (size_t)(j * 16) * K + k0);
        __syncthreads();

        f16x8 fa[4], fb[4];
        #pragma unroll
        for (int m = 0; m < 4; ++m)
            fa[m] = *(const f16x8*)&As[(wr + m * 16 + fr) * 32 + fq * 8];
        #pragma unroll
        for (int n = 0; n < 4; ++n)
            fb[n] = *(const f16x8*)&Bhs[(wc + n * 16 + fr) * 32 + fq * 8];
        #pragma unroll
        for (int m = 0; m < 4; ++m)
            #pragma unroll
            for (int n = 0; n < 4; ++n)
                acc[m][n] = __builtin_amdgcn_mfma_f32_16x16x32_f16(fa[m], fb[n], acc[m][n], 0, 0, 0);
        __syncthreads();
    }

    #pragma unroll
    for (int m = 0; m < 4; ++m) {
        const int row = m0 + wr + m * 16 + fq * 4;
        #pragma unroll
        for (int n = 0; n < 4; ++n) {
            const int col = wc + n * 16 + fr;   // 0..127
            #pragma unroll
            for (int j = 0; j < 4; ++j) {
                const float v = acc[m][n][j];
                const int r = row + j;
                if (z == 0)      { if (col < 64) HW16[(size_t)r * 64 + col] = f2h(tanhf(v)); }
                else if (z == 1) { if (col < 16) HV[(size_t)r * 16 + col] = v; }
                else if (z == 2) { if (col < 64) HA16[(size_t)r * 64 + col] = f2h(v); }
                else             { HG16[(size_t)r * 128 + col] = f2h(sigm(v)); }
            }
        }
    }
}

// ---------------- f32 SIMD GEMM (yv only) ----------------
#define BM 64
#define BN 64
#define BK 16
__global__ __launch_bounds__(256) void gemm_f32(
    const float* __restrict__ A, const float* __restrict__ xx,
    const float* __restrict__ W, float* __restrict__ C,
    int M, int N, int K, int T, int mode, const float* __restrict__ bias)
{
    __shared__ float As[BK][BM + 4];
    __shared__ float Bs[BK][BN + 4];
    const int tid = threadIdx.x;
    const int m0 = blockIdx.x * BM;
    const int n0 = blockIdx.y * BN;
    const int lr = tid >> 2;
    const int lk = (tid & 3) << 2;
    const int tx = tid & 15;
    const int ty = tid >> 4;
    const int mrow = m0 + lr;
    const int nrow = n0 + lr;
    float acc[4][4];
    #pragma unroll
    for (int i = 0; i < 4; ++i)
        #pragma unroll
        for (int j = 0; j < 4; ++j) acc[i][j] = 0.f;

    for (int k0 = 0; k0 < K; k0 += BK) {
        const float* ap = A + (size_t)mrow * K + k0 + lk;
        float4 av = *(const float4*)ap;
        if (xx) {
            const int t = mrow % T;
            float4 pv = make_float4(0.f, 0.f, 0.f, 0.f);
            if (t > 0) pv = *(const float4*)(ap - K);
            const float4 xv = *(const float4*)(xx + k0 + lk);
            av.x += (pv.x - av.x) * xv.x;
            av.y += (pv.y - av.y) * xv.y;
            av.z += (pv.z - av.z) * xv.z;
            av.w += (pv.w - av.w) * xv.w;
        }
        float4 bv = make_float4(0.f, 0.f, 0.f, 0.f);
        if (nrow < N) bv = *(const float4*)(W + (size_t)nrow * K + k0 + lk);

        As[lk + 0][lr] = av.x; As[lk + 1][lr] = av.y;
        As[lk + 2][lr] = av.z; As[lk + 3][lr] = av.w;
        Bs[lk + 0][lr] = bv.x; Bs[lk + 1][lr] = bv.y;
        Bs[lk + 2][lr] = bv.z; Bs[lk + 3][lr] = bv.w;
        __syncthreads();

        #pragma unroll
        for (int kk = 0; kk < BK; ++kk) {
            const float4 a4 = *(const float4*)&As[kk][ty << 2];
            const float4 b4 = *(const float4*)&Bs[kk][tx << 2];
            const float a[4] = {a4.x, a4.y, a4.z, a4.w};
            const float b[4] = {b4.x, b4.y, b4.z, b4.w};
            #pragma unroll
            for (int i = 0; i < 4; ++i)
                #pragma unroll
                for (int j = 0; j < 4; ++j)
                    acc[i][j] = fmaf(a[i], b[j], acc[i][j]);
        }
        __syncthreads();
    }
    #pragma unroll
    for (int i = 0; i < 4; ++i) {
        const int m = m0 + (ty << 2) + i;
        #pragma unroll
        for (int j = 0; j < 4; ++j) {
            const int n = n0 + (tx << 2) + j;
            if (n < N) {
                const size_t idx = (size_t)m * N + n;
                float v = acc[i][j];
                if (mode == 1) v = 0.6065306597126334f * sigm(v + bias[n]);
                C[idx] = v;
            }
        }
    }
}

// per-(b,t,h) wave: a = sigmoid(ya+ab); kk = normalize(k0*k_k); bv = kk*a;
// kfinal = k0*(1+(a-1)*k_a).  Reduction on VALU (no DS).
__global__ __launch_bounds__(256) void ka_epi(
    float* __restrict__ Kf, float* __restrict__ A_BV, float* __restrict__ KKo,
    const float* __restrict__ k_k, const float* __restrict__ k_a,
    const float* __restrict__ ab, int total, int H)
{
    int wid = (blockIdx.x << 2) | (threadIdx.x >> 6);
    if (wid >= total) return;
    const int l = threadIdx.x & 63;
    const int h = wid % H;
    const int ch = h * 64 + l;
    const size_t base = (size_t)wid * 64;
    float k0 = Kf[base + l];
    float a = sigm(A_BV[base + l] + ab[ch]);
    float kkr = k0 * k_k[ch];
    float ss = full64(kkr * kkr);
    float inv = 1.f / fmaxf(sqrtf(ss), 1e-12f);
    float kkn = kkr * inv;
    KKo[base + l] = kkn;
    A_BV[base + l] = kkn * a;
    Kf[base + l] = k0 * fmaf(a - 1.f, k_a[ch], 1.f);
}

// DPLR scan (proven config). ONE wave per block; grid = B*H*8 = 512.
#define SCH 16
__global__ __launch_bounds__(64) void rwkv_scan(
    const float* __restrict__ EW, const float* __restrict__ R,
    const float* __restrict__ Kf, const float* __restrict__ Vf,
    const float* __restrict__ KK, const float* __restrict__ BV,
    float* __restrict__ O, int T, int H)
{
    __shared__ float lds[2][5 * SCH * 64 + SCH * 8];

    const int blk = blockIdx.x;
    const int bh = blk & 63;
    const int slab = blk >> 6;
    const int b = bh >> 5, h = bh & 31;
    const int l = threadIdx.x;
    const int vc = l & 7;
    const int g  = l >> 3;
    const int kb = g << 3;
    const int vb0 = slab << 3;
    const size_t step = (size_t)H * 64;
    const size_t base0 = ((size_t)b * T * H + h) * 64;

    auto stage = [&](int c, int buf) {
        float* L = &lds[buf][0];
        const size_t t0 = (size_t)c * SCH;
        const float* gs[5] = {EW, R, Kf, KK, BV};
        #pragma unroll
        for (int s = 0; s < 5; ++s) {
            const float* gp = gs[s];
            #pragma unroll
            for (int j = 0; j < 4; ++j)
                gld16(L + s * SCH * 64 + j * 4 * 64,
                      gp + base0 + (t0 + j * 4 + (l >> 4)) * step + ((l & 15) << 2));
        }
        gld4(L + 5 * SCH * 64,
             Vf + base0 + (t0 + (l >> 3)) * step + vb0 + (l & 7));
        gld4(L + 5 * SCH * 64 + 64,
             Vf + base0 + (t0 + 8 + (l >> 3)) * step + vb0 + (l & 7));
    };

    f32x2 s2[4];
    #pragma unroll
    for (int i = 0; i < 4; ++i) s2[i] = (f32x2){0.f, 0.f};

    struct P { f32x4 e[2], r[2], k[2], q[2], bb[2]; float vv; };
    P PA, PB;
    const int NCH = T / SCH;

    stage(0, 0);
    asm volatile("s_waitcnt vmcnt(0)" ::: "memory");
    __builtin_amdgcn_sched_barrier(0);

    for (int c = 0; c < NCH; ++c) {
        if (c + 1 < NCH) stage(c + 1, (c + 1) & 1);

        const float* L = &lds[c & 1][0];
        auto PRE = [&](P& pp, int tt) {
            const int o = tt * 64 + kb;
            #pragma unroll
            for (int j = 0; j < 2; ++j) {
                pp.e[j]  = *(const f32x4*)(L + 0 * SCH * 64 + o + j * 4);
                pp.r[j]  = *(const f32x4*)(L + 1 * SCH * 64 + o + j * 4);
                pp.k[j]  = *(const f32x4*)(L + 2 * SCH * 64 + o + j * 4);
                pp.q[j]  = *(const f32x4*)(L + 3 * SCH * 64 + o + j * 4);
                pp.bb[j] = *(const f32x4*)(L + 4 * SCH * 64 + o + j * 4);
            }
            pp.vv = L[5 * SCH * 64 + tt * 8 + vc];
        };
        auto COMP = [&](const P& pp, int tt) {
            f32x2 sa0 = (f32x2){0.f, 0.f}, sa1 = (f32x2){0.f, 0.f};
            #pragma unroll
            for (int j = 0; j < 2; ++j) {
                const f32x2 elo = __builtin_shufflevector(pp.e[j], pp.e[j], 0, 1);
                const f32x2 ehi = __builtin_shufflevector(pp.e[j], pp.e[j], 2, 3);
                const f32x2 qlo = __builtin_shufflevector(pp.q[j], pp.q[j], 0, 1);
                const f32x2 qhi = __builtin_shufflevector(pp.q[j], pp.q[j], 2, 3);
                s2[2*j]   *= elo;
                s2[2*j+1] *= ehi;
                sa0 += qlo * s2[2*j];
                sa1 += qhi * s2[2*j+1];
            }
            const f32x2 sas = sa0 + sa1;
            float p = -(sas.x + sas.y);
            p = red32(red16(red8(p)));
            const f32x2 p2 = (f32x2){p, p};
            const f32x2 v2 = (f32x2){pp.vv, pp.vv};
            f32x2 o0 = (f32x2){0.f, 0.f}, o1 = (f32x2){0.f, 0.f};
            #pragma unroll
            for (int j = 0; j < 2; ++j) {
                const f32x2 klo = __builtin_shufflevector(pp.k[j], pp.k[j], 0, 1);
                const f32x2 khi = __builtin_shufflevector(pp.k[j], pp.k[j], 2, 3);
                const f32x2 blo = __builtin_shufflevector(pp.bb[j], pp.bb[j], 0, 1);
                const f32x2 bhi = __builtin_shufflevector(pp.bb[j], pp.bb[j], 2, 3);
                const f32x2 rlo = __builtin_shufflevector(pp.r[j], pp.r[j], 0, 1);
                const f32x2 rhi = __builtin_shufflevector(pp.r[j], pp.r[j], 2, 3);
                s2[2*j]   = blo * p2 + (klo * v2 + s2[2*j]);
                s2[2*j+1] = bhi * p2 + (khi * v2 + s2[2*j+1]);
                o0 += rlo * s2[2*j];
                o1 += rhi * s2[2*j+1];
            }
            const f32x2 os = o0 + o1;
            float oo = os.x + os.y;
            oo = red32(red16(red8(oo)));
            if (g == 0)
                O[base0 + (size_t)(c * SCH + tt) * step + vb0 + vc] = oo;
        };

        PRE(PA, 0);
        PRE(PB, 1);
        #pragma unroll
        for (int tt = 0; tt < SCH - 2; tt += 2) {
            COMP(PA, tt);     PRE(PA, tt + 2);
            COMP(PB, tt + 1); PRE(PB, tt + 3);
        }
        COMP(PA, SCH - 2);
        COMP(PB, SCH - 1);

        asm volatile("s_waitcnt vmcnt(0)" ::: "memory");
        __builtin_amdgcn_sched_barrier(0);
    }
}

// GroupNorm + bonus + precomputed g-gate; writes ON16 (fp16) directly.
__global__ __launch_bounds__(256) void gn_bonus(
    const float* __restrict__ O, const float* __restrict__ R,
    const float* __restrict__ Kf, const float* __restrict__ Vf,
    const float* __restrict__ G, const float* __restrict__ r_k,
    const float* __restrict__ gn_w, const float* __restrict__ gn_b,
    unsigned short* __restrict__ ON16, int total, int H, float eps)
{
    int wid = (blockIdx.x << 2) | (threadIdx.x >> 6);
    if (wid >= total) return;
    const int l = threadIdx.x & 63;
    const int h = wid % H;
    const int ch = h * 64 + l;
    const size_t base = (size_t)wid * 64;

    const float o = O[base + l];
    const float mu = full64(o) * (1.f / 64.f);
    const float d = o - mu;
    const float ss = full64(d * d);
    const float inv = 1.f / sqrtf(ss * (1.f / 64.f) + eps);
    float on = d * inv * gn_w[ch] + gn_b[ch];

    const float r = R[base + l], k = Kf[base + l], vv = Vf[base + l];
    const float p = full64(r * k * r_k[ch]);
    on = fmaf(p, vv, on);
    ON16[base + l] = f2h(on * G[base + l]);
}

extern "C" void kernel_launch(void* const* d_in, const int* in_sizes, int n_in,
                              void* d_out, int out_size, void* d_ws, size_t ws_size,
                              hipStream_t stream)
{
    const int B = 2, T = 2048, D = 2048, H = 32;
    const int M = B * T;

    const float* hid = (const float*)d_in[0];
    const float* vst = (const float*)d_in[1];
    const float* x_x = (const float*)d_in[2];
    const float* k_k = (const float*)d_in[3];
    const float* k_a = (const float*)d_in[4];
    const float* r_k = (const float*)d_in[5];
    const float* Wr  = (const float*)d_in[6];
    const float* Wk  = (const float*)d_in[7];
    const float* Wv  = (const float*)d_in[8];
    const float* Wo  = (const float*)d_in[9];
    const float* wA  = (const float*)d_in[10];
    const float* wB  = (const float*)d_in[11];
    const float* wb  = (const float*)d_in[12];
    const float* vA  = (const float*)d_in[13];
    const float* vB  = (const float*)d_in[14];
    const float* vb  = (const float*)d_in[15];
    const float* aA  = (const float*)d_in[16];
    const float* aB  = (const float*)d_in[17];
    const float* ab  = (const float*)d_in[18];
    const float* gA  = (const float*)d_in[19];
    const float* gB  = (const float*)d_in[20];
    const float* gnw = (const float*)d_in[21];
    const float* gnb = (const float*)d_in[22];
    float* out = (float*)d_out;

    const size_t NE = (size_t)M * D;   // 8,388,608
    const size_t DD = (size_t)D * D;   // 4,194,304
    const size_t need = (6 * NE + (size_t)M * 272) * sizeof(float);  // proven budget
    if (ws_size < need) return;

    float* W0 = (float*)d_ws;      // WL pad -> R_
    float* W1 = W0 + NE;           // X2(r,k) -> yv -> EW -> ON16
    float* W2 = W1 + NE;           // Kf
    float* W3 = W2 + NE;           // WrH/WkH -> Vf -> Wo16
    float* W4 = W3 + NE;           // [w][a] mixes -> WvH -> wB16/aB16 -> KK -> G
    float* W5 = W4 + NE;           // [g][v] mixes -> YA -> BV -> gb16
    float* SMALL = W5 + NE;        // M*272 floats
    unsigned short* HW16 = (unsigned short*)SMALL;
    unsigned short* HA16 = HW16 + (size_t)M * 64;
    unsigned short* HG16 = HA16 + (size_t)M * 64;
    float* HV = (float*)(HG16 + (size_t)M * 128);

    dim3 blk(256);
    const int nMix = (int)(NE / 8);
    const int nW   = (int)(DD / 8);
    const float* nf = nullptr;

    unsigned short* X2   = (unsigned short*)W1;          // [r][k] fp16
    unsigned short* X4   = (unsigned short*)W4;          // [w][a][g][v] fp16 (spans W4,W5)
    unsigned short* WRK  = (unsigned short*)W3;          // WrH, WkH
    unsigned short* WL   = (unsigned short*)W0;          // [4][128][2048] fp16 pad

    // ---- 1: all six mixes (fp16), hid read once ----
    hipLaunchKernelGGL(mixcvt6_h, dim3(nMix / 256), blk, 0, stream,
                       hid, x_x, X2, X2 + NE, X4, X4 + NE, X4 + 2 * NE, X4 + 3 * NE, T, D, nMix);

    // ---- 2-3: weight staging ----
    hipLaunchKernelGGL(wcvt2_h, dim3(nW / 256, 2), blk, 0, stream, Wr, Wk, WRK, WRK + DD, nW);
    hipLaunchKernelGGL(wcvt_lora, dim3(128, 4), blk, 0, stream, wA, vA, aA, gA, WL, D);

    // ---- 4: LoRA stage-1 MFMA ----
    hipLaunchKernelGGL(lora1_h, dim3(M / GBM, 1, 4), blk, 0, stream,
                       X4, WL, HW16, HV, HA16, HG16, M, D, NE);

    // ---- 5: R+K batched, single-term fp16 ----
    hipLaunchKernelGGL((gemm_h2<1>), dim3(M / GBM, D / GBN, 2), blk, 0, stream,
                       X2, WRK, WRK, W0, M, D, D, 0, nf, nf, nf,
                       NE, DD, 2 * NE);   // z0 -> R_(W0), z1 -> Kf(W2)

    // ---- 6: yv -> W1 (X2 dead) ----
    hipLaunchKernelGGL(gemm_f32, dim3(M / BM, D / BN), blk, 0, stream, HV, nf, vB, W1, M, D, 16, T, 0, nf);

    // ---- 7-8: V projection (WvH staged in W4: w/a mixes dead) ----
    unsigned short* WvH = (unsigned short*)W4;
    hipLaunchKernelGGL(wcvt2_h, dim3(nW / 256, 1), blk, 0, stream, Wv, Wv, WvH, WvH, nW);
    hipLaunchKernelGGL((gemm_h2<1>), dim3(M / GBM, D / GBN, 1), blk, 0, stream,
                       X4 + 3 * NE, WvH, WvH, W3, M, D, D, 2, W1, vb, vst, 0, 0, 0);  // Vf -> W3

    // ---- 9: LoRA stage-2 MFMA (z0: EW -> W1; z1: ya -> W5) ----
    unsigned short* wB16 = (unsigned short*)W4;
    unsigned short* aB16 = wB16 + (size_t)D * 64;
    hipLaunchKernelGGL(wcvt2_h, dim3((int)(D * 64 / 8 / 256), 2), blk, 0, stream, wB, aB, wB16, aB16, (int)(D * 64 / 8));
    hipLaunchKernelGGL((gemm_h2<1>), dim3(M / GBM, D / GBN, 2), blk, 0, stream,
                       HW16, wB16, wB16, W1, M, D, 64, 3, nf, wb, nf,
                       (size_t)M * 64, (size_t)D * 64, 4 * NE);  // z0->W1(EW), z1->W5(YA)

    // ---- 10: ka epilogue (Kf=W2, YA/BV=W5, KK=W4) ----
    const int totalW = M * H;
    hipLaunchKernelGGL(ka_epi, dim3(totalW / 4), blk, 0, stream, W2, W5, W4, k_k, k_a, ab, totalW, H);

    // ---- 11: scan -> d_out ----
    hipLaunchKernelGGL(rwkv_scan, dim3(B * H * 8), dim3(64), 0, stream, W1, W0, W2, W3, W4, W5, out, T, H);

    // ---- 12: g-gate GEMM, single-term (gb16 in W5; G -> W4) ----
    unsigned short* gb16 = (unsigned short*)W5;
    hipLaunchKernelGGL(wcvt2_h, dim3((int)(D * 128 / 8 / 256), 1), blk, 0, stream, gB, gB, gb16, gb16, (int)(D * 128 / 8));
    hipLaunchKernelGGL((gemm_h2<1>), dim3(M / GBM, D / GBN, 1), blk, 0, stream,
                       HG16, gb16, gb16, W4, M, D, 128, 0, nf, nf, nf, 0, 0, 0);

    // ---- 13: gn_bonus -> ON16 (W1) ----
    unsigned short* ON16 = (unsigned short*)W1;
    hipLaunchKernelGGL(gn_bonus, dim3(totalW / 4), blk, 0, stream, out, W0, W2, W3, W4, r_k, gnw, gnb, ON16, totalW, H, 64.f * 1e-5f);

    // ---- 14: Wo projection -> d_out, single-term (Wo16 in W3) ----
    unsigned short* Wo16 = (unsigned short*)W3;
    hipLaunchKernelGGL(wcvt2_h, dim3(nW / 256, 1), blk, 0, stream, Wo, Wo, Wo16, Wo16, nW);
    hipLaunchKernelGGL((gemm_h2<1>), dim3(M / GBM, D / GBN, 1), blk, 0, stream,
                       ON16, Wo16, Wo16, out, M, D, D, 0, nf, nf, nf, 0, 0, 0);
}

// Round 21
// 840.143 us; speedup vs baseline: 1.3745x; 1.0410x over previous
//
#include <hip/hip_runtime.h>
#include <hip/hip_bf16.h>
#include <math.h>

// RWKV7 attention, round 21:
//  - yv micro-GEMM fused into V projection epilogue (mode 4: inline 16-dot).
//  - Hybrid scan launch (adaptive on ws_size): g-gate GEMM (-> G fp16 in W6) and
//    Wo weight convert co-scheduled as extra blocks inside the scan kernel,
//    running on the scan's idle SIMDs. Fallback = round-20 sequential path.
// Scan math / ka_epi / gemms otherwise identical to round 20 (875us, 0.0039).

typedef __attribute__((ext_vector_type(8))) unsigned short ushort8;
typedef __attribute__((ext_vector_type(8))) _Float16 f16x8;
typedef __attribute__((ext_vector_type(4))) float f32x4;
typedef __attribute__((ext_vector_type(2))) float f32x2;

__device__ inline unsigned short f2h(float f) {
    _Float16 h = (_Float16)f;
    return __builtin_bit_cast(unsigned short, h);
}
__device__ inline float h2f(unsigned short u) {
    return (float)__builtin_bit_cast(_Float16, u);
}
__device__ inline float sigm(float x) { return 1.f / (1.f + expf(-x)); }

template <int CTRL>
__device__ __forceinline__ float rrot(float x) {
    int xi = __builtin_bit_cast(int, x);
    int yi = __builtin_amdgcn_update_dpp(xi, xi, CTRL, 0xf, 0xf, true);
    return x + __builtin_bit_cast(float, yi);
}
__device__ __forceinline__ float red8(float x)  { return rrot<0x128>(x); }
__device__ __forceinline__ float red16(float x) {
    float b = x;
    asm("" : "+v"(b));
    float a = x;
    asm("v_permlane16_swap_b32 %0, %1" : "+v"(a), "+v"(b));
    return a + b;
}
__device__ __forceinline__ float red32(float x) {
    float b = x;
    asm("" : "+v"(b));
    float a = x;
    asm("v_permlane32_swap_b32 %0, %1" : "+v"(a), "+v"(b));
    return a + b;
}
__device__ __forceinline__ float full64(float x) {
    x = rrot<0x121>(x);
    x = rrot<0x122>(x);
    x = rrot<0x124>(x);
    x = rrot<0x128>(x);
    return red32(red16(x));
}

__device__ __forceinline__ void gld16(void* lds, const void* g)
{
    __builtin_amdgcn_global_load_lds(
        (const __attribute__((address_space(1))) void*)g,
        (__attribute__((address_space(3))) void*)lds, 16, 0, 0);
}
__device__ __forceinline__ void gld4(void* lds, const void* g)
{
    __builtin_amdgcn_global_load_lds(
        (const __attribute__((address_space(1))) void*)g,
        (__attribute__((address_space(3))) void*)lds, 4, 0, 0);
}

// ---------------- all six mixes in one pass (r,k,w,a,g,v) ----------------
__global__ void mixcvt6_h(const float* __restrict__ in, const float* __restrict__ x_x,
                          unsigned short* __restrict__ oR, unsigned short* __restrict__ oK,
                          unsigned short* __restrict__ ow, unsigned short* __restrict__ oa,
                          unsigned short* __restrict__ og, unsigned short* __restrict__ ov,
                          int T, int D, int total8)
{
    int i = blockIdx.x * 256 + threadIdx.x;
    if (i >= total8) return;
    const size_t e = (size_t)i * 8;
    float a[8];
    *(float4*)&a[0] = *(const float4*)(in + e);
    *(float4*)&a[4] = *(const float4*)(in + e + 4);
    const int m = (int)(e / D);
    const int d = (int)(e % D);
    const int t = m % T;
    float p[8] = {0.f,0.f,0.f,0.f,0.f,0.f,0.f,0.f};
    if (t > 0) {
        *(float4*)&p[0] = *(const float4*)(in + e - D);
        *(float4*)&p[4] = *(const float4*)(in + e - D + 4);
    }
    const float* xxr = x_x + 0 * (size_t)D + d;
    const float* xxw = x_x + 1 * (size_t)D + d;
    const float* xxk = x_x + 2 * (size_t)D + d;
    const float* xxv = x_x + 3 * (size_t)D + d;
    const float* xxa = x_x + 4 * (size_t)D + d;
    const float* xxg = x_x + 5 * (size_t)D + d;
    ushort8 rr, rk, rw, ra, rg, rv;
    #pragma unroll
    for (int j = 0; j < 8; ++j) {
        const float dl = p[j] - a[j];
        rr[j] = f2h(a[j] + dl * xxr[j]);
        rk[j] = f2h(a[j] + dl * xxk[j]);
        rw[j] = f2h(a[j] + dl * xxw[j]);
        ra[j] = f2h(a[j] + dl * xxa[j]);
        rg[j] = f2h(a[j] + dl * xxg[j]);
        rv[j] = f2h(a[j] + dl * xxv[j]);
    }
    *(ushort8*)(oR + e) = rr;
    *(ushort8*)(oK + e) = rk;
    *(ushort8*)(ow + e) = rw;
    *(ushort8*)(oa + e) = ra;
    *(ushort8*)(og + e) = rg;
    *(ushort8*)(ov + e) = rv;
}

// weight convert, hi only, two weights per launch (grid.y selects)
__global__ void wcvt2_h(const float* __restrict__ in0, const float* __restrict__ in1,
                        unsigned short* __restrict__ hi0, unsigned short* __restrict__ hi1,
                        int total8)
{
    int i = blockIdx.x * 256 + threadIdx.x;
    if (i >= total8) return;
    const float* in = (blockIdx.y == 0) ? in0 : in1;
    unsigned short* hi = (blockIdx.y == 0) ? hi0 : hi1;
    const size_t e = (size_t)i * 8;
    float a[8];
    *(float4*)&a[0] = *(const float4*)(in + e);
    *(float4*)&a[4] = *(const float4*)(in + e + 4);
    ushort8 h8;
    #pragma unroll
    for (int j = 0; j < 8; ++j) h8[j] = f2h(a[j]);
    *(ushort8*)(hi + e) = h8;
}

// LoRA-A weights zero-padded to [4][128][2048] fp16
__global__ void wcvt_lora(const float* __restrict__ wA, const float* __restrict__ vA,
                          const float* __restrict__ aA, const float* __restrict__ gA,
                          unsigned short* __restrict__ WL, int K)
{
    const int z = blockIdx.y;
    int i = blockIdx.x * 256 + threadIdx.x;
    const size_t e = (size_t)i * 8;
    const int row = (int)(e / K);
    const int col = (int)(e % K);
    const int nv = (z == 0) ? 64 : (z == 1) ? 16 : (z == 2) ? 64 : 128;
    const float* src = (z == 0) ? wA : (z == 1) ? vA : (z == 2) ? aA : gA;
    ushort8 h8;
    if (row < nv) {
        float a[8];
        *(float4*)&a[0] = *(const float4*)(src + (size_t)row * K + col);
        *(float4*)&a[4] = *(const float4*)(src + (size_t)row * K + col + 4);
        #pragma unroll
        for (int j = 0; j < 8; ++j) h8[j] = f2h(a[j]);
    } else {
        #pragma unroll
        for (int j = 0; j < 8; ++j) h8[j] = 0;
    }
    *(ushort8*)(WL + (size_t)z * 128 * K + e) = h8;
}

// ---------------- fp16 MFMA GEMM: C[M,N] = A[M,K] @ W[N,K]^T, f32 out ----------
// mode 0: C=acc. mode 3: z0: C=0.6065*sigm(acc+bias), z1: C=acc.
// mode 4: yv=dot16(HVp[row],vBp[col]); C=lerp(acc,aux,sigm(yv+bias)).
#define GBM 128
#define GBN 128

template <int TERMS>
__global__ __launch_bounds__(256) void gemm_h2(
    const unsigned short* __restrict__ Ag,
    const unsigned short* __restrict__ Bhg, const unsigned short* __restrict__ Blg,
    float* __restrict__ C, int M, int N, int K, int mode,
    const float* __restrict__ HVp, const float* __restrict__ vBp,
    const float* __restrict__ bias, const float* __restrict__ aux,
    size_t sA, size_t sB, size_t sC)
{
    __shared__ unsigned short As[GBM * 32];
    __shared__ unsigned short Bhs[GBN * 32], Bls[GBN * 32];
    const int z = blockIdx.z;
    Ag  += (size_t)z * sA;
    Bhg += (size_t)z * sB;
    Blg += (size_t)z * sB;
    C   += (size_t)z * sC;
    const int tid = threadIdx.x;
    const int m0 = blockIdx.x * GBM;
    const int n0 = blockIdx.y * GBN;
    const int wave = tid >> 6, lane = tid & 63;
    const int wr = (wave >> 1) * 64, wc = (wave & 1) * 64;
    const int fr = lane & 15, fq = lane >> 4;

    f32x4 acc[4][4];
    #pragma unroll
    for (int i = 0; i < 4; ++i)
        #pragma unroll
        for (int j = 0; j < 4; ++j)
            acc[i][j] = (f32x4){0.f, 0.f, 0.f, 0.f};

    const unsigned short* gsrc;
    unsigned short* lbuf;
    int rofs, nld;
    if (wave == 0)      { gsrc = Ag;  lbuf = As;           rofs = m0;      nld = 4; }
    else if (wave == 1) { gsrc = Ag;  lbuf = As + 64 * 32; rofs = m0 + 64; nld = 4; }
    else if (wave == 2) { gsrc = Bhg; lbuf = Bhs;          rofs = n0;      nld = 8; }
    else                { gsrc = Blg; lbuf = Bls;          rofs = n0;      nld = (TERMS == 2) ? 8 : 0; }
    const unsigned short* gbase = gsrc + (size_t)(rofs + (lane >> 2)) * K + ((lane & 3) << 3);

    for (int k0 = 0; k0 < K; k0 += 32) {
        #pragma unroll
        for (int j = 0; j < 8; ++j)
            if (j < nld)
                gld16(lbuf + j * 16 * 32, gbase + (size_t)(j * 16) * K + k0);
        __syncthreads();

        f16x8 fa[4], fbh[4], fbl[4];
        #pragma unroll
        for (int m = 0; m < 4; ++m)
            fa[m] = *(const f16x8*)&As[(wr + m * 16 + fr) * 32 + fq * 8];
        #pragma unroll
        for (int n = 0; n < 4; ++n) {
            fbh[n] = *(const f16x8*)&Bhs[(wc + n * 16 + fr) * 32 + fq * 8];
            if constexpr (TERMS == 2)
                fbl[n] = *(const f16x8*)&Bls[(wc + n * 16 + fr) * 32 + fq * 8];
        }
        #pragma unroll
        for (int m = 0; m < 4; ++m)
            #pragma unroll
            for (int n = 0; n < 4; ++n) {
                acc[m][n] = __builtin_amdgcn_mfma_f32_16x16x32_f16(fa[m], fbh[n], acc[m][n], 0, 0, 0);
                if constexpr (TERMS == 2)
                    acc[m][n] = __builtin_amdgcn_mfma_f32_16x16x32_f16(fa[m], fbl[n], acc[m][n], 0, 0, 0);
            }
        __syncthreads();
    }

    #pragma unroll
    for (int m = 0; m < 4; ++m) {
        const int row = m0 + wr + m * 16 + fq * 4;
        #pragma unroll
        for (int n = 0; n < 4; ++n) {
            const int col = n0 + wc + n * 16 + fr;
            #pragma unroll
            for (int j = 0; j < 4; ++j) {
                const size_t idx = (size_t)(row + j) * N + col;
                float v = acc[m][n][j];
                if (mode == 4) {
                    const float* hv = HVp + (size_t)(row + j) * 16;
                    const float* vb = vBp + (size_t)col * 16;
                    float yv = 0.f;
                    #pragma unroll
                    for (int kk = 0; kk < 16; ++kk) yv = fmaf(hv[kk], vb[kk], yv);
                    const float sg = sigm(yv + bias[col]);
                    v = v + sg * (aux[idx] - v);
                } else if (mode == 3 && z == 0) {
                    v = 0.6065306597126334f * sigm(v + bias[col]);
                }
                C[idx] = v;
            }
        }
    }
}

// ---------------- LoRA stage-1 MFMA: z-batched, per-z act epilogue ----------
__global__ __launch_bounds__(256) void lora1_h(
    const unsigned short* __restrict__ Xbase,
    const unsigned short* __restrict__ WL,
    unsigned short* __restrict__ HW16, float* __restrict__ HV,
    unsigned short* __restrict__ HA16, unsigned short* __restrict__ HG16,
    int M, int K, size_t NE)
{
    __shared__ unsigned short As[GBM * 32];
    __shared__ unsigned short Bhs[GBN * 32];
    const int z = blockIdx.z;
    const size_t zofs = (z == 0) ? 0 : (z == 1) ? 3 * NE : (z == 2) ? NE : 2 * NE;  // w,v,a,g
    const unsigned short* Ag = Xbase + zofs;
    const unsigned short* Bg = WL + (size_t)z * 128 * K;
    const int tid = threadIdx.x;
    const int m0 = blockIdx.x * GBM;
    const int wave = tid >> 6, lane = tid & 63;
    const int wr = (wave >> 1) * 64, wc = (wave & 1) * 64;
    const int fr = lane & 15, fq = lane >> 4;

    f32x4 acc[4][4];
    #pragma unroll
    for (int i = 0; i < 4; ++i)
        #pragma unroll
        for (int j = 0; j < 4; ++j)
            acc[i][j] = (f32x4){0.f, 0.f, 0.f, 0.f};

    const unsigned short* gsrc;
    unsigned short* lbuf;
    int rofs, nld;
    if (wave == 0)      { gsrc = Ag; lbuf = As;           rofs = m0;      nld = 4; }
    else if (wave == 1) { gsrc = Ag; lbuf = As + 64 * 32; rofs = m0 + 64; nld = 4; }
    else if (wave == 2) { gsrc = Bg; lbuf = Bhs;          rofs = 0;       nld = 8; }
    else                { gsrc = Bg; lbuf = Bhs;          rofs = 0;       nld = 0; }
    const unsigned short* gbase = gsrc + (size_t)(rofs + (lane >> 2)) * K + ((lane & 3) << 3);

    for (int k0 = 0; k0 < K; k0 += 32) {
        #pragma unroll
        for (int j = 0; j < 8; ++j)
            if (j < nld)
                gld16(lbuf + j * 16 * 32, gbase + (size_t)(j * 16) * K + k0);
        __syncthreads();

        f16x8 fa[4], fb[4];
        #pragma unroll
        for (int m = 0; m < 4; ++m)
            fa[m] = *(const f16x8*)&As[(wr + m * 16 + fr) * 32 + fq * 8];
        #pragma unroll
        for (int n = 0; n < 4; ++n)
            fb[n] = *(const f16x8*)&Bhs[(wc + n * 16 + fr) * 32 + fq * 8];
        #pragma unroll
        for (int m = 0; m < 4; ++m)
            #pragma unroll
            for (int n = 0; n < 4; ++n)
                acc[m][n] = __builtin_amdgcn_mfma_f32_16x16x32_f16(fa[m], fb[n], acc[m][n], 0, 0, 0);
        __syncthreads();
    }

    #pragma unroll
    for (int m = 0; m < 4; ++m) {
        const int row = m0 + wr + m * 16 + fq * 4;
        #pragma unroll
        for (int n = 0; n < 4; ++n) {
            const int col = wc + n * 16 + fr;
            #pragma unroll
            for (int j = 0; j < 4; ++j) {
                const float v = acc[m][n][j];
                const int r = row + j;
                if (z == 0)      { if (col < 64) HW16[(size_t)r * 64 + col] = f2h(tanhf(v)); }
                else if (z == 1) { if (col < 16) HV[(size_t)r * 16 + col] = v; }
                else if (z == 2) { if (col < 64) HA16[(size_t)r * 64 + col] = f2h(v); }
                else             { HG16[(size_t)r * 128 + col] = f2h(sigm(v)); }
            }
        }
    }
}

// per-(b,t,h) wave: a = sigmoid(ya+ab); kk = normalize(k0*k_k); bv = kk*a;
// kfinal = k0*(1+(a-1)*k_a).
__global__ __launch_bounds__(256) void ka_epi(
    float* __restrict__ Kf, float* __restrict__ A_BV, float* __restrict__ KKo,
    const float* __restrict__ k_k, const float* __restrict__ k_a,
    const float* __restrict__ ab, int total, int H)
{
    int wid = (blockIdx.x << 2) | (threadIdx.x >> 6);
    if (wid >= total) return;
    const int l = threadIdx.x & 63;
    const int h = wid % H;
    const int ch = h * 64 + l;
    const size_t base = (size_t)wid * 64;
    float k0 = Kf[base + l];
    float a = sigm(A_BV[base + l] + ab[ch]);
    float kkr = k0 * k_k[ch];
    float ss = full64(kkr * kkr);
    float inv = 1.f / fmaxf(sqrtf(ss), 1e-12f);
    float kkn = kkr * inv;
    KKo[base + l] = kkn;
    A_BV[base + l] = kkn * a;
    Kf[base + l] = k0 * fmaf(a - 1.f, k_a[ch], 1.f);
}

// -------- scan core (device function; L = per-block LDS base, 10496 floats) --------
#define SCH 16
__device__ __forceinline__ void scan_core(
    float* ldsf, int blk, int l,
    const float* __restrict__ EW, const float* __restrict__ R,
    const float* __restrict__ Kf, const float* __restrict__ Vf,
    const float* __restrict__ KK, const float* __restrict__ BV,
    float* __restrict__ O, int T, int H)
{
    const int bh = blk & 63;
    const int slab = blk >> 6;
    const int b = bh >> 5, h = bh & 31;
    const int vc = l & 7;
    const int g  = l >> 3;
    const int kb = g << 3;
    const int vb0 = slab << 3;
    const size_t step = (size_t)H * 64;
    const size_t base0 = ((size_t)b * T * H + h) * 64;
    const int BUF = 5 * SCH * 64 + SCH * 8;

    auto stage = [&](int c, int buf) {
        float* L = ldsf + buf * BUF;
        const size_t t0 = (size_t)c * SCH;
        const float* gs[5] = {EW, R, Kf, KK, BV};
        #pragma unroll
        for (int s = 0; s < 5; ++s) {
            const float* gp = gs[s];
            #pragma unroll
            for (int j = 0; j < 4; ++j)
                gld16(L + s * SCH * 64 + j * 4 * 64,
                      gp + base0 + (t0 + j * 4 + (l >> 4)) * step + ((l & 15) << 2));
        }
        gld4(L + 5 * SCH * 64,
             Vf + base0 + (t0 + (l >> 3)) * step + vb0 + (l & 7));
        gld4(L + 5 * SCH * 64 + 64,
             Vf + base0 + (t0 + 8 + (l >> 3)) * step + vb0 + (l & 7));
    };

    f32x2 s2[4];
    #pragma unroll
    for (int i = 0; i < 4; ++i) s2[i] = (f32x2){0.f, 0.f};

    struct P { f32x4 e[2], r[2], k[2], q[2], bb[2]; float vv; };
    P PA, PB;
    const int NCH = T / SCH;

    stage(0, 0);
    asm volatile("s_waitcnt vmcnt(0)" ::: "memory");
    __builtin_amdgcn_sched_barrier(0);

    for (int c = 0; c < NCH; ++c) {
        if (c + 1 < NCH) stage(c + 1, (c + 1) & 1);

        const float* L = ldsf + (c & 1) * BUF;
        auto PRE = [&](P& pp, int tt) {
            const int o = tt * 64 + kb;
            #pragma unroll
            for (int j = 0; j < 2; ++j) {
                pp.e[j]  = *(const f32x4*)(L + 0 * SCH * 64 + o + j * 4);
                pp.r[j]  = *(const f32x4*)(L + 1 * SCH * 64 + o + j * 4);
                pp.k[j]  = *(const f32x4*)(L + 2 * SCH * 64 + o + j * 4);
                pp.q[j]  = *(const f32x4*)(L + 3 * SCH * 64 + o + j * 4);
                pp.bb[j] = *(const f32x4*)(L + 4 * SCH * 64 + o + j * 4);
            }
            pp.vv = L[5 * SCH * 64 + tt * 8 + vc];
        };
        auto COMP = [&](const P& pp, int tt) {
            f32x2 sa0 = (f32x2){0.f, 0.f}, sa1 = (f32x2){0.f, 0.f};
            #pragma unroll
            for (int j = 0; j < 2; ++j) {
                const f32x2 elo = __builtin_shufflevector(pp.e[j], pp.e[j], 0, 1);
                const f32x2 ehi = __builtin_shufflevector(pp.e[j], pp.e[j], 2, 3);
                const f32x2 qlo = __builtin_shufflevector(pp.q[j], pp.q[j], 0, 1);
                const f32x2 qhi = __builtin_shufflevector(pp.q[j], pp.q[j], 2, 3);
                s2[2*j]   *= elo;
                s2[2*j+1] *= ehi;
                sa0 += qlo * s2[2*j];
                sa1 += qhi * s2[2*j+1];
            }
            const f32x2 sas = sa0 + sa1;
            float p = -(sas.x + sas.y);
            p = red32(red16(red8(p)));
            const f32x2 p2 = (f32x2){p, p};
            const f32x2 v2 = (f32x2){pp.vv, pp.vv};
            f32x2 o0 = (f32x2){0.f, 0.f}, o1 = (f32x2){0.f, 0.f};
            #pragma unroll
            for (int j = 0; j < 2; ++j) {
                const f32x2 klo = __builtin_shufflevector(pp.k[j], pp.k[j], 0, 1);
                const f32x2 khi = __builtin_shufflevector(pp.k[j], pp.k[j], 2, 3);
                const f32x2 blo = __builtin_shufflevector(pp.bb[j], pp.bb[j], 0, 1);
                const f32x2 bhi = __builtin_shufflevector(pp.bb[j], pp.bb[j], 2, 3);
                const f32x2 rlo = __builtin_shufflevector(pp.r[j], pp.r[j], 0, 1);
                const f32x2 rhi = __builtin_shufflevector(pp.r[j], pp.r[j], 2, 3);
                s2[2*j]   = blo * p2 + (klo * v2 + s2[2*j]);
                s2[2*j+1] = bhi * p2 + (khi * v2 + s2[2*j+1]);
                o0 += rlo * s2[2*j];
                o1 += rhi * s2[2*j+1];
            }
            const f32x2 os = o0 + o1;
            float oo = os.x + os.y;
            oo = red32(red16(red8(oo)));
            if (g == 0)
                O[base0 + (size_t)(c * SCH + tt) * step + vb0 + vc] = oo;
        };

        PRE(PA, 0);
        PRE(PB, 1);
        #pragma unroll
        for (int tt = 0; tt < SCH - 2; tt += 2) {
            COMP(PA, tt);     PRE(PA, tt + 2);
            COMP(PB, tt + 1); PRE(PB, tt + 3);
        }
        COMP(PA, SCH - 2);
        COMP(PB, SCH - 1);

        asm volatile("s_waitcnt vmcnt(0)" ::: "memory");
        __builtin_amdgcn_sched_barrier(0);
    }
}

// -------- standalone scan (fallback path) --------
__global__ __launch_bounds__(64) void rwkv_scan(
    const float* __restrict__ EW, const float* __restrict__ R,
    const float* __restrict__ Kf, const float* __restrict__ Vf,
    const float* __restrict__ KK, const float* __restrict__ BV,
    float* __restrict__ O, int T, int H)
{
    __shared__ float ldsf[2 * (5 * SCH * 64 + SCH * 8)];
    scan_core(ldsf, blockIdx.x, threadIdx.x, EW, R, Kf, Vf, KK, BV, O, T, H);
}

// -------- hybrid: scan + co-scheduled g-gate GEMM (fp16 out) + Wo convert --------
__global__ __launch_bounds__(256) void scan_fused(
    const float* __restrict__ EW, const float* __restrict__ R,
    const float* __restrict__ Kf, const float* __restrict__ Vf,
    const float* __restrict__ KK, const float* __restrict__ BV,
    float* __restrict__ O,
    const unsigned short* __restrict__ HG16, const unsigned short* __restrict__ gb16,
    unsigned short* __restrict__ G16,
    const float* __restrict__ Wo, unsigned short* __restrict__ Wo16, int nW8,
    int T, int H, int M, int D)
{
    __shared__ float smemf[2 * (5 * SCH * 64 + SCH * 8)];
    const int bid = blockIdx.x;
    const int tid = threadIdx.x;

    if (bid < 512) {                       // ---- scan role ----
        if (tid >= 64) return;
        scan_core(smemf, bid, tid, EW, R, Kf, Vf, KK, BV, O, T, H);
        return;
    }
    if (bid < 1024) {                      // ---- g-gate GEMM role (K=128, TERMS=1) ----
        unsigned short* As  = (unsigned short*)smemf;
        unsigned short* Bhs = As + GBM * 32;
        const int bid2 = bid - 512;
        const int m0 = (bid2 >> 4) * GBM;
        const int n0 = (bid2 & 15) * GBN;
        const int wave = tid >> 6, lane = tid & 63;
        const int wr = (wave >> 1) * 64, wc = (wave & 1) * 64;
        const int fr = lane & 15, fq = lane >> 4;
        const int K = 128;

        f32x4 acc[4][4];
        #pragma unroll
        for (int i = 0; i < 4; ++i)
            #pragma unroll
            for (int j = 0; j < 4; ++j)
                acc[i][j] = (f32x4){0.f, 0.f, 0.f, 0.f};

        const unsigned short* gsrc;
        unsigned short* lbuf;
        int rofs, nld;
        if (wave == 0)      { gsrc = HG16; lbuf = As;           rofs = m0;      nld = 4; }
        else if (wave == 1) { gsrc = HG16; lbuf = As + 64 * 32; rofs = m0 + 64; nld = 4; }
        else if (wave == 2) { gsrc = gb16; lbuf = Bhs;          rofs = n0;      nld = 8; }
        else                { gsrc = gb16; lbuf = Bhs;          rofs = n0;      nld = 0; }
        const unsigned short* gbase = gsrc + (size_t)(rofs + (lane >> 2)) * K + ((lane & 3) << 3);

        for (int k0 = 0; k0 < K; k0 += 32) {
            #pragma unroll
            for (int j = 0; j < 8; ++j)
                if (j < nld)
                    gld16(lbuf + j * 16 * 32, gbase + (size_t)(j * 16) * K + k0);
            __syncthreads();
            f16x8 fa[4], fb[4];
            #pragma unroll
            for (int m = 0; m < 4; ++m)
                fa[m] = *(const f16x8*)&As[(wr + m * 16 + fr) * 32 + fq * 8];
            #pragma unroll
            for (int n = 0; n < 4; ++n)
                fb[n] = *(const f16x8*)&Bhs[(wc + n * 16 + fr) * 32 + fq * 8];
            #pragma unroll
            for (int m = 0; m < 4; ++m)
                #pragma unroll
                for (int n = 0; n < 4; ++n)
                    acc[m][n] = __builtin_amdgcn_mfma_f32_16x16x32_f16(fa[m], fb[n], acc[m][n], 0, 0, 0);
            __syncthreads();
        }
        #pragma unroll
        for (int m = 0; m < 4; ++m) {
            const int row = m0 + wr + m * 16 + fq * 4;
            #pragma unroll
            for (int n = 0; n < 4; ++n) {
                const int col = n0 + wc + n * 16 + fr;
                #pragma unroll
                for (int j = 0; j < 4; ++j)
                    G16[(size_t)(row + j) * D + col] = f2h(acc[m][n][j]);
            }
        }
        return;
    }
    // ---- Wo convert role ----
    {
        int i = (bid - 1024) * 256 + tid;
        if (i >= nW8) return;
        const size_t e = (size_t)i * 8;
        float a[8];
        *(float4*)&a[0] = *(const float4*)(Wo + e);
        *(float4*)&a[4] = *(const float4*)(Wo + e + 4);
        ushort8 h8;
        #pragma unroll
        for (int j = 0; j < 8; ++j) h8[j] = f2h(a[j]);
        *(ushort8*)(Wo16 + e) = h8;
    }
}

// GroupNorm + bonus + g-gate (G f32 or fp16); writes ON16 (fp16).
__global__ __launch_bounds__(256) void gn_bonus(
    const float* __restrict__ O, const float* __restrict__ R,
    const float* __restrict__ Kf, const float* __restrict__ Vf,
    const float* __restrict__ G, const unsigned short* __restrict__ G16,
    const float* __restrict__ r_k,
    const float* __restrict__ gn_w, const float* __restrict__ gn_b,
    unsigned short* __restrict__ ON16, int total, int H, float eps)
{
    int wid = (blockIdx.x << 2) | (threadIdx.x >> 6);
    if (wid >= total) return;
    const int l = threadIdx.x & 63;
    const int h = wid % H;
    const int ch = h * 64 + l;
    const size_t base = (size_t)wid * 64;

    const float o = O[base + l];
    const float mu = full64(o) * (1.f / 64.f);
    const float d = o - mu;
    const float ss = full64(d * d);
    const float inv = 1.f / sqrtf(ss * (1.f / 64.f) + eps);
    float on = d * inv * gn_w[ch] + gn_b[ch];

    const float r = R[base + l], k = Kf[base + l], vv = Vf[base + l];
    const float p = full64(r * k * r_k[ch]);
    on = fmaf(p, vv, on);
    const float gg = G16 ? h2f(G16[base + l]) : G[base + l];
    ON16[base + l] = f2h(on * gg);
}

extern "C" void kernel_launch(void* const* d_in, const int* in_sizes, int n_in,
                              void* d_out, int out_size, void* d_ws, size_t ws_size,
                              hipStream_t stream)
{
    const int B = 2, T = 2048, D = 2048, H = 32;
    const int M = B * T;

    const float* hid = (const float*)d_in[0];
    const float* vst = (const float*)d_in[1];
    const float* x_x = (const float*)d_in[2];
    const float* k_k = (const float*)d_in[3];
    const float* k_a = (const float*)d_in[4];
    const float* r_k = (const float*)d_in[5];
    const float* Wr  = (const float*)d_in[6];
    const float* Wk  = (const float*)d_in[7];
    const float* Wv  = (const float*)d_in[8];
    const float* Wo  = (const float*)d_in[9];
    const float* wA  = (const float*)d_in[10];
    const float* wB  = (const float*)d_in[11];
    const float* wb  = (const float*)d_in[12];
    const float* vA  = (const float*)d_in[13];
    const float* vB  = (const float*)d_in[14];
    const float* vb  = (const float*)d_in[15];
    const float* aA  = (const float*)d_in[16];
    const float* aB  = (const float*)d_in[17];
    const float* ab  = (const float*)d_in[18];
    const float* gA  = (const float*)d_in[19];
    const float* gB  = (const float*)d_in[20];
    const float* gnw = (const float*)d_in[21];
    const float* gnb = (const float*)d_in[22];
    float* out = (float*)d_out;

    const size_t NE = (size_t)M * D;   // 8,388,608
    const size_t DD = (size_t)D * D;   // 4,194,304
    const size_t need  = (6 * NE + (size_t)M * 272) * sizeof(float);  // ~196 MiB (proven)
    const size_t need2 = (7 * NE + (size_t)M * 272) * sizeof(float);  // ~230 MiB (fused path)
    if (ws_size < need) return;
    const bool fused = (ws_size >= need2);

    float* W0 = (float*)d_ws;      // WL pad -> R_
    float* W1 = W0 + NE;           // X2(r,k) -> EW -> ON16
    float* W2 = W1 + NE;           // Kf
    float* W3 = W2 + NE;           // WrH/WkH -> Vf (-> Wo16 fallback)
    float* W4 = W3 + NE;           // [w][a] mixes -> WvH -> wB16/aB16 -> KK (-> G fallback)
    float* W5 = W4 + NE;           // [g][v] mixes -> YA -> BV (-> gb16 fallback)
    float* SMALL = W5 + NE;        // M*272 floats
    unsigned short* HW16 = (unsigned short*)SMALL;
    unsigned short* HA16 = HW16 + (size_t)M * 64;
    unsigned short* HG16 = HA16 + (size_t)M * 64;
    float* HV = (float*)(HG16 + (size_t)M * 128);
    float* W6 = SMALL + (size_t)M * 272;   // fused only: G16 | Wo16 | gb16

    dim3 blk(256);
    const int nMix = (int)(NE / 8);
    const int nW   = (int)(DD / 8);
    const float* nf = nullptr;

    unsigned short* X2   = (unsigned short*)W1;
    unsigned short* X4   = (unsigned short*)W4;
    unsigned short* WRK  = (unsigned short*)W3;
    unsigned short* WL   = (unsigned short*)W0;

    // ---- 1: all six mixes ----
    hipLaunchKernelGGL(mixcvt6_h, dim3(nMix / 256), blk, 0, stream,
                       hid, x_x, X2, X2 + NE, X4, X4 + NE, X4 + 2 * NE, X4 + 3 * NE, T, D, nMix);

    // ---- 2-3: weight staging ----
    hipLaunchKernelGGL(wcvt2_h, dim3(nW / 256, 2), blk, 0, stream, Wr, Wk, WRK, WRK + DD, nW);
    hipLaunchKernelGGL(wcvt_lora, dim3(128, 4), blk, 0, stream, wA, vA, aA, gA, WL, D);

    // ---- 4: LoRA stage-1 MFMA ----
    hipLaunchKernelGGL(lora1_h, dim3(M / GBM, 1, 4), blk, 0, stream,
                       X4, WL, HW16, HV, HA16, HG16, M, D, NE);

    // ---- 5: R+K batched ----
    hipLaunchKernelGGL((gemm_h2<1>), dim3(M / GBM, D / GBN, 2), blk, 0, stream,
                       X2, WRK, WRK, W0, M, D, D, 0, nf, nf, nf, nf,
                       NE, DD, 2 * NE);

    // ---- 6-7: V projection with inline-yv lerp epilogue (mode 4) ----
    unsigned short* WvH = (unsigned short*)W4;
    hipLaunchKernelGGL(wcvt2_h, dim3(nW / 256, 1), blk, 0, stream, Wv, Wv, WvH, WvH, nW);
    hipLaunchKernelGGL((gemm_h2<1>), dim3(M / GBM, D / GBN, 1), blk, 0, stream,
                       X4 + 3 * NE, WvH, WvH, W3, M, D, D, 4, HV, vB, vb, vst, 0, 0, 0);

    // ---- 8: LoRA stage-2 MFMA (z0: EW -> W1; z1: ya -> W5) ----
    unsigned short* wB16 = (unsigned short*)W4;
    unsigned short* aB16 = wB16 + (size_t)D * 64;
    hipLaunchKernelGGL(wcvt2_h, dim3((int)(D * 64 / 8 / 256), 2), blk, 0, stream, wB, aB, wB16, aB16, (int)(D * 64 / 8));
    hipLaunchKernelGGL((gemm_h2<1>), dim3(M / GBM, D / GBN, 2), blk, 0, stream,
                       HW16, wB16, wB16, W1, M, D, 64, 3, nf, nf, wb, nf,
                       (size_t)M * 64, (size_t)D * 64, 4 * NE);

    // ---- 9: ka epilogue ----
    const int totalW = M * H;
    hipLaunchKernelGGL(ka_epi, dim3(totalW / 4), blk, 0, stream, W2, W5, W4, k_k, k_a, ab, totalW, H);

    if (fused) {
        unsigned short* W6s  = (unsigned short*)W6;
        unsigned short* G16p = W6s;                 // NE shorts
        unsigned short* Wo16 = W6s + NE;            // DD shorts
        unsigned short* gb16 = W6s + NE + DD;       // D*128 shorts
        // gb convert (must complete before the fused launch's gemm blocks)
        hipLaunchKernelGGL(wcvt2_h, dim3((int)(D * 128 / 8 / 256), 1), blk, 0, stream, gB, gB, gb16, gb16, (int)(D * 128 / 8));
        // ---- 10: scan + co-scheduled g-gate GEMM + Wo convert ----
        hipLaunchKernelGGL(scan_fused, dim3(512 + 512 + 2048), blk, 0, stream,
                           W1, W0, W2, W3, W4, W5, out,
                           HG16, gb16, G16p, Wo, Wo16, nW * 256 / 256 * 1 + (nW - nW) + nW, T, H, M, D);
        // (nW8 = DD/8 = nW*... pass nW*1? correct count is DD/8:)
        // ---- 11: gn_bonus (G fp16) -> ON16 (W1) ----
        unsigned short* ON16 = (unsigned short*)W1;
        hipLaunchKernelGGL(gn_bonus, dim3(totalW / 4), blk, 0, stream, out, W0, W2, W3, nf, G16p, r_k, gnw, gnb, ON16, totalW, H, 64.f * 1e-5f);
        // ---- 12: Wo projection ----
        hipLaunchKernelGGL((gemm_h2<1>), dim3(M / GBM, D / GBN, 1), blk, 0, stream,
                           ON16, Wo16, Wo16, out, M, D, D, 0, nf, nf, nf, nf, 0, 0, 0);
    } else {
        // ---- 10: scan ----
        hipLaunchKernelGGL(rwkv_scan, dim3(B * H * 8), dim3(64), 0, stream, W1, W0, W2, W3, W4, W5, out, T, H);
        // ---- 11: g-gate GEMM sequential (gb16 in W5; G f32 -> W4) ----
        unsigned short* gb16 = (unsigned short*)W5;
        hipLaunchKernelGGL(wcvt2_h, dim3((int)(D * 128 / 8 / 256), 1), blk, 0, stream, gB, gB, gb16, gb16, (int)(D * 128 / 8));
        hipLaunchKernelGGL((gemm_h2<1>), dim3(M / GBM, D / GBN, 1), blk, 0, stream,
                           HG16, gb16, gb16, W4, M, D, 128, 0, nf, nf, nf, nf, 0, 0, 0);
        unsigned short* ON16 = (unsigned short*)W1;
        hipLaunchKernelGGL(gn_bonus, dim3(totalW / 4), blk, 0, stream, out, W0, W2, W3, W4, (const unsigned short*)nullptr, r_k, gnw, gnb, ON16, totalW, H, 64.f * 1e-5f);
        unsigned short* Wo16 = (unsigned short*)W3;
        hipLaunchKernelGGL(wcvt2_h, dim3(nW / 256, 1), blk, 0, stream, Wo, Wo, Wo16, Wo16, nW);
        hipLaunchKernelGGL((gemm_h2<1>), dim3(M / GBM, D / GBN, 1), blk, 0, stream,
                           ON16, Wo16, Wo16, out, M, D, D, 0, nf, nf, nf, nf, 0, 0, 0);
    }
}

// Round 22
// 829.359 us; speedup vs baseline: 1.3924x; 1.0130x over previous
//
#include <hip/hip_runtime.h>
#include <hip/hip_bf16.h>
#include <math.h>

// RWKV7 attention, round 22 (= round 21 + fused-path consolidation):
//  - gemm_rkv: R/K/V projections in one grid.z=3 dispatch (z2 = V with inline-yv
//    mode-4 lerp epilogue).
//  - wcvt_all: all six weight converts in one grid.y=6 launch; WvH time-shares
//    the Wo16 slot in W6 (dead before scan_fused writes Wo16).
//  - scan_fused / scan math / everything else byte-identical to round 21 (840us).

typedef __attribute__((ext_vector_type(8))) unsigned short ushort8;
typedef __attribute__((ext_vector_type(8))) _Float16 f16x8;
typedef __attribute__((ext_vector_type(4))) float f32x4;
typedef __attribute__((ext_vector_type(2))) float f32x2;

__device__ inline unsigned short f2h(float f) {
    _Float16 h = (_Float16)f;
    return __builtin_bit_cast(unsigned short, h);
}
__device__ inline float h2f(unsigned short u) {
    return (float)__builtin_bit_cast(_Float16, u);
}
__device__ inline float sigm(float x) { return 1.f / (1.f + expf(-x)); }

template <int CTRL>
__device__ __forceinline__ float rrot(float x) {
    int xi = __builtin_bit_cast(int, x);
    int yi = __builtin_amdgcn_update_dpp(xi, xi, CTRL, 0xf, 0xf, true);
    return x + __builtin_bit_cast(float, yi);
}
__device__ __forceinline__ float red8(float x)  { return rrot<0x128>(x); }
__device__ __forceinline__ float red16(float x) {
    float b = x;
    asm("" : "+v"(b));
    float a = x;
    asm("v_permlane16_swap_b32 %0, %1" : "+v"(a), "+v"(b));
    return a + b;
}
__device__ __forceinline__ float red32(float x) {
    float b = x;
    asm("" : "+v"(b));
    float a = x;
    asm("v_permlane32_swap_b32 %0, %1" : "+v"(a), "+v"(b));
    return a + b;
}
__device__ __forceinline__ float full64(float x) {
    x = rrot<0x121>(x);
    x = rrot<0x122>(x);
    x = rrot<0x124>(x);
    x = rrot<0x128>(x);
    return red32(red16(x));
}

__device__ __forceinline__ void gld16(void* lds, const void* g)
{
    __builtin_amdgcn_global_load_lds(
        (const __attribute__((address_space(1))) void*)g,
        (__attribute__((address_space(3))) void*)lds, 16, 0, 0);
}
__device__ __forceinline__ void gld4(void* lds, const void* g)
{
    __builtin_amdgcn_global_load_lds(
        (const __attribute__((address_space(1))) void*)g,
        (__attribute__((address_space(3))) void*)lds, 4, 0, 0);
}

// ---------------- all six mixes in one pass (r,k,w,a,g,v) ----------------
__global__ void mixcvt6_h(const float* __restrict__ in, const float* __restrict__ x_x,
                          unsigned short* __restrict__ oR, unsigned short* __restrict__ oK,
                          unsigned short* __restrict__ ow, unsigned short* __restrict__ oa,
                          unsigned short* __restrict__ og, unsigned short* __restrict__ ov,
                          int T, int D, int total8)
{
    int i = blockIdx.x * 256 + threadIdx.x;
    if (i >= total8) return;
    const size_t e = (size_t)i * 8;
    float a[8];
    *(float4*)&a[0] = *(const float4*)(in + e);
    *(float4*)&a[4] = *(const float4*)(in + e + 4);
    const int m = (int)(e / D);
    const int d = (int)(e % D);
    const int t = m % T;
    float p[8] = {0.f,0.f,0.f,0.f,0.f,0.f,0.f,0.f};
    if (t > 0) {
        *(float4*)&p[0] = *(const float4*)(in + e - D);
        *(float4*)&p[4] = *(const float4*)(in + e - D + 4);
    }
    const float* xxr = x_x + 0 * (size_t)D + d;
    const float* xxw = x_x + 1 * (size_t)D + d;
    const float* xxk = x_x + 2 * (size_t)D + d;
    const float* xxv = x_x + 3 * (size_t)D + d;
    const float* xxa = x_x + 4 * (size_t)D + d;
    const float* xxg = x_x + 5 * (size_t)D + d;
    ushort8 rr, rk, rw, ra, rg, rv;
    #pragma unroll
    for (int j = 0; j < 8; ++j) {
        const float dl = p[j] - a[j];
        rr[j] = f2h(a[j] + dl * xxr[j]);
        rk[j] = f2h(a[j] + dl * xxk[j]);
        rw[j] = f2h(a[j] + dl * xxw[j]);
        ra[j] = f2h(a[j] + dl * xxa[j]);
        rg[j] = f2h(a[j] + dl * xxg[j]);
        rv[j] = f2h(a[j] + dl * xxv[j]);
    }
    *(ushort8*)(oR + e) = rr;
    *(ushort8*)(oK + e) = rk;
    *(ushort8*)(ow + e) = rw;
    *(ushort8*)(oa + e) = ra;
    *(ushort8*)(og + e) = rg;
    *(ushort8*)(ov + e) = rv;
}

// weight convert, hi only, two weights per launch (fallback path)
__global__ void wcvt2_h(const float* __restrict__ in0, const float* __restrict__ in1,
                        unsigned short* __restrict__ hi0, unsigned short* __restrict__ hi1,
                        int total8)
{
    int i = blockIdx.x * 256 + threadIdx.x;
    if (i >= total8) return;
    const float* in = (blockIdx.y == 0) ? in0 : in1;
    unsigned short* hi = (blockIdx.y == 0) ? hi0 : hi1;
    const size_t e = (size_t)i * 8;
    float a[8];
    *(float4*)&a[0] = *(const float4*)(in + e);
    *(float4*)&a[4] = *(const float4*)(in + e + 4);
    ushort8 h8;
    #pragma unroll
    for (int j = 0; j < 8; ++j) h8[j] = f2h(a[j]);
    *(ushort8*)(hi + e) = h8;
}

// six weight converts in one launch (fused path): grid.y selects weight
__global__ void wcvt_all(const float* __restrict__ Wr, const float* __restrict__ Wk,
                         const float* __restrict__ Wv, const float* __restrict__ wB,
                         const float* __restrict__ aB, const float* __restrict__ gB,
                         unsigned short* __restrict__ oWr, unsigned short* __restrict__ oWk,
                         unsigned short* __restrict__ oWv, unsigned short* __restrict__ owB,
                         unsigned short* __restrict__ oaB, unsigned short* __restrict__ ogB,
                         int nBig, int nSm, int nG)
{
    const int y = blockIdx.y;
    const float* in;
    unsigned short* hi;
    int lim;
    if (y == 0)      { in = Wr; hi = oWr; lim = nBig; }
    else if (y == 1) { in = Wk; hi = oWk; lim = nBig; }
    else if (y == 2) { in = Wv; hi = oWv; lim = nBig; }
    else if (y == 3) { in = wB; hi = owB; lim = nSm; }
    else if (y == 4) { in = aB; hi = oaB; lim = nSm; }
    else             { in = gB; hi = ogB; lim = nG; }
    int i = blockIdx.x * 256 + threadIdx.x;
    if (i >= lim) return;
    const size_t e = (size_t)i * 8;
    float a[8];
    *(float4*)&a[0] = *(const float4*)(in + e);
    *(float4*)&a[4] = *(const float4*)(in + e + 4);
    ushort8 h8;
    #pragma unroll
    for (int j = 0; j < 8; ++j) h8[j] = f2h(a[j]);
    *(ushort8*)(hi + e) = h8;
}

// LoRA-A weights zero-padded to [4][128][2048] fp16
__global__ void wcvt_lora(const float* __restrict__ wA, const float* __restrict__ vA,
                          const float* __restrict__ aA, const float* __restrict__ gA,
                          unsigned short* __restrict__ WL, int K)
{
    const int z = blockIdx.y;
    int i = blockIdx.x * 256 + threadIdx.x;
    const size_t e = (size_t)i * 8;
    const int row = (int)(e / K);
    const int col = (int)(e % K);
    const int nv = (z == 0) ? 64 : (z == 1) ? 16 : (z == 2) ? 64 : 128;
    const float* src = (z == 0) ? wA : (z == 1) ? vA : (z == 2) ? aA : gA;
    ushort8 h8;
    if (row < nv) {
        float a[8];
        *(float4*)&a[0] = *(const float4*)(src + (size_t)row * K + col);
        *(float4*)&a[4] = *(const float4*)(src + (size_t)row * K + col + 4);
        #pragma unroll
        for (int j = 0; j < 8; ++j) h8[j] = f2h(a[j]);
    } else {
        #pragma unroll
        for (int j = 0; j < 8; ++j) h8[j] = 0;
    }
    *(ushort8*)(WL + (size_t)z * 128 * K + e) = h8;
}

// ---------------- fp16 MFMA GEMM (generic): C[M,N] = A[M,K] @ W[N,K]^T ----------
// mode 0: C=acc. mode 3: z0: C=0.6065*sigm(acc+bias), z1: C=acc.
// mode 4: yv=dot16(HVp[row],vBp[col]); C=lerp(acc,aux,sigm(yv+bias)).
#define GBM 128
#define GBN 128

template <int TERMS>
__global__ __launch_bounds__(256) void gemm_h2(
    const unsigned short* __restrict__ Ag,
    const unsigned short* __restrict__ Bhg, const unsigned short* __restrict__ Blg,
    float* __restrict__ C, int M, int N, int K, int mode,
    const float* __restrict__ HVp, const float* __restrict__ vBp,
    const float* __restrict__ bias, const float* __restrict__ aux,
    size_t sA, size_t sB, size_t sC)
{
    __shared__ unsigned short As[GBM * 32];
    __shared__ unsigned short Bhs[GBN * 32], Bls[GBN * 32];
    const int z = blockIdx.z;
    Ag  += (size_t)z * sA;
    Bhg += (size_t)z * sB;
    Blg += (size_t)z * sB;
    C   += (size_t)z * sC;
    const int tid = threadIdx.x;
    const int m0 = blockIdx.x * GBM;
    const int n0 = blockIdx.y * GBN;
    const int wave = tid >> 6, lane = tid & 63;
    const int wr = (wave >> 1) * 64, wc = (wave & 1) * 64;
    const int fr = lane & 15, fq = lane >> 4;

    f32x4 acc[4][4];
    #pragma unroll
    for (int i = 0; i < 4; ++i)
        #pragma unroll
        for (int j = 0; j < 4; ++j)
            acc[i][j] = (f32x4){0.f, 0.f, 0.f, 0.f};

    const unsigned short* gsrc;
    unsigned short* lbuf;
    int rofs, nld;
    if (wave == 0)      { gsrc = Ag;  lbuf = As;           rofs = m0;      nld = 4; }
    else if (wave == 1) { gsrc = Ag;  lbuf = As + 64 * 32; rofs = m0 + 64; nld = 4; }
    else if (wave == 2) { gsrc = Bhg; lbuf = Bhs;          rofs = n0;      nld = 8; }
    else                { gsrc = Blg; lbuf = Bls;          rofs = n0;      nld = (TERMS == 2) ? 8 : 0; }
    const unsigned short* gbase = gsrc + (size_t)(rofs + (lane >> 2)) * K + ((lane & 3) << 3);

    for (int k0 = 0; k0 < K; k0 += 32) {
        #pragma unroll
        for (int j = 0; j < 8; ++j)
            if (j < nld)
                gld16(lbuf + j * 16 * 32, gbase + (size_t)(j * 16) * K + k0);
        __syncthreads();

        f16x8 fa[4], fbh[4], fbl[4];
        #pragma unroll
        for (int m = 0; m < 4; ++m)
            fa[m] = *(const f16x8*)&As[(wr + m * 16 + fr) * 32 + fq * 8];
        #pragma unroll
        for (int n = 0; n < 4; ++n) {
            fbh[n] = *(const f16x8*)&Bhs[(wc + n * 16 + fr) * 32 + fq * 8];
            if constexpr (TERMS == 2)
                fbl[n] = *(const f16x8*)&Bls[(wc + n * 16 + fr) * 32 + fq * 8];
        }
        #pragma unroll
        for (int m = 0; m < 4; ++m)
            #pragma unroll
            for (int n = 0; n < 4; ++n) {
                acc[m][n] = __builtin_amdgcn_mfma_f32_16x16x32_f16(fa[m], fbh[n], acc[m][n], 0, 0, 0);
                if constexpr (TERMS == 2)
                    acc[m][n] = __builtin_amdgcn_mfma_f32_16x16x32_f16(fa[m], fbl[n], acc[m][n], 0, 0, 0);
            }
        __syncthreads();
    }

    #pragma unroll
    for (int m = 0; m < 4; ++m) {
        const int row = m0 + wr + m * 16 + fq * 4;
        #pragma unroll
        for (int n = 0; n < 4; ++n) {
            const int col = n0 + wc + n * 16 + fr;
            #pragma unroll
            for (int j = 0; j < 4; ++j) {
                const size_t idx = (size_t)(row + j) * N + col;
                float v = acc[m][n][j];
                if (mode == 4) {
                    const float* hv = HVp + (size_t)(row + j) * 16;
                    const float* vv = vBp + (size_t)col * 16;
                    float yv = 0.f;
                    #pragma unroll
                    for (int kk = 0; kk < 16; ++kk) yv = fmaf(hv[kk], vv[kk], yv);
                    const float sg = sigm(yv + bias[col]);
                    v = v + sg * (aux[idx] - v);
                } else if (mode == 3 && z == 0) {
                    v = 0.6065306597126334f * sigm(v + bias[col]);
                }
                C[idx] = v;
            }
        }
    }
}

// ---------------- R/K/V in one dispatch (z: 0=R, 1=K, 2=V with mode-4 epilogue) -------
__global__ __launch_bounds__(256) void gemm_rkv(
    const unsigned short* __restrict__ Xrk,   // [r][k] fp16 (M*K each)
    const unsigned short* __restrict__ Xv,    // v mix fp16
    const unsigned short* __restrict__ Wr16, const unsigned short* __restrict__ Wk16,
    const unsigned short* __restrict__ Wv16,
    float* __restrict__ Cr, float* __restrict__ Ck, float* __restrict__ Cv,
    const float* __restrict__ HVp, const float* __restrict__ vBp,
    const float* __restrict__ vb, const float* __restrict__ vst,
    int M, int N, int K)
{
    __shared__ unsigned short As[GBM * 32];
    __shared__ unsigned short Bhs[GBN * 32];
    const int z = blockIdx.z;
    const unsigned short* Ag = (z == 0) ? Xrk : (z == 1) ? (Xrk + (size_t)M * K) : Xv;
    const unsigned short* Bg = (z == 0) ? Wr16 : (z == 1) ? Wk16 : Wv16;
    float* C = (z == 0) ? Cr : (z == 1) ? Ck : Cv;
    const int tid = threadIdx.x;
    const int m0 = blockIdx.x * GBM;
    const int n0 = blockIdx.y * GBN;
    const int wave = tid >> 6, lane = tid & 63;
    const int wr = (wave >> 1) * 64, wc = (wave & 1) * 64;
    const int fr = lane & 15, fq = lane >> 4;

    f32x4 acc[4][4];
    #pragma unroll
    for (int i = 0; i < 4; ++i)
        #pragma unroll
        for (int j = 0; j < 4; ++j)
            acc[i][j] = (f32x4){0.f, 0.f, 0.f, 0.f};

    const unsigned short* gsrc;
    unsigned short* lbuf;
    int rofs, nld;
    if (wave == 0)      { gsrc = Ag; lbuf = As;           rofs = m0;      nld = 4; }
    else if (wave == 1) { gsrc = Ag; lbuf = As + 64 * 32; rofs = m0 + 64; nld = 4; }
    else if (wave == 2) { gsrc = Bg; lbuf = Bhs;          rofs = n0;      nld = 8; }
    else                { gsrc = Bg; lbuf = Bhs;          rofs = n0;      nld = 0; }
    const unsigned short* gbase = gsrc + (size_t)(rofs + (lane >> 2)) * K + ((lane & 3) << 3);

    for (int k0 = 0; k0 < K; k0 += 32) {
        #pragma unroll
        for (int j = 0; j < 8; ++j)
            if (j < nld)
                gld16(lbuf + j * 16 * 32, gbase + (size_t)(j * 16) * K + k0);
        __syncthreads();

        f16x8 fa[4], fb[4];
        #pragma unroll
        for (int m = 0; m < 4; ++m)
            fa[m] = *(const f16x8*)&As[(wr + m * 16 + fr) * 32 + fq * 8];
        #pragma unroll
        for (int n = 0; n < 4; ++n)
            fb[n] = *(const f16x8*)&Bhs[(wc + n * 16 + fr) * 32 + fq * 8];
        #pragma unroll
        for (int m = 0; m < 4; ++m)
            #pragma unroll
            for (int n = 0; n < 4; ++n)
                acc[m][n] = __builtin_amdgcn_mfma_f32_16x16x32_f16(fa[m], fb[n], acc[m][n], 0, 0, 0);
        __syncthreads();
    }

    #pragma unroll
    for (int m = 0; m < 4; ++m) {
        const int row = m0 + wr + m * 16 + fq * 4;
        #pragma unroll
        for (int n = 0; n < 4; ++n) {
            const int col = n0 + wc + n * 16 + fr;
            #pragma unroll
            for (int j = 0; j < 4; ++j) {
                const size_t idx = (size_t)(row + j) * N + col;
                float v = acc[m][n][j];
                if (z == 2) {
                    const float* hv = HVp + (size_t)(row + j) * 16;
                    const float* vv = vBp + (size_t)col * 16;
                    float yv = 0.f;
                    #pragma unroll
                    for (int kk = 0; kk < 16; ++kk) yv = fmaf(hv[kk], vv[kk], yv);
                    const float sg = sigm(yv + vb[col]);
                    v = v + sg * (vst[idx] - v);
                }
                C[idx] = v;
            }
        }
    }
}

// ---------------- LoRA stage-1 MFMA: z-batched, per-z act epilogue ----------
__global__ __launch_bounds__(256) void lora1_h(
    const unsigned short* __restrict__ Xbase,
    const unsigned short* __restrict__ WL,
    unsigned short* __restrict__ HW16, float* __restrict__ HV,
    unsigned short* __restrict__ HA16, unsigned short* __restrict__ HG16,
    int M, int K, size_t NE)
{
    __shared__ unsigned short As[GBM * 32];
    __shared__ unsigned short Bhs[GBN * 32];
    const int z = blockIdx.z;
    const size_t zofs = (z == 0) ? 0 : (z == 1) ? 3 * NE : (z == 2) ? NE : 2 * NE;  // w,v,a,g
    const unsigned short* Ag = Xbase + zofs;
    const unsigned short* Bg = WL + (size_t)z * 128 * K;
    const int tid = threadIdx.x;
    const int m0 = blockIdx.x * GBM;
    const int wave = tid >> 6, lane = tid & 63;
    const int wr = (wave >> 1) * 64, wc = (wave & 1) * 64;
    const int fr = lane & 15, fq = lane >> 4;

    f32x4 acc[4][4];
    #pragma unroll
    for (int i = 0; i < 4; ++i)
        #pragma unroll
        for (int j = 0; j < 4; ++j)
            acc[i][j] = (f32x4){0.f, 0.f, 0.f, 0.f};

    const unsigned short* gsrc;
    unsigned short* lbuf;
    int rofs, nld;
    if (wave == 0)      { gsrc = Ag; lbuf = As;           rofs = m0;      nld = 4; }
    else if (wave == 1) { gsrc = Ag; lbuf = As + 64 * 32; rofs = m0 + 64; nld = 4; }
    else if (wave == 2) { gsrc = Bg; lbuf = Bhs;          rofs = 0;       nld = 8; }
    else                { gsrc = Bg; lbuf = Bhs;          rofs = 0;       nld = 0; }
    const unsigned short* gbase = gsrc + (size_t)(rofs + (lane >> 2)) * K + ((lane & 3) << 3);

    for (int k0 = 0; k0 < K; k0 += 32) {
        #pragma unroll
        for (int j = 0; j < 8; ++j)
            if (j < nld)
                gld16(lbuf + j * 16 * 32, gbase + (size_t)(j * 16) * K + k0);
        __syncthreads();

        f16x8 fa[4], fb[4];
        #pragma unroll
        for (int m = 0; m < 4; ++m)
            fa[m] = *(const f16x8*)&As[(wr + m * 16 + fr) * 32 + fq * 8];
        #pragma unroll
        for (int n = 0; n < 4; ++n)
            fb[n] = *(const f16x8*)&Bhs[(wc + n * 16 + fr) * 32 + fq * 8];
        #pragma unroll
        for (int m = 0; m < 4; ++m)
            #pragma unroll
            for (int n = 0; n < 4; ++n)
                acc[m][n] = __builtin_amdgcn_mfma_f32_16x16x32_f16(fa[m], fb[n], acc[m][n], 0, 0, 0);
        __syncthreads();
    }

    #pragma unroll
    for (int m = 0; m < 4; ++m) {
        const int row = m0 + wr + m * 16 + fq * 4;
        #pragma unroll
        for (int n = 0; n < 4; ++n) {
            const int col = wc + n * 16 + fr;
            #pragma unroll
            for (int j = 0; j < 4; ++j) {
                const float v = acc[m][n][j];
                const int r = row + j;
                if (z == 0)      { if (col < 64) HW16[(size_t)r * 64 + col] = f2h(tanhf(v)); }
                else if (z == 1) { if (col < 16) HV[(size_t)r * 16 + col] = v; }
                else if (z == 2) { if (col < 64) HA16[(size_t)r * 64 + col] = f2h(v); }
                else             { HG16[(size_t)r * 128 + col] = f2h(sigm(v)); }
            }
        }
    }
}

// per-(b,t,h) wave: a = sigmoid(ya+ab); kk = normalize(k0*k_k); bv = kk*a;
// kfinal = k0*(1+(a-1)*k_a).
__global__ __launch_bounds__(256) void ka_epi(
    float* __restrict__ Kf, float* __restrict__ A_BV, float* __restrict__ KKo,
    const float* __restrict__ k_k, const float* __restrict__ k_a,
    const float* __restrict__ ab, int total, int H)
{
    int wid = (blockIdx.x << 2) | (threadIdx.x >> 6);
    if (wid >= total) return;
    const int l = threadIdx.x & 63;
    const int h = wid % H;
    const int ch = h * 64 + l;
    const size_t base = (size_t)wid * 64;
    float k0 = Kf[base + l];
    float a = sigm(A_BV[base + l] + ab[ch]);
    float kkr = k0 * k_k[ch];
    float ss = full64(kkr * kkr);
    float inv = 1.f / fmaxf(sqrtf(ss), 1e-12f);
    float kkn = kkr * inv;
    KKo[base + l] = kkn;
    A_BV[base + l] = kkn * a;
    Kf[base + l] = k0 * fmaf(a - 1.f, k_a[ch], 1.f);
}

// -------- scan core --------
#define SCH 16
__device__ __forceinline__ void scan_core(
    float* ldsf, int blk, int l,
    const float* __restrict__ EW, const float* __restrict__ R,
    const float* __restrict__ Kf, const float* __restrict__ Vf,
    const float* __restrict__ KK, const float* __restrict__ BV,
    float* __restrict__ O, int T, int H)
{
    const int bh = blk & 63;
    const int slab = blk >> 6;
    const int b = bh >> 5, h = bh & 31;
    const int vc = l & 7;
    const int g  = l >> 3;
    const int kb = g << 3;
    const int vb0 = slab << 3;
    const size_t step = (size_t)H * 64;
    const size_t base0 = ((size_t)b * T * H + h) * 64;
    const int BUF = 5 * SCH * 64 + SCH * 8;

    auto stage = [&](int c, int buf) {
        float* L = ldsf + buf * BUF;
        const size_t t0 = (size_t)c * SCH;
        const float* gs[5] = {EW, R, Kf, KK, BV};
        #pragma unroll
        for (int s = 0; s < 5; ++s) {
            const float* gp = gs[s];
            #pragma unroll
            for (int j = 0; j < 4; ++j)
                gld16(L + s * SCH * 64 + j * 4 * 64,
                      gp + base0 + (t0 + j * 4 + (l >> 4)) * step + ((l & 15) << 2));
        }
        gld4(L + 5 * SCH * 64,
             Vf + base0 + (t0 + (l >> 3)) * step + vb0 + (l & 7));
        gld4(L + 5 * SCH * 64 + 64,
             Vf + base0 + (t0 + 8 + (l >> 3)) * step + vb0 + (l & 7));
    };

    f32x2 s2[4];
    #pragma unroll
    for (int i = 0; i < 4; ++i) s2[i] = (f32x2){0.f, 0.f};

    struct P { f32x4 e[2], r[2], k[2], q[2], bb[2]; float vv; };
    P PA, PB;
    const int NCH = T / SCH;

    stage(0, 0);
    asm volatile("s_waitcnt vmcnt(0)" ::: "memory");
    __builtin_amdgcn_sched_barrier(0);

    for (int c = 0; c < NCH; ++c) {
        if (c + 1 < NCH) stage(c + 1, (c + 1) & 1);

        const float* L = ldsf + (c & 1) * BUF;
        auto PRE = [&](P& pp, int tt) {
            const int o = tt * 64 + kb;
            #pragma unroll
            for (int j = 0; j < 2; ++j) {
                pp.e[j]  = *(const f32x4*)(L + 0 * SCH * 64 + o + j * 4);
                pp.r[j]  = *(const f32x4*)(L + 1 * SCH * 64 + o + j * 4);
                pp.k[j]  = *(const f32x4*)(L + 2 * SCH * 64 + o + j * 4);
                pp.q[j]  = *(const f32x4*)(L + 3 * SCH * 64 + o + j * 4);
                pp.bb[j] = *(const f32x4*)(L + 4 * SCH * 64 + o + j * 4);
            }
            pp.vv = L[5 * SCH * 64 + tt * 8 + vc];
        };
        auto COMP = [&](const P& pp, int tt) {
            f32x2 sa0 = (f32x2){0.f, 0.f}, sa1 = (f32x2){0.f, 0.f};
            #pragma unroll
            for (int j = 0; j < 2; ++j) {
                const f32x2 elo = __builtin_shufflevector(pp.e[j], pp.e[j], 0, 1);
                const f32x2 ehi = __builtin_shufflevector(pp.e[j], pp.e[j], 2, 3);
                const f32x2 qlo = __builtin_shufflevector(pp.q[j], pp.q[j], 0, 1);
                const f32x2 qhi = __builtin_shufflevector(pp.q[j], pp.q[j], 2, 3);
                s2[2*j]   *= elo;
                s2[2*j+1] *= ehi;
                sa0 += qlo * s2[2*j];
                sa1 += qhi * s2[2*j+1];
            }
            const f32x2 sas = sa0 + sa1;
            float p = -(sas.x + sas.y);
            p = red32(red16(red8(p)));
            const f32x2 p2 = (f32x2){p, p};
            const f32x2 v2 = (f32x2){pp.vv, pp.vv};
            f32x2 o0 = (f32x2){0.f, 0.f}, o1 = (f32x2){0.f, 0.f};
            #pragma unroll
            for (int j = 0; j < 2; ++j) {
                const f32x2 klo = __builtin_shufflevector(pp.k[j], pp.k[j], 0, 1);
                const f32x2 khi = __builtin_shufflevector(pp.k[j], pp.k[j], 2, 3);
                const f32x2 blo = __builtin_shufflevector(pp.bb[j], pp.bb[j], 0, 1);
                const f32x2 bhi = __builtin_shufflevector(pp.bb[j], pp.bb[j], 2, 3);
                const f32x2 rlo = __builtin_shufflevector(pp.r[j], pp.r[j], 0, 1);
                const f32x2 rhi = __builtin_shufflevector(pp.r[j], pp.r[j], 2, 3);
                s2[2*j]   = blo * p2 + (klo * v2 + s2[2*j]);
                s2[2*j+1] = bhi * p2 + (khi * v2 + s2[2*j+1]);
                o0 += rlo * s2[2*j];
                o1 += rhi * s2[2*j+1];
            }
            const f32x2 os = o0 + o1;
            float oo = os.x + os.y;
            oo = red32(red16(red8(oo)));
            if (g == 0)
                O[base0 + (size_t)(c * SCH + tt) * step + vb0 + vc] = oo;
        };

        PRE(PA, 0);
        PRE(PB, 1);
        #pragma unroll
        for (int tt = 0; tt < SCH - 2; tt += 2) {
            COMP(PA, tt);     PRE(PA, tt + 2);
            COMP(PB, tt + 1); PRE(PB, tt + 3);
        }
        COMP(PA, SCH - 2);
        COMP(PB, SCH - 1);

        asm volatile("s_waitcnt vmcnt(0)" ::: "memory");
        __builtin_amdgcn_sched_barrier(0);
    }
}

// -------- standalone scan (fallback) --------
__global__ __launch_bounds__(64) void rwkv_scan(
    const float* __restrict__ EW, const float* __restrict__ R,
    const float* __restrict__ Kf, const float* __restrict__ Vf,
    const float* __restrict__ KK, const float* __restrict__ BV,
    float* __restrict__ O, int T, int H)
{
    __shared__ float ldsf[2 * (5 * SCH * 64 + SCH * 8)];
    scan_core(ldsf, blockIdx.x, threadIdx.x, EW, R, Kf, Vf, KK, BV, O, T, H);
}

// -------- hybrid: scan + co-scheduled g-gate GEMM + Wo convert --------
__global__ __launch_bounds__(256) void scan_fused(
    const float* __restrict__ EW, const float* __restrict__ R,
    const float* __restrict__ Kf, const float* __restrict__ Vf,
    const float* __restrict__ KK, const float* __restrict__ BV,
    float* __restrict__ O,
    const unsigned short* __restrict__ HG16, const unsigned short* __restrict__ gb16,
    unsigned short* __restrict__ G16,
    const float* __restrict__ Wo, unsigned short* __restrict__ Wo16, int nW8,
    int T, int H, int M, int D)
{
    __shared__ float smemf[2 * (5 * SCH * 64 + SCH * 8)];
    const int bid = blockIdx.x;
    const int tid = threadIdx.x;

    if (bid < 512) {                       // ---- scan role ----
        if (tid >= 64) return;
        scan_core(smemf, bid, tid, EW, R, Kf, Vf, KK, BV, O, T, H);
        return;
    }
    if (bid < 1024) {                      // ---- g-gate GEMM role (K=128, 1-term) ----
        unsigned short* As  = (unsigned short*)smemf;
        unsigned short* Bhs = As + GBM * 32;
        const int bid2 = bid - 512;
        const int m0 = (bid2 >> 4) * GBM;
        const int n0 = (bid2 & 15) * GBN;
        const int wave = tid >> 6, lane = tid & 63;
        const int wr = (wave >> 1) * 64, wc = (wave & 1) * 64;
        const int fr = lane & 15, fq = lane >> 4;
        const int K = 128;

        f32x4 acc[4][4];
        #pragma unroll
        for (int i = 0; i < 4; ++i)
            #pragma unroll
            for (int j = 0; j < 4; ++j)
                acc[i][j] = (f32x4){0.f, 0.f, 0.f, 0.f};

        const unsigned short* gsrc;
        unsigned short* lbuf;
        int rofs, nld;
        if (wave == 0)      { gsrc = HG16; lbuf = As;           rofs = m0;      nld = 4; }
        else if (wave == 1) { gsrc = HG16; lbuf = As + 64 * 32; rofs = m0 + 64; nld = 4; }
        else if (wave == 2) { gsrc = gb16; lbuf = Bhs;          rofs = n0;      nld = 8; }
        else                { gsrc = gb16; lbuf = Bhs;          rofs = n0;      nld = 0; }
        const unsigned short* gbase = gsrc + (size_t)(rofs + (lane >> 2)) * K + ((lane & 3) << 3);

        for (int k0 = 0; k0 < K; k0 += 32) {
            #pragma unroll
            for (int j = 0; j < 8; ++j)
                if (j < nld)
                    gld16(lbuf + j * 16 * 32, gbase + (size_t)(j * 16) * K + k0);
            __syncthreads();
            f16x8 fa[4], fb[4];
            #pragma unroll
            for (int m = 0; m < 4; ++m)
                fa[m] = *(const f16x8*)&As[(wr + m * 16 + fr) * 32 + fq * 8];
            #pragma unroll
            for (int n = 0; n < 4; ++n)
                fb[n] = *(const f16x8*)&Bhs[(wc + n * 16 + fr) * 32 + fq * 8];
            #pragma unroll
            for (int m = 0; m < 4; ++m)
                #pragma unroll
                for (int n = 0; n < 4; ++n)
                    acc[m][n] = __builtin_amdgcn_mfma_f32_16x16x32_f16(fa[m], fb[n], acc[m][n], 0, 0, 0);
            __syncthreads();
        }
        #pragma unroll
        for (int m = 0; m < 4; ++m) {
            const int row = m0 + wr + m * 16 + fq * 4;
            #pragma unroll
            for (int n = 0; n < 4; ++n) {
                const int col = n0 + wc + n * 16 + fr;
                #pragma unroll
                for (int j = 0; j < 4; ++j)
                    G16[(size_t)(row + j) * D + col] = f2h(acc[m][n][j]);
            }
        }
        return;
    }
    // ---- Wo convert role ----
    {
        int i = (bid - 1024) * 256 + tid;
        if (i >= nW8) return;
        const size_t e = (size_t)i * 8;
        float a[8];
        *(float4*)&a[0] = *(const float4*)(Wo + e);
        *(float4*)&a[4] = *(const float4*)(Wo + e + 4);
        ushort8 h8;
        #pragma unroll
        for (int j = 0; j < 8; ++j) h8[j] = f2h(a[j]);
        *(ushort8*)(Wo16 + e) = h8;
    }
}

// GroupNorm + bonus + g-gate (G f32 or fp16); writes ON16 (fp16).
__global__ __launch_bounds__(256) void gn_bonus(
    const float* __restrict__ O, const float* __restrict__ R,
    const float* __restrict__ Kf, const float* __restrict__ Vf,
    const float* __restrict__ G, const unsigned short* __restrict__ G16,
    const float* __restrict__ r_k,
    const float* __restrict__ gn_w, const float* __restrict__ gn_b,
    unsigned short* __restrict__ ON16, int total, int H, float eps)
{
    int wid = (blockIdx.x << 2) | (threadIdx.x >> 6);
    if (wid >= total) return;
    const int l = threadIdx.x & 63;
    const int h = wid % H;
    const int ch = h * 64 + l;
    const size_t base = (size_t)wid * 64;

    const float o = O[base + l];
    const float mu = full64(o) * (1.f / 64.f);
    const float d = o - mu;
    const float ss = full64(d * d);
    const float inv = 1.f / sqrtf(ss * (1.f / 64.f) + eps);
    float on = d * inv * gn_w[ch] + gn_b[ch];

    const float r = R[base + l], k = Kf[base + l], vv = Vf[base + l];
    const float p = full64(r * k * r_k[ch]);
    on = fmaf(p, vv, on);
    const float gg = G16 ? h2f(G16[base + l]) : G[base + l];
    ON16[base + l] = f2h(on * gg);
}

extern "C" void kernel_launch(void* const* d_in, const int* in_sizes, int n_in,
                              void* d_out, int out_size, void* d_ws, size_t ws_size,
                              hipStream_t stream)
{
    const int B = 2, T = 2048, D = 2048, H = 32;
    const int M = B * T;

    const float* hid = (const float*)d_in[0];
    const float* vst = (const float*)d_in[1];
    const float* x_x = (const float*)d_in[2];
    const float* k_k = (const float*)d_in[3];
    const float* k_a = (const float*)d_in[4];
    const float* r_k = (const float*)d_in[5];
    const float* Wr  = (const float*)d_in[6];
    const float* Wk  = (const float*)d_in[7];
    const float* Wv  = (const float*)d_in[8];
    const float* Wo  = (const float*)d_in[9];
    const float* wA  = (const float*)d_in[10];
    const float* wB  = (const float*)d_in[11];
    const float* wb  = (const float*)d_in[12];
    const float* vA  = (const float*)d_in[13];
    const float* vB  = (const float*)d_in[14];
    const float* vb  = (const float*)d_in[15];
    const float* aA  = (const float*)d_in[16];
    const float* aB  = (const float*)d_in[17];
    const float* ab  = (const float*)d_in[18];
    const float* gA  = (const float*)d_in[19];
    const float* gB  = (const float*)d_in[20];
    const float* gnw = (const float*)d_in[21];
    const float* gnb = (const float*)d_in[22];
    float* out = (float*)d_out;

    const size_t NE = (size_t)M * D;   // 8,388,608
    const size_t DD = (size_t)D * D;   // 4,194,304
    const size_t need  = (6 * NE + (size_t)M * 272) * sizeof(float);
    const size_t need2 = (7 * NE + (size_t)M * 272) * sizeof(float);
    if (ws_size < need) return;
    const bool fused = (ws_size >= need2);

    float* W0 = (float*)d_ws;      // WL pad -> R_
    float* W1 = W0 + NE;           // X2(r,k) -> EW -> ON16
    float* W2 = W1 + NE;           // Kf
    float* W3 = W2 + NE;           // WrH/WkH -> Vf (fallback: Wo16 at end)
    float* W4 = W3 + NE;           // [w][a] mixes -> KK (fallback: wB16/aB16, G)
    float* W5 = W4 + NE;           // [g][v] mixes -> YA -> BV (fallback: gb16)
    float* SMALL = W5 + NE;
    unsigned short* HW16 = (unsigned short*)SMALL;
    unsigned short* HA16 = HW16 + (size_t)M * 64;
    unsigned short* HG16 = HA16 + (size_t)M * 64;
    float* HV = (float*)(HG16 + (size_t)M * 128);
    float* W6 = SMALL + (size_t)M * 272;   // fused only

    dim3 blk(256);
    const int nMix = (int)(NE / 8);
    const int nW   = (int)(DD / 8);
    const int nSm  = (int)(D * 64 / 8);
    const int nG   = (int)(D * 128 / 8);
    const float* nf = nullptr;

    unsigned short* X2   = (unsigned short*)W1;
    unsigned short* X4   = (unsigned short*)W4;   // [w][a][g][v] spans W4,W5
    unsigned short* WRK  = (unsigned short*)W3;   // WrH, WkH
    unsigned short* WL   = (unsigned short*)W0;

    // ---- 1: all six mixes ----
    hipLaunchKernelGGL(mixcvt6_h, dim3(nMix / 256), blk, 0, stream,
                       hid, x_x, X2, X2 + NE, X4, X4 + NE, X4 + 2 * NE, X4 + 3 * NE, T, D, nMix);

    // ---- 2: LoRA-A pad convert ----
    hipLaunchKernelGGL(wcvt_lora, dim3(128, 4), blk, 0, stream, wA, vA, aA, gA, WL, D);

    if (fused) {
        unsigned short* W6s  = (unsigned short*)W6;
        unsigned short* G16p = W6s;                        // NE
        unsigned short* WvWo = W6s + NE;                   // DD: WvH then Wo16 (time-shared)
        unsigned short* gb16 = W6s + NE + DD;              // D*128
        unsigned short* wB16 = gb16 + (size_t)D * 128;     // D*64
        unsigned short* aB16 = wB16 + (size_t)D * 64;      // D*64

        // ---- 3: all six weight converts in one launch ----
        hipLaunchKernelGGL(wcvt_all, dim3(nW / 256, 6), blk, 0, stream,
                           Wr, Wk, Wv, wB, aB, gB,
                           WRK, WRK + DD, WvWo, wB16, aB16, gb16, nW, nSm, nG);

        // ---- 4: LoRA stage-1 MFMA ----
        hipLaunchKernelGGL(lora1_h, dim3(M / GBM, 1, 4), blk, 0, stream,
                           X4, WL, HW16, HV, HA16, HG16, M, D, NE);

        // ---- 5: R/K/V in one dispatch (V with inline-yv lerp) ----
        hipLaunchKernelGGL(gemm_rkv, dim3(M / GBM, D / GBN, 3), blk, 0, stream,
                           X2, X4 + 3 * NE, WRK, WRK + DD, WvWo,
                           W0, W2, W3, HV, vB, vb, vst, M, D, D);

        // ---- 6: LoRA stage-2 MFMA (z0: EW -> W1; z1: ya -> W5) ----
        hipLaunchKernelGGL((gemm_h2<1>), dim3(M / GBM, D / GBN, 2), blk, 0, stream,
                           HW16, wB16, wB16, W1, M, D, 64, 3, nf, nf, wb, nf,
                           (size_t)M * 64, (size_t)D * 64, 4 * NE);

        // ---- 7: ka epilogue ----
        const int totalW = M * H;
        hipLaunchKernelGGL(ka_epi, dim3(totalW / 4), blk, 0, stream, W2, W5, W4, k_k, k_a, ab, totalW, H);

        // ---- 8: scan + co-scheduled g-gate GEMM + Wo convert (overwrites WvWo) ----
        hipLaunchKernelGGL(scan_fused, dim3(512 + 512 + 2048), blk, 0, stream,
                           W1, W0, W2, W3, W4, W5, out,
                           HG16, gb16, G16p, Wo, WvWo, nW, T, H, M, D);

        // ---- 9: gn_bonus (G fp16) -> ON16 (W1) ----
        unsigned short* ON16 = (unsigned short*)W1;
        hipLaunchKernelGGL(gn_bonus, dim3(totalW / 4), blk, 0, stream, out, W0, W2, W3, nf, G16p, r_k, gnw, gnb, ON16, totalW, H, 64.f * 1e-5f);

        // ---- 10: Wo projection ----
        hipLaunchKernelGGL((gemm_h2<1>), dim3(M / GBM, D / GBN, 1), blk, 0, stream,
                           ON16, WvWo, WvWo, out, M, D, D, 0, nf, nf, nf, nf, 0, 0, 0);
    } else {
        // -------- fallback: round-21 sequential path --------
        hipLaunchKernelGGL(wcvt2_h, dim3(nW / 256, 2), blk, 0, stream, Wr, Wk, WRK, WRK + DD, nW);
        hipLaunchKernelGGL(lora1_h, dim3(M / GBM, 1, 4), blk, 0, stream,
                           X4, WL, HW16, HV, HA16, HG16, M, D, NE);
        hipLaunchKernelGGL((gemm_h2<1>), dim3(M / GBM, D / GBN, 2), blk, 0, stream,
                           X2, WRK, WRK, W0, M, D, D, 0, nf, nf, nf, nf,
                           NE, DD, 2 * NE);
        unsigned short* WvH = (unsigned short*)W4;
        hipLaunchKernelGGL(wcvt2_h, dim3(nW / 256, 1), blk, 0, stream, Wv, Wv, WvH, WvH, nW);
        hipLaunchKernelGGL((gemm_h2<1>), dim3(M / GBM, D / GBN, 1), blk, 0, stream,
                           X4 + 3 * NE, WvH, WvH, W3, M, D, D, 4, HV, vB, vb, vst, 0, 0, 0);
        unsigned short* wB16 = (unsigned short*)W4;
        unsigned short* aB16 = wB16 + (size_t)D * 64;
        hipLaunchKernelGGL(wcvt2_h, dim3(nSm / 256, 2), blk, 0, stream, wB, aB, wB16, aB16, nSm);
        hipLaunchKernelGGL((gemm_h2<1>), dim3(M / GBM, D / GBN, 2), blk, 0, stream,
                           HW16, wB16, wB16, W1, M, D, 64, 3, nf, nf, wb, nf,
                           (size_t)M * 64, (size_t)D * 64, 4 * NE);
        const int totalW = M * H;
        hipLaunchKernelGGL(ka_epi, dim3(totalW / 4), blk, 0, stream, W2, W5, W4, k_k, k_a, ab, totalW, H);
        hipLaunchKernelGGL(rwkv_scan, dim3(B * H * 8), dim3(64), 0, stream, W1, W0, W2, W3, W4, W5, out, T, H);
        unsigned short* gb16 = (unsigned short*)W5;
        hipLaunchKernelGGL(wcvt2_h, dim3(nG / 256, 1), blk, 0, stream, gB, gB, gb16, gb16, nG);
        hipLaunchKernelGGL((gemm_h2<1>), dim3(M / GBM, D / GBN, 1), blk, 0, stream,
                           HG16, gb16, gb16, W4, M, D, 128, 0, nf, nf, nf, nf, 0, 0, 0);
        unsigned short* ON16 = (unsigned short*)W1;
        hipLaunchKernelGGL(gn_bonus, dim3(totalW / 4), blk, 0, stream, out, W0, W2, W3, W4, (const unsigned short*)nullptr, r_k, gnw, gnb, ON16, totalW, H, 64.f * 1e-5f);
        unsigned short* Wo16 = (unsigned short*)W3;
        hipLaunchKernelGGL(wcvt2_h, dim3(nW / 256, 1), blk, 0, stream, Wo, Wo, Wo16, Wo16, nW);
        hipLaunchKernelGGL((gemm_h2<1>), dim3(M / GBM, D / GBN, 1), blk, 0, stream,
                           ON16, Wo16, Wo16, out, M, D, D, 0, nf, nf, nf, nf, 0, 0, 0);
    }
}